// Round 1
// baseline (10093.246 us; speedup 1.0000x reference)
//
#include <hip/hip_runtime.h>
#include <hip/hip_bf16.h>
#include <math.h>

#define NHEADS 8

// ---------------- helpers ----------------
static __device__ __forceinline__ float block_reduce_sum(float v, float* red) {
  int t = threadIdx.x;
  red[t] = v; __syncthreads();
  for (int s = 128; s > 0; s >>= 1) {
    if (t < s) red[t] += red[t + s];
    __syncthreads();
  }
  float r = red[0];
  __syncthreads();
  return r;
}

// ---------------- sigmoid table + row sums ----------------
// Sg[r,k] = sigmoid(Wp[r,k]); Ssum[r] = sum_k Sg[r,k]
__global__ __launch_bounds__(256) void sig_kernel(
    const float* __restrict__ Wp, float* __restrict__ Sg,
    float* __restrict__ Ssum, int Kd)
{
  __shared__ float red[256];
  int row = blockIdx.x;
  float s = 0.f;
  for (int k = threadIdx.x; k < Kd; k += 256) {
    float v = 1.f / (1.f + __expf(-Wp[(size_t)row * Kd + k]));
    Sg[(size_t)row * Kd + k] = v;
    s += v;
  }
  float tot = block_reduce_sum(s, red);
  if (threadIdx.x == 0) Ssum[row] = tot;
}

// ---------------- generic tiled SGEMM: C = epi(A@W + bias) ----------------
// A [M,K] row-major, W [K,N] row-major. EPI: 0=none, 1=relu, 2=relu then /divv[row]
template<int EPI>
__global__ __launch_bounds__(256) void gemm_kernel(
    const float* __restrict__ A, const float* __restrict__ W,
    const float* __restrict__ bias, float* __restrict__ C,
    int M, int N, int K, const float* __restrict__ divv)
{
  __shared__ float As[16][68];
  __shared__ float Bs[16][68];
  int tid = threadIdx.x;
  int tx = tid & 15, ty = tid >> 4;
  int row0 = blockIdx.y * 64, col0 = blockIdx.x * 64;
  float acc[4][4] = {};

  for (int k0 = 0; k0 < K; k0 += 16) {
    { // load A tile (64 rows x 16 k), 4 contiguous k per thread
      int m = tid >> 2;
      int kk0 = (tid & 3) * 4;
      int gr = row0 + m;
      const float* ap = A + (size_t)gr * K + k0 + kk0;
      #pragma unroll
      for (int u = 0; u < 4; ++u) {
        int kk = kk0 + u;
        As[kk][m] = (gr < M && (k0 + kk) < K) ? ap[u] : 0.f;
      }
    }
    { // load B tile (16 k x 64 cols), 4 contiguous cols per thread
      int kk = tid >> 4;
      int nn0 = (tid & 15) * 4;
      int gk = k0 + kk;
      const float* wp = W + (size_t)gk * N + col0 + nn0;
      #pragma unroll
      for (int u = 0; u < 4; ++u) {
        int gc = col0 + nn0 + u;
        Bs[kk][nn0 + u] = (gk < K && gc < N) ? wp[u] : 0.f;
      }
    }
    __syncthreads();
    #pragma unroll
    for (int kk = 0; kk < 16; ++kk) {
      float a[4], bq[4];
      #pragma unroll
      for (int u = 0; u < 4; ++u) a[u] = As[kk][ty * 4 + u];
      #pragma unroll
      for (int u = 0; u < 4; ++u) bq[u] = Bs[kk][tx * 4 + u];
      #pragma unroll
      for (int ii = 0; ii < 4; ++ii)
        #pragma unroll
        for (int jj = 0; jj < 4; ++jj)
          acc[ii][jj] += a[ii] * bq[jj];
    }
    __syncthreads();
  }

  #pragma unroll
  for (int ii = 0; ii < 4; ++ii) {
    int gr = row0 + ty * 4 + ii;
    if (gr >= M) continue;
    #pragma unroll
    for (int jj = 0; jj < 4; ++jj) {
      int gc = col0 + tx * 4 + jj;
      if (gc >= N) continue;
      float v = acc[ii][jj] + (bias ? bias[gc] : 0.f);
      if (EPI >= 1) v = fmaxf(v, 0.f);
      if (EPI == 2) v /= divv[gr];
      C[(size_t)gr * N + gc] = v;
    }
  }
}

// ---------------- embedding gather ----------------
// qemb[row,c] = E[p,c] + diff_W[p]   (c<256)
// qaemb[row,c] = (c<256 ? E[pa_pos,c] : E[pa_neg,c-256]) + diff_W[p]
__global__ __launch_bounds__(256) void gather_kernel(
    const int* __restrict__ p_data, const int* __restrict__ pa_data,
    const float* __restrict__ E, const float* __restrict__ diff_W,
    float* __restrict__ qemb, float* __restrict__ qaemb)
{
  int idx = blockIdx.x * 256 + threadIdx.x;
  if (idx >= 8192 * 512) return;
  int row = idx >> 9, c = idx & 511;
  int p = p_data[row];
  float pid = diff_W[p];
  if (c < 256) qemb[(size_t)row * 256 + c] = E[(size_t)p * 256 + c] + pid;
  int pa = pa_data[row];
  int ppos = (pa > 4096) ? pa - 4096 : 0;
  int pneg = (pa <= 4096) ? pa : 0;
  float v = (c < 256) ? E[(size_t)ppos * 256 + c] : E[(size_t)pneg * 256 + (c - 256)];
  qaemb[(size_t)row * 512 + c] = v + pid;
}

// ---------------- c_reg ----------------
__global__ __launch_bounds__(256) void creg_kernel(
    const int* __restrict__ p_data, const float* __restrict__ dW,
    float* __restrict__ out)
{
  __shared__ float red[256];
  float s = 0.f;
  for (int i = threadIdx.x; i < 8192; i += 256) {
    float v = dW[p_data[i]];
    s += v * v;
  }
  float tot = block_reduce_sum(s, red);
  if (threadIdx.x == 0) out[0] = tot * 1e-5f;
}

// ---------------- distance-decay attention, one query row per block ----------------
// QK: [B*S, H*DK], V: [B*S, H*DV], O: [B*S, H*DV]
template<int DK, int DV>
__global__ __launch_bounds__(256) void attn_kernel(
    const float* __restrict__ QK, const float* __restrict__ Vv,
    const float* __restrict__ gamp, float* __restrict__ O,
    int S, int maskk, int zeropad)
{
  const int i = blockIdx.x;
  const int b = blockIdx.y / NHEADS, h = blockIdx.y % NHEADS;
  const int DMK = NHEADS * DK, DMV = NHEADS * DV;
  const int tid = threadIdx.x;
  float* orow = O + ((size_t)(b * S + i)) * DMV + h * DV;
  const int jmax = maskk ? i : i - 1;

  __shared__ float sc[1024];
  __shared__ float pa[1024];
  __shared__ float pb[1024];
  __shared__ float qv[64];
  __shared__ float red[256];

  if ((zeropad && i == 0) || jmax < 0) {
    for (int d = tid; d < DV; d += 256) orow[d] = 0.f;
    return;
  }

  const float* qrow = QK + ((size_t)(b * S + i)) * DMK + h * DK;
  if (tid < DK) qv[tid] = qrow[tid];
  __syncthreads();

  const float rscale = rsqrtf((float)DK);
  const int n = jmax + 1;

  // raw scores
  for (int j = tid; j < n; j += 256) {
    const float* kr = QK + ((size_t)(b * S + j)) * DMK + h * DK;
    float s = 0.f;
    #pragma unroll
    for (int d = 0; d < DK; ++d) s += qv[d] * kr[d];
    sc[j] = s * rscale;
  }
  __syncthreads();

  // softmax #1 -> pa (probabilities)
  float lm = -1e30f;
  for (int j = tid; j < n; j += 256) lm = fmaxf(lm, sc[j]);
  red[tid] = lm; __syncthreads();
  for (int s2 = 128; s2 > 0; s2 >>= 1) { if (tid < s2) red[tid] = fmaxf(red[tid], red[tid + s2]); __syncthreads(); }
  float m1 = red[0]; __syncthreads();
  float ls = 0.f;
  for (int j = tid; j < n; j += 256) { float e = __expf(sc[j] - m1); pa[j] = e; ls += e; }
  red[tid] = ls; __syncthreads();
  for (int s2 = 128; s2 > 0; s2 >>= 1) { if (tid < s2) red[tid] += red[tid + s2]; __syncthreads(); }
  float inv1 = 1.f / red[0]; __syncthreads();
  for (int j = tid; j < 1024; j += 256) pa[j] = (j < n) ? pa[j] * inv1 : 0.f;
  __syncthreads();

  // inclusive cumsum of pa[0..n) (Hillis-Steele, ping-pong pa<->pb)
  float* src = pa; float* dst = pb;
  for (int off = 1; off < n; off <<= 1) {
    for (int j = tid; j < n; j += 256)
      dst[j] = src[j] + (j >= off ? src[j - off] : 0.f);
    __syncthreads();
    float* t = src; src = dst; dst = t;
  }

  // distance effect: disttot = 1 (valid row). eff = clip(exp(gamma*dist),1e-5,1e5)
  float g = gamp[h];
  float sp = fmaxf(g, 0.f) + log1pf(__expf(-fabsf(g)));  // stable softplus
  float gm = -sp;
  for (int j = tid; j < n; j += 256) {
    float rem = fmaxf(1.f - src[j], 0.f);
    float dist = sqrtf(rem * fabsf((float)(j - i)));
    float eff = __expf(gm * dist);
    eff = fminf(fmaxf(eff, 1e-5f), 1e5f);
    sc[j] = sc[j] * eff;
  }
  __syncthreads();

  // softmax #2 -> pa (weights)
  float lm2 = -1e30f;
  for (int j = tid; j < n; j += 256) lm2 = fmaxf(lm2, sc[j]);
  red[tid] = lm2; __syncthreads();
  for (int s2 = 128; s2 > 0; s2 >>= 1) { if (tid < s2) red[tid] = fmaxf(red[tid], red[tid + s2]); __syncthreads(); }
  float m2 = red[0]; __syncthreads();
  float ls2 = 0.f;
  for (int j = tid; j < n; j += 256) { float e = __expf(sc[j] - m2); pa[j] = e; ls2 += e; }
  red[tid] = ls2; __syncthreads();
  for (int s2 = 128; s2 > 0; s2 >>= 1) { if (tid < s2) red[tid] += red[tid + s2]; __syncthreads(); }
  float inv2 = 1.f / red[0]; __syncthreads();
  for (int j = tid; j < n; j += 256) pa[j] *= inv2;
  __syncthreads();

  // PV: out[d] = sum_j pa[j] * V[j,d]
  const int NCH = 256 / DV;
  const int d = tid % DV, c = tid / DV;
  float acc = 0.f;
  for (int j = c; j < n; j += NCH)
    acc += pa[j] * Vv[((size_t)(b * S + j)) * DMV + h * DV + d];
  red[tid] = acc; __syncthreads();
  if (c == 0) {
    #pragma unroll
    for (int cc = 1; cc < NCH; ++cc) acc += red[cc * DV + d];
    orow[d] = acc;
  }
}

// ---------------- LayerNorm: Y = g*((X(+R))-mean)*rsqrt(var+eps)+b ----------------
__global__ __launch_bounds__(256) void ln_kernel(
    const float* __restrict__ X, const float* __restrict__ R,
    const float* __restrict__ g, const float* __restrict__ be,
    float* __restrict__ Y, int D)
{
  __shared__ float red[256];
  int row = blockIdx.x, tid = threadIdx.x;
  const float* x = X + (size_t)row * D;
  const float* r = R ? R + (size_t)row * D : nullptr;
  int ne = D >> 8;  // 1 (D=256) or 2 (D=512)
  float xl[2];
  float s = 0.f;
  for (int e = 0; e < ne; ++e) {
    int j = tid + e * 256;
    float v = x[j] + (r ? r[j] : 0.f);
    xl[e] = v; s += v;
  }
  float mean = block_reduce_sum(s, red) / (float)D;
  float vs = 0.f;
  for (int e = 0; e < ne; ++e) { float dd = xl[e] - mean; vs += dd * dd; }
  float var = block_reduce_sum(vs, red) / (float)D;
  float rstd = rsqrtf(var + 1e-5f);
  for (int e = 0; e < ne; ++e) {
    int j = tid + e * 256;
    Y[(size_t)row * D + j] = g[j] * (xl[e] - mean) * rstd + be[j];
  }
}

// ---------------- concat c = [x | q_embed] ----------------
__global__ __launch_bounds__(256) void concat_kernel(
    const float* __restrict__ Xh, const float* __restrict__ Qe,
    float* __restrict__ Cc)
{
  int idx = blockIdx.x * 256 + threadIdx.x;
  if (idx >= 8192 * 512) return;
  int row = idx >> 9, c = idx & 511;
  Cc[(size_t)row * 512 + c] = (c < 256) ? Xh[(size_t)row * 256 + c]
                                        : Qe[(size_t)row * 256 + (c - 256)];
}

// ---------------- final row-dot: out[row] = dot(X[row,:256], w) + b ----------------
__global__ __launch_bounds__(256) void dot_kernel(
    const float* __restrict__ X, const float* __restrict__ w,
    const float* __restrict__ b, float* __restrict__ out)
{
  __shared__ float red[256];
  int row = blockIdx.x;
  float v = X[(size_t)row * 256 + threadIdx.x] * w[threadIdx.x];
  float s = block_reduce_sum(v, red);
  if (threadIdx.x == 0) out[row] = s + b[0];
}

// ---------------- launch ----------------
extern "C" void kernel_launch(void* const* d_in, const int* in_sizes, int n_in,
                              void* d_out, int out_size, void* d_ws, size_t ws_size,
                              hipStream_t stream) {
  const int* p_data  = (const int*)d_in[0];
  const int* pa_data = (const int*)d_in[1];
  const float* pemb_W = (const float*)d_in[3];
  const float* diff_W = (const float*)d_in[4];
  const float* qemb_W = (const float*)d_in[5];
  const float* qemb_b = (const float*)d_in[6];
  const float* y_kW = (const float*)d_in[7];   const float* y_kb = (const float*)d_in[8];
  const float* y_vW = (const float*)d_in[9];   const float* y_vb = (const float*)d_in[10];
  const float* y_oW = (const float*)d_in[11];  const float* y_ob = (const float*)d_in[12];
  const float* y_gam = (const float*)d_in[13];
  const float* y_ln1g = (const float*)d_in[14]; const float* y_ln1b = (const float*)d_in[15];
  const float* y_f1W = (const float*)d_in[16]; const float* y_f1b = (const float*)d_in[17];
  const float* y_f2W = (const float*)d_in[18]; const float* y_f2b = (const float*)d_in[19];
  const float* y_ln2g = (const float*)d_in[20]; const float* y_ln2b = (const float*)d_in[21];
  const float* x_kW = (const float*)d_in[22];  const float* x_kb = (const float*)d_in[23];
  const float* x_vW = (const float*)d_in[24];  const float* x_vb = (const float*)d_in[25];
  const float* x_oW = (const float*)d_in[26];  const float* x_ob = (const float*)d_in[27];
  const float* x_gam = (const float*)d_in[28];
  const float* x_ln1g = (const float*)d_in[29]; const float* x_ln1b = (const float*)d_in[30];
  const float* h_kW = (const float*)d_in[31];  const float* h_kb = (const float*)d_in[32];
  const float* h_vW = (const float*)d_in[33];  const float* h_vb = (const float*)d_in[34];
  const float* h_oW = (const float*)d_in[35];  const float* h_ob = (const float*)d_in[36];
  const float* h_gam = (const float*)d_in[37];
  const float* h_ln1g = (const float*)d_in[38]; const float* h_ln1b = (const float*)d_in[39];
  const float* h_f1W = (const float*)d_in[40]; const float* h_f1b = (const float*)d_in[41];
  const float* h_f2W = (const float*)d_in[42]; const float* h_f2b = (const float*)d_in[43];
  const float* h_ln2g = (const float*)d_in[44]; const float* h_ln2b = (const float*)d_in[45];
  const float* oln1g = (const float*)d_in[46]; const float* oln1b = (const float*)d_in[47];
  const float* o1W = (const float*)d_in[48];   const float* o1b = (const float*)d_in[49];
  const float* oln2g = (const float*)d_in[50]; const float* oln2b = (const float*)d_in[51];
  const float* o2W = (const float*)d_in[52];   const float* o2b = (const float*)d_in[53];
  const float* oln3g = (const float*)d_in[54]; const float* oln3b = (const float*)d_in[55];
  const float* o3W = (const float*)d_in[56];   const float* o3b = (const float*)d_in[57];

  float* out_f = (float*)d_out;

  const int B = 8, S = 1024, M = B * S;       // 8192 rows
  const int R = 4097, KQ = 1025;              // embedding table dims

  // workspace arena (floats)
  float* ws = (float*)d_ws;
  size_t off = 0;
  auto alloc = [&](size_t n) { size_t o = off; off += (n + 255) & ~(size_t)255; return o; };
  size_t oE    = alloc((size_t)R * 256);
  size_t oSIG  = alloc((size_t)R * KQ);
  size_t oSSUM = alloc(R);
  size_t oQE   = alloc((size_t)M * 256);
  size_t oQA   = alloc((size_t)M * 512);
  size_t oYO   = alloc((size_t)M * 512);
  size_t oXO   = alloc((size_t)M * 256);
  size_t oHO   = alloc((size_t)M * 256);
  size_t oS0   = alloc((size_t)M * 512);  // S0..S3 contiguous; FF hidden aliases them
  size_t oS1   = alloc((size_t)M * 512);
  size_t oS2   = alloc((size_t)M * 512);
  size_t oS3   = alloc((size_t)M * 512);
  size_t oS4   = alloc((size_t)M * 512);
  size_t oSX   = alloc((size_t)M * 512);
  (void)ws_size; (void)in_sizes; (void)n_in; (void)out_size;

  float* E    = ws + oE;
  float* SIG  = ws + oSIG;
  float* SSUM = ws + oSSUM;
  float* QE   = ws + oQE;
  float* QA   = ws + oQA;
  float* YO   = ws + oYO;
  float* XO   = ws + oXO;
  float* HO   = ws + oHO;
  float* S0   = ws + oS0;
  float* S1   = ws + oS1;
  float* S2   = ws + oS2;
  float* S3   = ws + oS3;
  float* S4   = ws + oS4;
  float* SX   = ws + oSX;
  float* FF   = S0;  // [8192,2048] aliases S0..S3 (16,777,216 floats available)

  auto grid_of = [](int Mm, int Nn) { return dim3((unsigned)((Nn + 63) / 64), (unsigned)((Mm + 63) / 64)); };
  dim3 blk(256);
  int nElem512 = (8192 * 512 + 255) / 256;

  // 1. embedding table
  sig_kernel<<<R, blk, 0, stream>>>(pemb_W, SIG, SSUM, KQ);
  gemm_kernel<2><<<grid_of(R, 256), blk, 0, stream>>>(SIG, qemb_W, qemb_b, E, R, 256, KQ, SSUM);
  gather_kernel<<<nElem512, blk, 0, stream>>>(p_data, pa_data, E, diff_W, QE, QA);
  creg_kernel<<<1, blk, 0, stream>>>(p_data, diff_W, out_f + 8192);

  dim3 agrid(S, B * NHEADS);

  // 2. y layer (dm=512, mask_k=1, zero_pad=0, FFN)
  gemm_kernel<0><<<grid_of(M, 512), blk, 0, stream>>>(QA, y_kW, y_kb, S0, M, 512, 512, nullptr);
  gemm_kernel<0><<<grid_of(M, 512), blk, 0, stream>>>(QA, y_vW, y_vb, S1, M, 512, 512, nullptr);
  attn_kernel<64, 64><<<agrid, blk, 0, stream>>>(S0, S1, y_gam, S2, S, 1, 0);
  gemm_kernel<0><<<grid_of(M, 512), blk, 0, stream>>>(S2, y_oW, y_ob, S3, M, 512, 512, nullptr);
  ln_kernel<<<M, blk, 0, stream>>>(QA, S3, y_ln1g, y_ln1b, SX, 512);
  gemm_kernel<1><<<grid_of(M, 2048), blk, 0, stream>>>(SX, y_f1W, y_f1b, FF, M, 2048, 512, nullptr);
  gemm_kernel<0><<<grid_of(M, 512), blk, 0, stream>>>(FF, y_f2W, y_f2b, S4, M, 512, 2048, nullptr);
  ln_kernel<<<M, blk, 0, stream>>>(SX, S4, y_ln2g, y_ln2b, YO, 512);

  // 3. x layer (dm=256, mask_k=1, zero_pad=0, no FFN)
  gemm_kernel<0><<<grid_of(M, 256), blk, 0, stream>>>(QE, x_kW, x_kb, S0, M, 256, 256, nullptr);
  gemm_kernel<0><<<grid_of(M, 256), blk, 0, stream>>>(QE, x_vW, x_vb, S1, M, 256, 256, nullptr);
  attn_kernel<32, 32><<<agrid, blk, 0, stream>>>(S0, S1, x_gam, S2, S, 1, 0);
  gemm_kernel<0><<<grid_of(M, 256), blk, 0, stream>>>(S2, x_oW, x_ob, S3, M, 256, 256, nullptr);
  ln_kernel<<<M, blk, 0, stream>>>(QE, S3, x_ln1g, x_ln1b, XO, 256);

  // 4. h layer (q,k from XO dm=256; v from YO dm=512; mask_k=0, zero_pad=1, FFN)
  gemm_kernel<0><<<grid_of(M, 256), blk, 0, stream>>>(XO, h_kW, h_kb, S0, M, 256, 256, nullptr);
  gemm_kernel<0><<<grid_of(M, 512), blk, 0, stream>>>(YO, h_vW, h_vb, S1, M, 512, 512, nullptr);
  attn_kernel<32, 64><<<agrid, blk, 0, stream>>>(S0, S1, h_gam, S2, S, 0, 1);
  gemm_kernel<0><<<grid_of(M, 256), blk, 0, stream>>>(S2, h_oW, h_ob, S3, M, 256, 512, nullptr);
  ln_kernel<<<M, blk, 0, stream>>>(XO, S3, h_ln1g, h_ln1b, SX, 256);
  gemm_kernel<1><<<grid_of(M, 2048), blk, 0, stream>>>(SX, h_f1W, h_f1b, FF, M, 2048, 256, nullptr);
  gemm_kernel<0><<<grid_of(M, 256), blk, 0, stream>>>(FF, h_f2W, h_f2b, S4, M, 256, 2048, nullptr);
  ln_kernel<<<M, blk, 0, stream>>>(SX, S4, h_ln2g, h_ln2b, HO, 256);

  // 5. head
  concat_kernel<<<nElem512, blk, 0, stream>>>(HO, QE, S0);
  ln_kernel<<<M, blk, 0, stream>>>(S0, nullptr, oln1g, oln1b, S1, 512);
  gemm_kernel<1><<<grid_of(M, 512), blk, 0, stream>>>(S1, o1W, o1b, S2, M, 512, 512, nullptr);
  ln_kernel<<<M, blk, 0, stream>>>(S2, nullptr, oln2g, oln2b, S3, 512);
  gemm_kernel<1><<<grid_of(M, 256), blk, 0, stream>>>(S3, o2W, o2b, SX, M, 256, 512, nullptr);
  ln_kernel<<<M, blk, 0, stream>>>(SX, nullptr, oln3g, oln3b, S4, 256);
  dot_kernel<<<M, blk, 0, stream>>>(S4, o3W, o3b, out_f);
}

// Round 2
// 4195.703 us; speedup vs baseline: 2.4056x; 2.4056x over previous
//
#include <hip/hip_runtime.h>
#include <hip/hip_bf16.h>
#include <math.h>

#define NHEADS 8

// ---------------- helpers ----------------
static __device__ __forceinline__ float block_reduce_sum(float v, float* red) {
  int t = threadIdx.x;
  red[t] = v; __syncthreads();
  for (int s = 128; s > 0; s >>= 1) {
    if (t < s) red[t] += red[t + s];
    __syncthreads();
  }
  float r = red[0];
  __syncthreads();
  return r;
}

// ---------------- sigmoid table + row sums ----------------
__global__ __launch_bounds__(256) void sig_kernel(
    const float* __restrict__ Wp, float* __restrict__ Sg,
    float* __restrict__ Ssum, int Kd)
{
  __shared__ float red[256];
  int row = blockIdx.x;
  float s = 0.f;
  for (int k = threadIdx.x; k < Kd; k += 256) {
    float v = 1.f / (1.f + __expf(-Wp[(size_t)row * Kd + k]));
    Sg[(size_t)row * Kd + k] = v;
    s += v;
  }
  float tot = block_reduce_sum(s, red);
  if (threadIdx.x == 0) Ssum[row] = tot;
}

// ---------------- generic tiled SGEMM: C = epi(A@W + bias) ----------------
template<int EPI>
__global__ __launch_bounds__(256) void gemm_kernel(
    const float* __restrict__ A, const float* __restrict__ W,
    const float* __restrict__ bias, float* __restrict__ C,
    int M, int N, int K, const float* __restrict__ divv)
{
  __shared__ float As[16][68];
  __shared__ float Bs[16][68];
  int tid = threadIdx.x;
  int tx = tid & 15, ty = tid >> 4;
  int row0 = blockIdx.y * 64, col0 = blockIdx.x * 64;
  float acc[4][4] = {};

  for (int k0 = 0; k0 < K; k0 += 16) {
    {
      int m = tid >> 2;
      int kk0 = (tid & 3) * 4;
      int gr = row0 + m;
      const float* ap = A + (size_t)gr * K + k0 + kk0;
      #pragma unroll
      for (int u = 0; u < 4; ++u) {
        int kk = kk0 + u;
        As[kk][m] = (gr < M && (k0 + kk) < K) ? ap[u] : 0.f;
      }
    }
    {
      int kk = tid >> 4;
      int nn0 = (tid & 15) * 4;
      int gk = k0 + kk;
      const float* wp = W + (size_t)gk * N + col0 + nn0;
      #pragma unroll
      for (int u = 0; u < 4; ++u) {
        int gc = col0 + nn0 + u;
        Bs[kk][nn0 + u] = (gk < K && gc < N) ? wp[u] : 0.f;
      }
    }
    __syncthreads();
    #pragma unroll
    for (int kk = 0; kk < 16; ++kk) {
      float a[4], bq[4];
      #pragma unroll
      for (int u = 0; u < 4; ++u) a[u] = As[kk][ty * 4 + u];
      #pragma unroll
      for (int u = 0; u < 4; ++u) bq[u] = Bs[kk][tx * 4 + u];
      #pragma unroll
      for (int ii = 0; ii < 4; ++ii)
        #pragma unroll
        for (int jj = 0; jj < 4; ++jj)
          acc[ii][jj] += a[ii] * bq[jj];
    }
    __syncthreads();
  }

  #pragma unroll
  for (int ii = 0; ii < 4; ++ii) {
    int gr = row0 + ty * 4 + ii;
    if (gr >= M) continue;
    #pragma unroll
    for (int jj = 0; jj < 4; ++jj) {
      int gc = col0 + tx * 4 + jj;
      if (gc >= N) continue;
      float v = acc[ii][jj] + (bias ? bias[gc] : 0.f);
      if (EPI >= 1) v = fmaxf(v, 0.f);
      if (EPI == 2) v /= divv[gr];
      C[(size_t)gr * N + gc] = v;
    }
  }
}

// ---------------- embedding gather ----------------
__global__ __launch_bounds__(256) void gather_kernel(
    const int* __restrict__ p_data, const int* __restrict__ pa_data,
    const float* __restrict__ E, const float* __restrict__ diff_W,
    float* __restrict__ qemb, float* __restrict__ qaemb)
{
  int idx = blockIdx.x * 256 + threadIdx.x;
  if (idx >= 8192 * 512) return;
  int row = idx >> 9, c = idx & 511;
  int p = p_data[row];
  float pid = diff_W[p];
  if (c < 256) qemb[(size_t)row * 256 + c] = E[(size_t)p * 256 + c] + pid;
  int pa = pa_data[row];
  int ppos = (pa > 4096) ? pa - 4096 : 0;
  int pneg = (pa <= 4096) ? pa : 0;
  float v = (c < 256) ? E[(size_t)ppos * 256 + c] : E[(size_t)pneg * 256 + (c - 256)];
  qaemb[(size_t)row * 512 + c] = v + pid;
}

// ---------------- c_reg ----------------
__global__ __launch_bounds__(256) void creg_kernel(
    const int* __restrict__ p_data, const float* __restrict__ dW,
    float* __restrict__ out)
{
  __shared__ float red[256];
  float s = 0.f;
  for (int i = threadIdx.x; i < 8192; i += 256) {
    float v = dW[p_data[i]];
    s += v * v;
  }
  float tot = block_reduce_sum(s, red);
  if (threadIdx.x == 0) out[0] = tot * 1e-5f;
}

// ---------------- distance-decay attention v2 ----------------
// 8 query rows per block; 256 threads = 8 groups x 32 lanes.
// K/V staged in LDS tiles of 64 rows; scores in swizzled LDS
// (addr = g*1056 + j + (j>>5)); softmax1/cumsum/effect/softmax2 in registers.
template<int DK, int DV, int MASKK, int ZP>
__global__ __launch_bounds__(256) void attn2_kernel(
    const float* __restrict__ QK, const float* __restrict__ Vv,
    const float* __restrict__ gamp, float* __restrict__ O, int S)
{
  const int DMK = NHEADS * DK, DMV = NHEADS * DV;
  const int DS = (DK > DV ? DK : DV);
  const int i0 = blockIdx.x * 8;
  const int b = blockIdx.y >> 3, h = blockIdx.y & 7;
  const int tid = threadIdx.x;
  const int g = tid >> 5;          // group 0..7 (query row)
  const int l = tid & 31;          // lane in group
  const int i = i0 + g;
  const int jmax = MASKK ? i : i - 1;
  const int jmaxBlk = MASKK ? (i0 + 7) : (i0 + 6);
  const int nT = jmaxBlk / 64 + 1;

  __shared__ float sc[8 * 1056];
  __shared__ float kv[64 * (DS + 1)];
  __shared__ float qs[8 * (DK + 1)];

  // load Q rows (coalesced)
  for (int idx = tid; idx < 8 * DK; idx += 256) {
    int r = idx / DK, d = idx % DK;
    qs[r * (DK + 1) + d] = QK[((size_t)(b * S + i0 + r)) * DMK + h * DK + d];
  }
  __syncthreads();

  // q into registers (LDS broadcast read within group)
  float qreg[DK];
  #pragma unroll
  for (int d = 0; d < DK; ++d) qreg[d] = qs[g * (DK + 1) + d];

  const float rscale = rsqrtf((float)DK);

  // ---- score tiles ----
  for (int t0 = 0; t0 < nT * 64; t0 += 64) {
    for (int idx = tid; idx < 64 * DK; idx += 256) {
      int r = idx / DK, d = idx % DK;
      kv[r * (DK + 1) + d] = QK[((size_t)(b * S + t0 + r)) * DMK + h * DK + d];
    }
    __syncthreads();
    float s0 = 0.f, s1 = 0.f;
    #pragma unroll
    for (int d = 0; d < DK; ++d) {
      s0 += qreg[d] * kv[l * (DK + 1) + d];
      s1 += qreg[d] * kv[(l + 32) * (DK + 1) + d];
    }
    int j0 = t0 + l, j1 = t0 + l + 32;
    sc[g * 1056 + j0 + (j0 >> 5)] = s0 * rscale;
    sc[g * 1056 + j1 + (j1 >> 5)] = s1 * rscale;
    __syncthreads();
  }

  // ---- in-register softmax pipeline; lane l owns j = 32*l + t ----
  const int jbase = 32 * l;
  const int sbase = g * 1056 + 33 * l;   // j + (j>>5) for this chunk

  float sreg[32];
  #pragma unroll
  for (int t = 0; t < 32; ++t) {
    int j = jbase + t;
    sreg[t] = (j <= jmax) ? sc[sbase + t] : -1e30f;
  }

  // softmax #1
  float m1 = -1e30f;
  #pragma unroll
  for (int t = 0; t < 32; ++t) m1 = fmaxf(m1, sreg[t]);
  #pragma unroll
  for (int o = 16; o > 0; o >>= 1) m1 = fmaxf(m1, __shfl_xor(m1, o, 32));
  float p[32];
  float l1 = 0.f;
  #pragma unroll
  for (int t = 0; t < 32; ++t) { p[t] = __expf(sreg[t] - m1); l1 += p[t]; }
  #pragma unroll
  for (int o = 16; o > 0; o >>= 1) l1 += __shfl_xor(l1, o, 32);
  float inv1 = 1.f / l1;

  // local inclusive prefix of probabilities
  float run = 0.f;
  #pragma unroll
  for (int t = 0; t < 32; ++t) { run += p[t] * inv1; p[t] = run; }
  // exclusive chunk offset across 32 lanes (inclusive shfl_up scan minus own)
  float scn = run;
  #pragma unroll
  for (int o = 1; o < 32; o <<= 1) {
    float u = __shfl_up(scn, o, 32);
    if (l >= o) scn += u;
  }
  float pre = scn - run;

  // distance effect (disttot == 1 for valid rows)
  float gv = gamp[h];
  float sp = fmaxf(gv, 0.f) + log1pf(__expf(-fabsf(gv)));
  float gm = -sp;
  #pragma unroll
  for (int t = 0; t < 32; ++t) {
    int j = jbase + t;
    float rem = fmaxf(1.f - (pre + p[t]), 0.f);
    float dist = sqrtf(rem * fabsf((float)(j - i)));
    float eff = __expf(gm * dist);
    eff = fminf(fmaxf(eff, 1e-5f), 1e5f);
    sreg[t] = sreg[t] * eff;   // masked entries stay <= -1e25 (eff >= 1e-5)
  }

  // softmax #2 -> weights, written back to swizzled LDS
  float m2 = -1e30f;
  #pragma unroll
  for (int t = 0; t < 32; ++t) m2 = fmaxf(m2, sreg[t]);
  #pragma unroll
  for (int o = 16; o > 0; o >>= 1) m2 = fmaxf(m2, __shfl_xor(m2, o, 32));
  float l2 = 0.f;
  #pragma unroll
  for (int t = 0; t < 32; ++t) { p[t] = __expf(sreg[t] - m2); l2 += p[t]; }
  #pragma unroll
  for (int o = 16; o > 0; o >>= 1) l2 += __shfl_xor(l2, o, 32);
  bool validrow = (jmax >= 0) && !(ZP && i == 0);
  float w = validrow ? (1.f / l2) : 0.f;
  __syncthreads();   // everyone done reading sc as scores
  #pragma unroll
  for (int t = 0; t < 32; ++t) sc[sbase + t] = p[t] * w;
  __syncthreads();

  // ---- PV over V tiles ----
  float acc0 = 0.f, acc1 = 0.f;
  for (int t0 = 0; t0 < nT * 64; t0 += 64) {
    for (int idx = tid; idx < 64 * DV; idx += 256) {
      int r = idx / DV, d = idx % DV;
      kv[r * (DV + 1) + d] = Vv[((size_t)(b * S + t0 + r)) * DMV + h * DV + d];
    }
    __syncthreads();
    #pragma unroll 8
    for (int jr = 0; jr < 64; ++jr) {
      int j = t0 + jr;
      float pj = sc[g * 1056 + j + (j >> 5)];
      acc0 += pj * kv[jr * (DV + 1) + l];
      if (DV == 64) acc1 += pj * kv[jr * (DV + 1) + l + 32];
    }
    __syncthreads();
  }

  float* orow = O + ((size_t)(b * S + i)) * DMV + h * DV;
  orow[l] = acc0;
  if (DV == 64) orow[l + 32] = acc1;
}

// ---------------- LayerNorm ----------------
__global__ __launch_bounds__(256) void ln_kernel(
    const float* __restrict__ X, const float* __restrict__ R,
    const float* __restrict__ g, const float* __restrict__ be,
    float* __restrict__ Y, int D)
{
  __shared__ float red[256];
  int row = blockIdx.x, tid = threadIdx.x;
  const float* x = X + (size_t)row * D;
  const float* r = R ? R + (size_t)row * D : nullptr;
  int ne = D >> 8;
  float xl[2];
  float s = 0.f;
  for (int e = 0; e < ne; ++e) {
    int j = tid + e * 256;
    float v = x[j] + (r ? r[j] : 0.f);
    xl[e] = v; s += v;
  }
  float mean = block_reduce_sum(s, red) / (float)D;
  float vs = 0.f;
  for (int e = 0; e < ne; ++e) { float dd = xl[e] - mean; vs += dd * dd; }
  float var = block_reduce_sum(vs, red) / (float)D;
  float rstd = rsqrtf(var + 1e-5f);
  for (int e = 0; e < ne; ++e) {
    int j = tid + e * 256;
    Y[(size_t)row * D + j] = g[j] * (xl[e] - mean) * rstd + be[j];
  }
}

// ---------------- concat ----------------
__global__ __launch_bounds__(256) void concat_kernel(
    const float* __restrict__ Xh, const float* __restrict__ Qe,
    float* __restrict__ Cc)
{
  int idx = blockIdx.x * 256 + threadIdx.x;
  if (idx >= 8192 * 512) return;
  int row = idx >> 9, c = idx & 511;
  Cc[(size_t)row * 512 + c] = (c < 256) ? Xh[(size_t)row * 256 + c]
                                        : Qe[(size_t)row * 256 + (c - 256)];
}

// ---------------- final row-dot ----------------
__global__ __launch_bounds__(256) void dot_kernel(
    const float* __restrict__ X, const float* __restrict__ w,
    const float* __restrict__ b, float* __restrict__ out)
{
  __shared__ float red[256];
  int row = blockIdx.x;
  float v = X[(size_t)row * 256 + threadIdx.x] * w[threadIdx.x];
  float s = block_reduce_sum(v, red);
  if (threadIdx.x == 0) out[row] = s + b[0];
}

// ---------------- launch ----------------
extern "C" void kernel_launch(void* const* d_in, const int* in_sizes, int n_in,
                              void* d_out, int out_size, void* d_ws, size_t ws_size,
                              hipStream_t stream) {
  const int* p_data  = (const int*)d_in[0];
  const int* pa_data = (const int*)d_in[1];
  const float* pemb_W = (const float*)d_in[3];
  const float* diff_W = (const float*)d_in[4];
  const float* qemb_W = (const float*)d_in[5];
  const float* qemb_b = (const float*)d_in[6];
  const float* y_kW = (const float*)d_in[7];   const float* y_kb = (const float*)d_in[8];
  const float* y_vW = (const float*)d_in[9];   const float* y_vb = (const float*)d_in[10];
  const float* y_oW = (const float*)d_in[11];  const float* y_ob = (const float*)d_in[12];
  const float* y_gam = (const float*)d_in[13];
  const float* y_ln1g = (const float*)d_in[14]; const float* y_ln1b = (const float*)d_in[15];
  const float* y_f1W = (const float*)d_in[16]; const float* y_f1b = (const float*)d_in[17];
  const float* y_f2W = (const float*)d_in[18]; const float* y_f2b = (const float*)d_in[19];
  const float* y_ln2g = (const float*)d_in[20]; const float* y_ln2b = (const float*)d_in[21];
  const float* x_kW = (const float*)d_in[22];  const float* x_kb = (const float*)d_in[23];
  const float* x_vW = (const float*)d_in[24];  const float* x_vb = (const float*)d_in[25];
  const float* x_oW = (const float*)d_in[26];  const float* x_ob = (const float*)d_in[27];
  const float* x_gam = (const float*)d_in[28];
  const float* x_ln1g = (const float*)d_in[29]; const float* x_ln1b = (const float*)d_in[30];
  const float* h_kW = (const float*)d_in[31];  const float* h_kb = (const float*)d_in[32];
  const float* h_vW = (const float*)d_in[33];  const float* h_vb = (const float*)d_in[34];
  const float* h_oW = (const float*)d_in[35];  const float* h_ob = (const float*)d_in[36];
  const float* h_gam = (const float*)d_in[37];
  const float* h_ln1g = (const float*)d_in[38]; const float* h_ln1b = (const float*)d_in[39];
  const float* h_f1W = (const float*)d_in[40]; const float* h_f1b = (const float*)d_in[41];
  const float* h_f2W = (const float*)d_in[42]; const float* h_f2b = (const float*)d_in[43];
  const float* h_ln2g = (const float*)d_in[44]; const float* h_ln2b = (const float*)d_in[45];
  const float* oln1g = (const float*)d_in[46]; const float* oln1b = (const float*)d_in[47];
  const float* o1W = (const float*)d_in[48];   const float* o1b = (const float*)d_in[49];
  const float* oln2g = (const float*)d_in[50]; const float* oln2b = (const float*)d_in[51];
  const float* o2W = (const float*)d_in[52];   const float* o2b = (const float*)d_in[53];
  const float* oln3g = (const float*)d_in[54]; const float* oln3b = (const float*)d_in[55];
  const float* o3W = (const float*)d_in[56];   const float* o3b = (const float*)d_in[57];

  float* out_f = (float*)d_out;

  const int B = 8, S = 1024, M = B * S;
  const int R = 4097, KQ = 1025;

  float* ws = (float*)d_ws;
  size_t off = 0;
  auto alloc = [&](size_t n) { size_t o = off; off += (n + 255) & ~(size_t)255; return o; };
  size_t oE    = alloc((size_t)R * 256);
  size_t oSIG  = alloc((size_t)R * KQ);
  size_t oSSUM = alloc(R);
  size_t oQE   = alloc((size_t)M * 256);
  size_t oQA   = alloc((size_t)M * 512);
  size_t oYO   = alloc((size_t)M * 512);
  size_t oXO   = alloc((size_t)M * 256);
  size_t oHO   = alloc((size_t)M * 256);
  size_t oS0   = alloc((size_t)M * 512);
  size_t oS1   = alloc((size_t)M * 512);
  size_t oS2   = alloc((size_t)M * 512);
  size_t oS3   = alloc((size_t)M * 512);
  size_t oS4   = alloc((size_t)M * 512);
  size_t oSX   = alloc((size_t)M * 512);
  (void)ws_size; (void)in_sizes; (void)n_in; (void)out_size;

  float* E    = ws + oE;
  float* SIG  = ws + oSIG;
  float* SSUM = ws + oSSUM;
  float* QE   = ws + oQE;
  float* QA   = ws + oQA;
  float* YO   = ws + oYO;
  float* XO   = ws + oXO;
  float* HO   = ws + oHO;
  float* S0   = ws + oS0;
  float* S1   = ws + oS1;
  float* S2   = ws + oS2;
  float* S3   = ws + oS3;
  float* S4   = ws + oS4;
  float* SX   = ws + oSX;
  float* FF   = S0;

  auto grid_of = [](int Mm, int Nn) { return dim3((unsigned)((Nn + 63) / 64), (unsigned)((Mm + 63) / 64)); };
  dim3 blk(256);
  int nElem512 = (8192 * 512 + 255) / 256;

  // 1. embedding table
  sig_kernel<<<R, blk, 0, stream>>>(pemb_W, SIG, SSUM, KQ);
  gemm_kernel<2><<<grid_of(R, 256), blk, 0, stream>>>(SIG, qemb_W, qemb_b, E, R, 256, KQ, SSUM);
  gather_kernel<<<nElem512, blk, 0, stream>>>(p_data, pa_data, E, diff_W, QE, QA);
  creg_kernel<<<1, blk, 0, stream>>>(p_data, diff_W, out_f + 8192);

  dim3 agrid(S / 8, B * NHEADS);

  // 2. y layer (dm=512, mask_k=1, zero_pad=0, FFN)
  gemm_kernel<0><<<grid_of(M, 512), blk, 0, stream>>>(QA, y_kW, y_kb, S0, M, 512, 512, nullptr);
  gemm_kernel<0><<<grid_of(M, 512), blk, 0, stream>>>(QA, y_vW, y_vb, S1, M, 512, 512, nullptr);
  attn2_kernel<64, 64, 1, 0><<<agrid, blk, 0, stream>>>(S0, S1, y_gam, S2, S);
  gemm_kernel<0><<<grid_of(M, 512), blk, 0, stream>>>(S2, y_oW, y_ob, S3, M, 512, 512, nullptr);
  ln_kernel<<<M, blk, 0, stream>>>(QA, S3, y_ln1g, y_ln1b, SX, 512);
  gemm_kernel<1><<<grid_of(M, 2048), blk, 0, stream>>>(SX, y_f1W, y_f1b, FF, M, 2048, 512, nullptr);
  gemm_kernel<0><<<grid_of(M, 512), blk, 0, stream>>>(FF, y_f2W, y_f2b, S4, M, 512, 2048, nullptr);
  ln_kernel<<<M, blk, 0, stream>>>(SX, S4, y_ln2g, y_ln2b, YO, 512);

  // 3. x layer (dm=256, mask_k=1, zero_pad=0, no FFN)
  gemm_kernel<0><<<grid_of(M, 256), blk, 0, stream>>>(QE, x_kW, x_kb, S0, M, 256, 256, nullptr);
  gemm_kernel<0><<<grid_of(M, 256), blk, 0, stream>>>(QE, x_vW, x_vb, S1, M, 256, 256, nullptr);
  attn2_kernel<32, 32, 1, 0><<<agrid, blk, 0, stream>>>(S0, S1, x_gam, S2, S);
  gemm_kernel<0><<<grid_of(M, 256), blk, 0, stream>>>(S2, x_oW, x_ob, S3, M, 256, 256, nullptr);
  ln_kernel<<<M, blk, 0, stream>>>(QE, S3, x_ln1g, x_ln1b, XO, 256);

  // 4. h layer (q,k from XO dm=256; v from YO dm=512; mask_k=0, zero_pad=1, FFN)
  gemm_kernel<0><<<grid_of(M, 256), blk, 0, stream>>>(XO, h_kW, h_kb, S0, M, 256, 256, nullptr);
  gemm_kernel<0><<<grid_of(M, 512), blk, 0, stream>>>(YO, h_vW, h_vb, S1, M, 512, 512, nullptr);
  attn2_kernel<32, 64, 0, 1><<<agrid, blk, 0, stream>>>(S0, S1, h_gam, S2, S);
  gemm_kernel<0><<<grid_of(M, 256), blk, 0, stream>>>(S2, h_oW, h_ob, S3, M, 256, 512, nullptr);
  ln_kernel<<<M, blk, 0, stream>>>(XO, S3, h_ln1g, h_ln1b, SX, 256);
  gemm_kernel<1><<<grid_of(M, 2048), blk, 0, stream>>>(SX, h_f1W, h_f1b, FF, M, 2048, 256, nullptr);
  gemm_kernel<0><<<grid_of(M, 256), blk, 0, stream>>>(FF, h_f2W, h_f2b, S4, M, 256, 2048, nullptr);
  ln_kernel<<<M, blk, 0, stream>>>(SX, S4, h_ln2g, h_ln2b, HO, 256);

  // 5. head
  concat_kernel<<<nElem512, blk, 0, stream>>>(HO, QE, S0);
  ln_kernel<<<M, blk, 0, stream>>>(S0, nullptr, oln1g, oln1b, S1, 512);
  gemm_kernel<1><<<grid_of(M, 512), blk, 0, stream>>>(S1, o1W, o1b, S2, M, 512, 512, nullptr);
  ln_kernel<<<M, blk, 0, stream>>>(S2, nullptr, oln2g, oln2b, S3, 512);
  gemm_kernel<1><<<grid_of(M, 256), blk, 0, stream>>>(S3, o2W, o2b, SX, M, 256, 512, nullptr);
  ln_kernel<<<M, blk, 0, stream>>>(SX, nullptr, oln3g, oln3b, S4, 256);
  dot_kernel<<<M, blk, 0, stream>>>(S4, o3W, o3b, out_f);
}

// Round 3
// 2389.727 us; speedup vs baseline: 4.2236x; 1.7557x over previous
//
#include <hip/hip_runtime.h>
#include <hip/hip_bf16.h>
#include <math.h>

#define NHEADS 8

typedef __attribute__((ext_vector_type(8))) __bf16 bfrag;
typedef __attribute__((ext_vector_type(4))) float f32x4;

static __device__ __forceinline__ unsigned short f2bf(float f) {
  unsigned u = __float_as_uint(f);
  unsigned r = (u + 0x7fffu + ((u >> 16) & 1u)) >> 16;
  return (unsigned short)r;
}

static __device__ __forceinline__ void gload_lds16(const void* g, void* l) {
  __builtin_amdgcn_global_load_lds(
      (const __attribute__((address_space(1))) unsigned int*)g,
      (__attribute__((address_space(3))) unsigned int*)l, 16, 0, 0);
}

static __device__ __forceinline__ float block_reduce_sum(float v, float* red) {
  int t = threadIdx.x;
  red[t] = v; __syncthreads();
  for (int s = 128; s > 0; s >>= 1) {
    if (t < s) red[t] += red[t + s];
    __syncthreads();
  }
  float r = red[0];
  __syncthreads();
  return r;
}

// ---------------- sigmoid table (bf16, padded to Kp) + row sums ----------------
__global__ __launch_bounds__(256) void sig_kernel(
    const float* __restrict__ Wp, unsigned short* __restrict__ Sgb,
    float* __restrict__ Ssum, int Kd, int Kp)
{
  __shared__ float red[256];
  int row = blockIdx.x;
  float s = 0.f;
  for (int k = threadIdx.x; k < Kp; k += 256) {
    float v = 0.f;
    if (k < Kd) {
      v = 1.f / (1.f + __expf(-Wp[(size_t)row * Kd + k]));
      s += v;
    }
    Sgb[(size_t)row * Kp + k] = f2bf(v);
  }
  float tot = block_reduce_sum(s, red);
  if (threadIdx.x == 0) Ssum[row] = tot;
}

// ---------------- transpose + convert: dst[n][k] = bf16(src[k][n]), K padded to Kp ----------------
__global__ __launch_bounds__(256) void tconv_kernel(
    const float* __restrict__ src, unsigned short* __restrict__ dst,
    int K, int N, int Kp)
{
  __shared__ float t[32][33];
  int tid = threadIdx.x;
  int tx = tid & 31, ty = tid >> 5;          // 32 x 8
  int bk = blockIdx.y * 32, bn = blockIdx.x * 32;
  #pragma unroll
  for (int u = 0; u < 4; ++u) {
    int k = bk + ty + u * 8, n = bn + tx;
    t[ty + u * 8][tx] = (k < K && n < N) ? src[(size_t)k * N + n] : 0.f;
  }
  __syncthreads();
  #pragma unroll
  for (int u = 0; u < 4; ++u) {
    int n = bn + ty + u * 8, kk = bk + tx;
    if (n < N && kk < Kp)
      dst[(size_t)n * Kp + kk] = f2bf(t[tx][ty + u * 8]);
  }
}

// ---------------- MFMA bf16 GEMM: C = epi(A @ Bt^T + bias) ----------------
// A [M][K] bf16, Bt [N][K] bf16 (pre-transposed weights). 128x128 tile, BK=32.
// EPI: 0 none, 1 relu, 2 relu + /divv[row]
template<int EPI, bool WBF>
__global__ __launch_bounds__(256) void mgemm_kernel(
    const unsigned short* __restrict__ A, const unsigned short* __restrict__ Bt,
    const float* __restrict__ bias, float* __restrict__ C,
    unsigned short* __restrict__ Cb,
    int M, int N, int K, const float* __restrict__ divv)
{
  __shared__ __align__(16) unsigned short Als[128 * 32];
  __shared__ __align__(16) unsigned short Bls[128 * 32];
  const int tid = threadIdx.x;
  const int lane = tid & 63, w = tid >> 6;
  const int wm = w >> 1, wn = w & 1;
  const int brow = blockIdx.y * 128, bcol = blockIdx.x * 128;

  f32x4 acc[4][4] = {};

  for (int k0 = 0; k0 < K; k0 += 32) {
    #pragma unroll
    for (int q = 0; q < 2; ++q) {
      int s = w * 128 + q * 64 + lane;
      int r = s >> 2, g = s & 3;
      int gs = g ^ (r & 3);                 // pre-swizzled source granule
      int gr = brow + r; if (gr > M - 1) gr = M - 1;
      gload_lds16(A + (size_t)gr * K + k0 + gs * 8,
                  (char*)Als + (w * 2048 + q * 1024));
      int gc = bcol + r; if (gc > N - 1) gc = N - 1;
      gload_lds16(Bt + (size_t)gc * K + k0 + gs * 8,
                  (char*)Bls + (w * 2048 + q * 1024));
    }
    __syncthreads();

    bfrag av[4], bv[4];
    #pragma unroll
    for (int f = 0; f < 4; ++f) {
      int rA = wm * 64 + f * 16 + (lane & 15);
      av[f] = *(const bfrag*)((const char*)Als + rA * 64 + ((((lane >> 4) ^ (rA & 3))) << 4));
      int rB = wn * 64 + f * 16 + (lane & 15);
      bv[f] = *(const bfrag*)((const char*)Bls + rB * 64 + ((((lane >> 4) ^ (rB & 3))) << 4));
    }
    #pragma unroll
    for (int i = 0; i < 4; ++i)
      #pragma unroll
      for (int j = 0; j < 4; ++j)
        acc[i][j] = __builtin_amdgcn_mfma_f32_16x16x32_bf16(av[i], bv[j], acc[i][j], 0, 0, 0);
    __syncthreads();
  }

  #pragma unroll
  for (int i = 0; i < 4; ++i) {
    int gr0 = brow + wm * 64 + i * 16 + (lane >> 4) * 4;
    #pragma unroll
    for (int j = 0; j < 4; ++j) {
      int gc = bcol + wn * 64 + j * 16 + (lane & 15);
      float bsv = bias ? bias[gc] : 0.f;
      #pragma unroll
      for (int q = 0; q < 4; ++q) {
        int gr = gr0 + q;
        if (gr >= M) continue;
        float v = acc[i][j][q] + bsv;
        if (EPI >= 1) v = fmaxf(v, 0.f);
        if (EPI == 2) v /= divv[gr];
        if (C)  C[(size_t)gr * N + gc] = v;
        if (WBF) Cb[(size_t)gr * N + gc] = f2bf(v);
      }
    }
  }
}

// ---------------- embedding gather (fp32 + bf16 outputs) ----------------
__global__ __launch_bounds__(256) void gather_kernel(
    const int* __restrict__ p_data, const int* __restrict__ pa_data,
    const float* __restrict__ E, const float* __restrict__ diff_W,
    float* __restrict__ qemb, unsigned short* __restrict__ qembb,
    float* __restrict__ qaemb, unsigned short* __restrict__ qaembb)
{
  int idx = blockIdx.x * 256 + threadIdx.x;
  if (idx >= 8192 * 512) return;
  int row = idx >> 9, c = idx & 511;
  int p = p_data[row];
  float pid = diff_W[p];
  if (c < 256) {
    float v = E[(size_t)p * 256 + c] + pid;
    qemb[(size_t)row * 256 + c] = v;
    qembb[(size_t)row * 256 + c] = f2bf(v);
  }
  int pa = pa_data[row];
  int ppos = (pa > 4096) ? pa - 4096 : 0;
  int pneg = (pa <= 4096) ? pa : 0;
  float v = (c < 256) ? E[(size_t)ppos * 256 + c] : E[(size_t)pneg * 256 + (c - 256)];
  v += pid;
  qaemb[(size_t)row * 512 + c] = v;
  qaembb[(size_t)row * 512 + c] = f2bf(v);
}

// ---------------- c_reg ----------------
__global__ __launch_bounds__(256) void creg_kernel(
    const int* __restrict__ p_data, const float* __restrict__ dW,
    float* __restrict__ out)
{
  __shared__ float red[256];
  float s = 0.f;
  for (int i = threadIdx.x; i < 8192; i += 256) {
    float v = dW[p_data[i]];
    s += v * v;
  }
  float tot = block_reduce_sum(s, red);
  if (threadIdx.x == 0) out[0] = tot * 1e-5f;
}

// ---------------- distance-decay attention v2 (fp32 math, bf16 out) ----------------
template<int DK, int DV, int MASKK, int ZP>
__global__ __launch_bounds__(256) void attn2_kernel(
    const float* __restrict__ QK, const float* __restrict__ Vv,
    const float* __restrict__ gamp, unsigned short* __restrict__ O, int S)
{
  const int DMK = NHEADS * DK, DMV = NHEADS * DV;
  const int DS = (DK > DV ? DK : DV);
  const int i0 = blockIdx.x * 8;
  const int b = blockIdx.y >> 3, h = blockIdx.y & 7;
  const int tid = threadIdx.x;
  const int g = tid >> 5;
  const int l = tid & 31;
  const int i = i0 + g;
  const int jmax = MASKK ? i : i - 1;
  const int jmaxBlk = MASKK ? (i0 + 7) : (i0 + 6);
  const int nT = jmaxBlk / 64 + 1;

  __shared__ float sc[8 * 1056];
  __shared__ float kv[64 * (DS + 1)];
  __shared__ float qs[8 * (DK + 1)];

  for (int idx = tid; idx < 8 * DK; idx += 256) {
    int r = idx / DK, d = idx % DK;
    qs[r * (DK + 1) + d] = QK[((size_t)(b * S + i0 + r)) * DMK + h * DK + d];
  }
  __syncthreads();

  float qreg[DK];
  #pragma unroll
  for (int d = 0; d < DK; ++d) qreg[d] = qs[g * (DK + 1) + d];

  const float rscale = rsqrtf((float)DK);

  for (int t0 = 0; t0 < nT * 64; t0 += 64) {
    for (int idx = tid; idx < 64 * DK; idx += 256) {
      int r = idx / DK, d = idx % DK;
      kv[r * (DK + 1) + d] = QK[((size_t)(b * S + t0 + r)) * DMK + h * DK + d];
    }
    __syncthreads();
    float s0 = 0.f, s1 = 0.f;
    #pragma unroll
    for (int d = 0; d < DK; ++d) {
      s0 += qreg[d] * kv[l * (DK + 1) + d];
      s1 += qreg[d] * kv[(l + 32) * (DK + 1) + d];
    }
    int j0 = t0 + l, j1 = t0 + l + 32;
    sc[g * 1056 + j0 + (j0 >> 5)] = s0 * rscale;
    sc[g * 1056 + j1 + (j1 >> 5)] = s1 * rscale;
    __syncthreads();
  }

  const int jbase = 32 * l;
  const int sbase = g * 1056 + 33 * l;

  float sreg[32];
  #pragma unroll
  for (int t = 0; t < 32; ++t) {
    int j = jbase + t;
    sreg[t] = (j <= jmax) ? sc[sbase + t] : -1e30f;
  }

  float m1 = -1e30f;
  #pragma unroll
  for (int t = 0; t < 32; ++t) m1 = fmaxf(m1, sreg[t]);
  #pragma unroll
  for (int o = 16; o > 0; o >>= 1) m1 = fmaxf(m1, __shfl_xor(m1, o, 32));
  float p[32];
  float l1 = 0.f;
  #pragma unroll
  for (int t = 0; t < 32; ++t) { p[t] = __expf(sreg[t] - m1); l1 += p[t]; }
  #pragma unroll
  for (int o = 16; o > 0; o >>= 1) l1 += __shfl_xor(l1, o, 32);
  float inv1 = 1.f / l1;

  float run = 0.f;
  #pragma unroll
  for (int t = 0; t < 32; ++t) { run += p[t] * inv1; p[t] = run; }
  float scn = run;
  #pragma unroll
  for (int o = 1; o < 32; o <<= 1) {
    float u = __shfl_up(scn, o, 32);
    if (l >= o) scn += u;
  }
  float pre = scn - run;

  float gv = gamp[h];
  float sp = fmaxf(gv, 0.f) + log1pf(__expf(-fabsf(gv)));
  float gm = -sp;
  #pragma unroll
  for (int t = 0; t < 32; ++t) {
    int j = jbase + t;
    float rem = fmaxf(1.f - (pre + p[t]), 0.f);
    float dist = sqrtf(rem * fabsf((float)(j - i)));
    float eff = __expf(gm * dist);
    eff = fminf(fmaxf(eff, 1e-5f), 1e5f);
    sreg[t] = sreg[t] * eff;
  }

  float m2 = -1e30f;
  #pragma unroll
  for (int t = 0; t < 32; ++t) m2 = fmaxf(m2, sreg[t]);
  #pragma unroll
  for (int o = 16; o > 0; o >>= 1) m2 = fmaxf(m2, __shfl_xor(m2, o, 32));
  float l2 = 0.f;
  #pragma unroll
  for (int t = 0; t < 32; ++t) { p[t] = __expf(sreg[t] - m2); l2 += p[t]; }
  #pragma unroll
  for (int o = 16; o > 0; o >>= 1) l2 += __shfl_xor(l2, o, 32);
  bool validrow = (jmax >= 0) && !(ZP && i == 0);
  float wgt = validrow ? (1.f / l2) : 0.f;
  __syncthreads();
  #pragma unroll
  for (int t = 0; t < 32; ++t) sc[sbase + t] = p[t] * wgt;
  __syncthreads();

  float acc0 = 0.f, acc1 = 0.f;
  for (int t0 = 0; t0 < nT * 64; t0 += 64) {
    for (int idx = tid; idx < 64 * DV; idx += 256) {
      int r = idx / DV, d = idx % DV;
      kv[r * (DV + 1) + d] = Vv[((size_t)(b * S + t0 + r)) * DMV + h * DV + d];
    }
    __syncthreads();
    #pragma unroll 8
    for (int jr = 0; jr < 64; ++jr) {
      int j = t0 + jr;
      float pj = sc[g * 1056 + j + (j >> 5)];
      acc0 += pj * kv[jr * (DV + 1) + l];
      if (DV == 64) acc1 += pj * kv[jr * (DV + 1) + l + 32];
    }
    __syncthreads();
  }

  unsigned short* orow = O + ((size_t)(b * S + i)) * DMV + h * DV;
  orow[l] = f2bf(acc0);
  if (DV == 64) orow[l + 32] = f2bf(acc1);
}

// ---------------- LayerNorm (optional fp32 / bf16 outputs) ----------------
__global__ __launch_bounds__(256) void ln_kernel(
    const float* __restrict__ X, const float* __restrict__ R,
    const float* __restrict__ g, const float* __restrict__ be,
    float* __restrict__ Y, unsigned short* __restrict__ Yb, int D)
{
  __shared__ float red[256];
  int row = blockIdx.x, tid = threadIdx.x;
  const float* x = X + (size_t)row * D;
  const float* r = R ? R + (size_t)row * D : nullptr;
  int ne = D >> 8;
  float xl[2];
  float s = 0.f;
  for (int e = 0; e < ne; ++e) {
    int j = tid + e * 256;
    float v = x[j] + (r ? r[j] : 0.f);
    xl[e] = v; s += v;
  }
  float mean = block_reduce_sum(s, red) / (float)D;
  float vs = 0.f;
  for (int e = 0; e < ne; ++e) { float dd = xl[e] - mean; vs += dd * dd; }
  float var = block_reduce_sum(vs, red) / (float)D;
  float rstd = rsqrtf(var + 1e-5f);
  for (int e = 0; e < ne; ++e) {
    int j = tid + e * 256;
    float v = g[j] * (xl[e] - mean) * rstd + be[j];
    if (Y)  Y[(size_t)row * D + j] = v;
    if (Yb) Yb[(size_t)row * D + j] = f2bf(v);
  }
}

// ---------------- concat ----------------
__global__ __launch_bounds__(256) void concat_kernel(
    const float* __restrict__ Xh, const float* __restrict__ Qe,
    float* __restrict__ Cc)
{
  int idx = blockIdx.x * 256 + threadIdx.x;
  if (idx >= 8192 * 512) return;
  int row = idx >> 9, c = idx & 511;
  Cc[(size_t)row * 512 + c] = (c < 256) ? Xh[(size_t)row * 256 + c]
                                        : Qe[(size_t)row * 256 + (c - 256)];
}

// ---------------- final row-dot ----------------
__global__ __launch_bounds__(256) void dot_kernel(
    const float* __restrict__ X, const float* __restrict__ w,
    const float* __restrict__ b, float* __restrict__ out)
{
  __shared__ float red[256];
  int row = blockIdx.x;
  float v = X[(size_t)row * 256 + threadIdx.x] * w[threadIdx.x];
  float s = block_reduce_sum(v, red);
  if (threadIdx.x == 0) out[row] = s + b[0];
}

// ---------------- launch ----------------
extern "C" void kernel_launch(void* const* d_in, const int* in_sizes, int n_in,
                              void* d_out, int out_size, void* d_ws, size_t ws_size,
                              hipStream_t stream) {
  const int* p_data  = (const int*)d_in[0];
  const int* pa_data = (const int*)d_in[1];
  const float* pemb_W = (const float*)d_in[3];
  const float* diff_W = (const float*)d_in[4];
  const float* qemb_W = (const float*)d_in[5];
  const float* qemb_b = (const float*)d_in[6];
  const float* y_kW = (const float*)d_in[7];   const float* y_kb = (const float*)d_in[8];
  const float* y_vW = (const float*)d_in[9];   const float* y_vb = (const float*)d_in[10];
  const float* y_oW = (const float*)d_in[11];  const float* y_ob = (const float*)d_in[12];
  const float* y_gam = (const float*)d_in[13];
  const float* y_ln1g = (const float*)d_in[14]; const float* y_ln1b = (const float*)d_in[15];
  const float* y_f1W = (const float*)d_in[16]; const float* y_f1b = (const float*)d_in[17];
  const float* y_f2W = (const float*)d_in[18]; const float* y_f2b = (const float*)d_in[19];
  const float* y_ln2g = (const float*)d_in[20]; const float* y_ln2b = (const float*)d_in[21];
  const float* x_kW = (const float*)d_in[22];  const float* x_kb = (const float*)d_in[23];
  const float* x_vW = (const float*)d_in[24];  const float* x_vb = (const float*)d_in[25];
  const float* x_oW = (const float*)d_in[26];  const float* x_ob = (const float*)d_in[27];
  const float* x_gam = (const float*)d_in[28];
  const float* x_ln1g = (const float*)d_in[29]; const float* x_ln1b = (const float*)d_in[30];
  const float* h_kW = (const float*)d_in[31];  const float* h_kb = (const float*)d_in[32];
  const float* h_vW = (const float*)d_in[33];  const float* h_vb = (const float*)d_in[34];
  const float* h_oW = (const float*)d_in[35];  const float* h_ob = (const float*)d_in[36];
  const float* h_gam = (const float*)d_in[37];
  const float* h_ln1g = (const float*)d_in[38]; const float* h_ln1b = (const float*)d_in[39];
  const float* h_f1W = (const float*)d_in[40]; const float* h_f1b = (const float*)d_in[41];
  const float* h_f2W = (const float*)d_in[42]; const float* h_f2b = (const float*)d_in[43];
  const float* h_ln2g = (const float*)d_in[44]; const float* h_ln2b = (const float*)d_in[45];
  const float* oln1g = (const float*)d_in[46]; const float* oln1b = (const float*)d_in[47];
  const float* o1W = (const float*)d_in[48];   const float* o1b = (const float*)d_in[49];
  const float* oln2g = (const float*)d_in[50]; const float* oln2b = (const float*)d_in[51];
  const float* o2W = (const float*)d_in[52];   const float* o2b = (const float*)d_in[53];
  const float* oln3g = (const float*)d_in[54]; const float* oln3b = (const float*)d_in[55];
  const float* o3W = (const float*)d_in[56];   const float* o3b = (const float*)d_in[57];

  float* out_f = (float*)d_out;

  const int B = 8, S = 1024, M = B * S;
  const int R = 4097, KQ = 1025, KQP = 1056;

  float* ws = (float*)d_ws;
  size_t off = 0;
  auto alloc = [&](size_t nfloats) { size_t o = off; off += (nfloats + 255) & ~(size_t)255; return o; };
  auto allocs = [&](size_t nshorts) { return alloc((nshorts + 1) / 2); };

  size_t oE    = alloc((size_t)R * 256);
  size_t oSIGb = allocs((size_t)R * KQP);
  size_t oSSUM = alloc(R);
  size_t oQE   = alloc((size_t)M * 256);
  size_t oQEb  = allocs((size_t)M * 256);
  size_t oQA   = alloc((size_t)M * 512);
  size_t oQAb  = allocs((size_t)M * 512);
  size_t oYOb  = allocs((size_t)M * 512);
  size_t oXO   = alloc((size_t)M * 256);
  size_t oXOb  = allocs((size_t)M * 256);
  size_t oHO   = alloc((size_t)M * 256);
  size_t oS0   = alloc((size_t)M * 512);   // also FFb arena start (S0+S1)
  size_t oS1   = alloc((size_t)M * 512);
  size_t oS2b  = allocs((size_t)M * 512);
  size_t oS3   = alloc((size_t)M * 512);
  size_t oS4   = alloc((size_t)M * 512);
  size_t oSX   = alloc((size_t)M * 512);
  size_t oSXb  = allocs((size_t)M * 512);
  // bf16 transposed weights
  size_t oWqe  = allocs((size_t)256 * KQP);
  size_t oWyk  = allocs((size_t)512 * 512);
  size_t oWyv  = allocs((size_t)512 * 512);
  size_t oWyo  = allocs((size_t)512 * 512);
  size_t oWyf1 = allocs((size_t)2048 * 512);
  size_t oWyf2 = allocs((size_t)512 * 2048);
  size_t oWxk  = allocs((size_t)256 * 256);
  size_t oWxv  = allocs((size_t)256 * 256);
  size_t oWxo  = allocs((size_t)256 * 256);
  size_t oWhk  = allocs((size_t)256 * 256);
  size_t oWhv  = allocs((size_t)512 * 512);
  size_t oWho  = allocs((size_t)256 * 512);
  size_t oWhf1 = allocs((size_t)2048 * 256);
  size_t oWhf2 = allocs((size_t)256 * 2048);
  size_t oWo1  = allocs((size_t)512 * 512);
  size_t oWo2  = allocs((size_t)256 * 512);
  (void)ws_size; (void)in_sizes; (void)n_in; (void)out_size;

  float* E    = ws + oE;
  unsigned short* SIGb = (unsigned short*)(ws + oSIGb);
  float* SSUM = ws + oSSUM;
  float* QE   = ws + oQE;   unsigned short* QEb = (unsigned short*)(ws + oQEb);
  float* QA   = ws + oQA;   unsigned short* QAb = (unsigned short*)(ws + oQAb);
  unsigned short* YOb = (unsigned short*)(ws + oYOb);
  float* XO   = ws + oXO;   unsigned short* XOb = (unsigned short*)(ws + oXOb);
  float* HO   = ws + oHO;
  float* S0   = ws + oS0;
  float* S1   = ws + oS1;
  unsigned short* S2b = (unsigned short*)(ws + oS2b);
  float* S3   = ws + oS3;
  float* S4   = ws + oS4;
  float* SX   = ws + oSX;   unsigned short* SXb = (unsigned short*)(ws + oSXb);
  unsigned short* FFb = (unsigned short*)S0;  // [8192][2048] bf16 aliases S0+S1

  unsigned short* Wqe  = (unsigned short*)(ws + oWqe);
  unsigned short* Wyk  = (unsigned short*)(ws + oWyk);
  unsigned short* Wyv  = (unsigned short*)(ws + oWyv);
  unsigned short* Wyo  = (unsigned short*)(ws + oWyo);
  unsigned short* Wyf1 = (unsigned short*)(ws + oWyf1);
  unsigned short* Wyf2 = (unsigned short*)(ws + oWyf2);
  unsigned short* Wxk  = (unsigned short*)(ws + oWxk);
  unsigned short* Wxv  = (unsigned short*)(ws + oWxv);
  unsigned short* Wxo  = (unsigned short*)(ws + oWxo);
  unsigned short* Whk  = (unsigned short*)(ws + oWhk);
  unsigned short* Whv  = (unsigned short*)(ws + oWhv);
  unsigned short* Who  = (unsigned short*)(ws + oWho);
  unsigned short* Whf1 = (unsigned short*)(ws + oWhf1);
  unsigned short* Whf2 = (unsigned short*)(ws + oWhf2);
  unsigned short* Wo1  = (unsigned short*)(ws + oWo1);
  unsigned short* Wo2  = (unsigned short*)(ws + oWo2);

  dim3 blk(256);
  int nElem512 = (8192 * 512 + 255) / 256;

  // ---- weight transposes (fp32 [K][N] -> bf16 [N][Kp]) ----
  struct TD { const float* src; unsigned short* dst; int K, N, Kp; };
  const TD tds[] = {
    {qemb_W, Wqe, KQ, 256, KQP},
    {y_kW, Wyk, 512, 512, 512}, {y_vW, Wyv, 512, 512, 512}, {y_oW, Wyo, 512, 512, 512},
    {y_f1W, Wyf1, 512, 2048, 512}, {y_f2W, Wyf2, 2048, 512, 2048},
    {x_kW, Wxk, 256, 256, 256}, {x_vW, Wxv, 256, 256, 256}, {x_oW, Wxo, 256, 256, 256},
    {h_kW, Whk, 256, 256, 256}, {h_vW, Whv, 512, 512, 512}, {h_oW, Who, 512, 256, 512},
    {h_f1W, Whf1, 256, 2048, 256}, {h_f2W, Whf2, 2048, 256, 2048},
    {o1W, Wo1, 512, 512, 512}, {o2W, Wo2, 512, 256, 512},
  };
  for (const TD& t : tds) {
    dim3 g((t.N + 31) / 32, (t.Kp + 31) / 32);
    tconv_kernel<<<g, blk, 0, stream>>>(t.src, t.dst, t.K, t.N, t.Kp);
  }

  auto ggrid = [](int Mm, int Nn) { return dim3((unsigned)(Nn / 128), (unsigned)((Mm + 127) / 128)); };

  // 1. embedding table
  sig_kernel<<<R, blk, 0, stream>>>(pemb_W, SIGb, SSUM, KQ, KQP);
  mgemm_kernel<2, false><<<ggrid(R, 256), blk, 0, stream>>>(SIGb, Wqe, qemb_b, E, nullptr, R, 256, KQP, SSUM);
  gather_kernel<<<nElem512, blk, 0, stream>>>(p_data, pa_data, E, diff_W, QE, QEb, QA, QAb);
  creg_kernel<<<1, blk, 0, stream>>>(p_data, diff_W, out_f + 8192);

  dim3 agrid(S / 8, B * NHEADS);

  // 2. y layer (dm=512, mask_k=1, zero_pad=0, FFN)
  mgemm_kernel<0, false><<<ggrid(M, 512), blk, 0, stream>>>(QAb, Wyk, y_kb, S0, nullptr, M, 512, 512, nullptr);
  mgemm_kernel<0, false><<<ggrid(M, 512), blk, 0, stream>>>(QAb, Wyv, y_vb, S1, nullptr, M, 512, 512, nullptr);
  attn2_kernel<64, 64, 1, 0><<<agrid, blk, 0, stream>>>(S0, S1, y_gam, S2b, S);
  mgemm_kernel<0, false><<<ggrid(M, 512), blk, 0, stream>>>(S2b, Wyo, y_ob, S3, nullptr, M, 512, 512, nullptr);
  ln_kernel<<<M, blk, 0, stream>>>(QA, S3, y_ln1g, y_ln1b, SX, SXb, 512);
  mgemm_kernel<1, true><<<ggrid(M, 2048), blk, 0, stream>>>(SXb, Wyf1, y_f1b, nullptr, FFb, M, 2048, 512, nullptr);
  mgemm_kernel<0, false><<<ggrid(M, 512), blk, 0, stream>>>(FFb, Wyf2, y_f2b, S4, nullptr, M, 512, 2048, nullptr);
  ln_kernel<<<M, blk, 0, stream>>>(SX, S4, y_ln2g, y_ln2b, nullptr, YOb, 512);

  // 3. x layer (dm=256, mask_k=1, zero_pad=0, no FFN)
  mgemm_kernel<0, false><<<ggrid(M, 256), blk, 0, stream>>>(QEb, Wxk, x_kb, S0, nullptr, M, 256, 256, nullptr);
  mgemm_kernel<0, false><<<ggrid(M, 256), blk, 0, stream>>>(QEb, Wxv, x_vb, S1, nullptr, M, 256, 256, nullptr);
  attn2_kernel<32, 32, 1, 0><<<agrid, blk, 0, stream>>>(S0, S1, x_gam, S2b, S);
  mgemm_kernel<0, false><<<ggrid(M, 256), blk, 0, stream>>>(S2b, Wxo, x_ob, S3, nullptr, M, 256, 256, nullptr);
  ln_kernel<<<M, blk, 0, stream>>>(QE, S3, x_ln1g, x_ln1b, XO, XOb, 256);

  // 4. h layer (q,k from XO; v from YO; mask_k=0, zero_pad=1, FFN)
  mgemm_kernel<0, false><<<ggrid(M, 256), blk, 0, stream>>>(XOb, Whk, h_kb, S0, nullptr, M, 256, 256, nullptr);
  mgemm_kernel<0, false><<<ggrid(M, 512), blk, 0, stream>>>(YOb, Whv, h_vb, S1, nullptr, M, 512, 512, nullptr);
  attn2_kernel<32, 64, 0, 1><<<agrid, blk, 0, stream>>>(S0, S1, h_gam, S2b, S);
  mgemm_kernel<0, false><<<ggrid(M, 256), blk, 0, stream>>>(S2b, Who, h_ob, S3, nullptr, M, 256, 512, nullptr);
  ln_kernel<<<M, blk, 0, stream>>>(XO, S3, h_ln1g, h_ln1b, SX, SXb, 256);
  mgemm_kernel<1, true><<<ggrid(M, 2048), blk, 0, stream>>>(SXb, Whf1, h_f1b, nullptr, FFb, M, 2048, 256, nullptr);
  mgemm_kernel<0, false><<<ggrid(M, 256), blk, 0, stream>>>(FFb, Whf2, h_f2b, S4, nullptr, M, 256, 2048, nullptr);
  ln_kernel<<<M, blk, 0, stream>>>(SX, S4, h_ln2g, h_ln2b, HO, nullptr, 256);

  // 5. head
  concat_kernel<<<nElem512, blk, 0, stream>>>(HO, QE, S3);
  ln_kernel<<<M, blk, 0, stream>>>(S3, nullptr, oln1g, oln1b, nullptr, SXb, 512);
  mgemm_kernel<1, false><<<ggrid(M, 512), blk, 0, stream>>>(SXb, Wo1, o1b, S3, nullptr, M, 512, 512, nullptr);
  ln_kernel<<<M, blk, 0, stream>>>(S3, nullptr, oln2g, oln2b, nullptr, SXb, 512);
  mgemm_kernel<1, false><<<ggrid(M, 256), blk, 0, stream>>>(SXb, Wo2, o2b, S4, nullptr, M, 256, 512, nullptr);
  ln_kernel<<<M, blk, 0, stream>>>(S4, nullptr, oln3g, oln3b, SX, nullptr, 256);
  dot_kernel<<<M, blk, 0, stream>>>(SX, o3W, o3b, out_f);
}

// Round 4
// 1117.357 us; speedup vs baseline: 9.0331x; 2.1387x over previous
//
#include <hip/hip_runtime.h>
#include <hip/hip_bf16.h>
#include <math.h>

#define NHEADS 8

typedef __attribute__((ext_vector_type(8))) __bf16 bfrag;
typedef __attribute__((ext_vector_type(4))) float f32x4;

static __device__ __forceinline__ unsigned short f2bf(float f) {
  unsigned u = __float_as_uint(f);
  unsigned r = (u + 0x7fffu + ((u >> 16) & 1u)) >> 16;
  return (unsigned short)r;
}

static __device__ __forceinline__ void gload_lds16(const void* g, void* l) {
  __builtin_amdgcn_global_load_lds(
      (const __attribute__((address_space(1))) unsigned int*)g,
      (__attribute__((address_space(3))) unsigned int*)l, 16, 0, 0);
}

static __device__ __forceinline__ float block_reduce_sum(float v, float* red) {
  int t = threadIdx.x;
  red[t] = v; __syncthreads();
  for (int s = 128; s > 0; s >>= 1) {
    if (t < s) red[t] += red[t + s];
    __syncthreads();
  }
  float r = red[0];
  __syncthreads();
  return r;
}

// ---------------- sigmoid table (bf16, padded to Kp) + row sums ----------------
__global__ __launch_bounds__(256) void sig_kernel(
    const float* __restrict__ Wp, unsigned short* __restrict__ Sgb,
    float* __restrict__ Ssum, int Kd, int Kp)
{
  __shared__ float red[256];
  int row = blockIdx.x;
  float s = 0.f;
  for (int k = threadIdx.x; k < Kp; k += 256) {
    float v = 0.f;
    if (k < Kd) {
      v = 1.f / (1.f + __expf(-Wp[(size_t)row * Kd + k]));
      s += v;
    }
    Sgb[(size_t)row * Kp + k] = f2bf(v);
  }
  float tot = block_reduce_sum(s, red);
  if (threadIdx.x == 0) Ssum[row] = tot;
}

// ---------------- transpose + convert: dst[n][k] = bf16(src[k][n]) ----------------
__global__ __launch_bounds__(256) void tconv_kernel(
    const float* __restrict__ src, unsigned short* __restrict__ dst,
    int K, int N, int Kp)
{
  __shared__ float t[32][33];
  int tid = threadIdx.x;
  int tx = tid & 31, ty = tid >> 5;
  int bk = blockIdx.y * 32, bn = blockIdx.x * 32;
  #pragma unroll
  for (int u = 0; u < 4; ++u) {
    int k = bk + ty + u * 8, n = bn + tx;
    t[ty + u * 8][tx] = (k < K && n < N) ? src[(size_t)k * N + n] : 0.f;
  }
  __syncthreads();
  #pragma unroll
  for (int u = 0; u < 4; ++u) {
    int n = bn + ty + u * 8, kk = bk + tx;
    if (n < N && kk < Kp)
      dst[(size_t)n * Kp + kk] = f2bf(t[tx][ty + u * 8]);
  }
}

// ---------------- MFMA bf16 GEMM: C = epi(A @ Bt^T + bias) ----------------
// Outputs: WF32 -> C fp32 [M][N]; WBF -> Cb bf16 [M][N]; WTR -> Ct bf16 [N][M] (M%128==0)
template<int EPI, bool WF32, bool WBF, bool WTR>
__global__ __launch_bounds__(256) void mgemm_kernel(
    const unsigned short* __restrict__ A, const unsigned short* __restrict__ Bt,
    const float* __restrict__ bias, float* __restrict__ C,
    unsigned short* __restrict__ Cb, unsigned short* __restrict__ Ct,
    int M, int N, int K, const float* __restrict__ divv)
{
  __shared__ __align__(16) unsigned short Als[128 * 32];
  __shared__ __align__(16) unsigned short Bls[128 * 32];
  const int tid = threadIdx.x;
  const int lane = tid & 63, w = tid >> 6;
  const int wm = w >> 1, wn = w & 1;
  const int brow = blockIdx.y * 128, bcol = blockIdx.x * 128;

  f32x4 acc[4][4] = {};

  for (int k0 = 0; k0 < K; k0 += 32) {
    #pragma unroll
    for (int q = 0; q < 2; ++q) {
      int s = w * 128 + q * 64 + lane;
      int r = s >> 2, g = s & 3;
      int gs = g ^ (r & 3);
      int gr = brow + r; if (gr > M - 1) gr = M - 1;
      gload_lds16(A + (size_t)gr * K + k0 + gs * 8,
                  (char*)Als + (w * 2048 + q * 1024));
      int gc = bcol + r; if (gc > N - 1) gc = N - 1;
      gload_lds16(Bt + (size_t)gc * K + k0 + gs * 8,
                  (char*)Bls + (w * 2048 + q * 1024));
    }
    __syncthreads();

    bfrag av[4], bv[4];
    #pragma unroll
    for (int f = 0; f < 4; ++f) {
      int rA = wm * 64 + f * 16 + (lane & 15);
      av[f] = *(const bfrag*)((const char*)Als + rA * 64 + ((((lane >> 4) ^ (rA & 3))) << 4));
      int rB = wn * 64 + f * 16 + (lane & 15);
      bv[f] = *(const bfrag*)((const char*)Bls + rB * 64 + ((((lane >> 4) ^ (rB & 3))) << 4));
    }
    #pragma unroll
    for (int i = 0; i < 4; ++i)
      #pragma unroll
      for (int j = 0; j < 4; ++j)
        acc[i][j] = __builtin_amdgcn_mfma_f32_16x16x32_bf16(av[i], bv[j], acc[i][j], 0, 0, 0);
    __syncthreads();
  }

  #pragma unroll
  for (int i = 0; i < 4; ++i) {
    int gr0 = brow + wm * 64 + i * 16 + (lane >> 4) * 4;
    #pragma unroll
    for (int j = 0; j < 4; ++j) {
      int gc = bcol + wn * 64 + j * 16 + (lane & 15);
      float bsv = bias ? bias[gc] : 0.f;
      float vv[4];
      #pragma unroll
      for (int q = 0; q < 4; ++q) {
        int gr = gr0 + q;
        float v = acc[i][j][q] + bsv;
        if (EPI >= 1) v = fmaxf(v, 0.f);
        if (EPI == 2) v = (gr < M) ? v / divv[gr] : v;
        vv[q] = v;
      }
      #pragma unroll
      for (int q = 0; q < 4; ++q) {
        int gr = gr0 + q;
        if (gr >= M) continue;
        if (WF32) C[(size_t)gr * N + gc] = vv[q];
        if (WBF)  Cb[(size_t)gr * N + gc] = f2bf(vv[q]);
      }
      if (WTR) {
        ushort4 h4 = { f2bf(vv[0]), f2bf(vv[1]), f2bf(vv[2]), f2bf(vv[3]) };
        *(ushort4*)(Ct + (size_t)gc * M + gr0) = h4;
      }
    }
  }
}

// ---------------- embedding gather ----------------
__global__ __launch_bounds__(256) void gather_kernel(
    const int* __restrict__ p_data, const int* __restrict__ pa_data,
    const float* __restrict__ E, const float* __restrict__ diff_W,
    float* __restrict__ qemb, unsigned short* __restrict__ qembb,
    float* __restrict__ qaemb, unsigned short* __restrict__ qaembb)
{
  int idx = blockIdx.x * 256 + threadIdx.x;
  if (idx >= 8192 * 512) return;
  int row = idx >> 9, c = idx & 511;
  int p = p_data[row];
  float pid = diff_W[p];
  if (c < 256) {
    float v = E[(size_t)p * 256 + c] + pid;
    qemb[(size_t)row * 256 + c] = v;
    qembb[(size_t)row * 256 + c] = f2bf(v);
  }
  int pa = pa_data[row];
  int ppos = (pa > 4096) ? pa - 4096 : 0;
  int pneg = (pa <= 4096) ? pa : 0;
  float v = (c < 256) ? E[(size_t)ppos * 256 + c] : E[(size_t)pneg * 256 + (c - 256)];
  v += pid;
  qaemb[(size_t)row * 512 + c] = v;
  qaembb[(size_t)row * 512 + c] = f2bf(v);
}

// ---------------- c_reg ----------------
__global__ __launch_bounds__(256) void creg_kernel(
    const int* __restrict__ p_data, const float* __restrict__ dW,
    float* __restrict__ out)
{
  __shared__ float red[256];
  float s = 0.f;
  for (int i = threadIdx.x; i < 8192; i += 256) {
    float v = dW[p_data[i]];
    s += v * v;
  }
  float tot = block_reduce_sum(s, red);
  if (threadIdx.x == 0) out[0] = tot * 1e-5f;
}

// ---------------- MFMA distance-decay attention ----------------
// QKb: bf16 [B*S][H*DK]; Vt: bf16 [H*DV][MT]; O: bf16 [B*S][H*DV]
// 8 query rows per block, 4 waves. Scores in swizzled LDS: a(r,j)=r*1156+j+4*(j>>5).
template<int DK, int DV, int MASKK, int ZP>
__global__ __launch_bounds__(256) void attn3_kernel(
    const unsigned short* __restrict__ QKb, const unsigned short* __restrict__ Vt,
    const float* __restrict__ gamp, unsigned short* __restrict__ O,
    int S, int MT)
{
  const int DMK = NHEADS * DK, DMV = NHEADS * DV;
  const int i0 = blockIdx.x * 8;
  const int b = blockIdx.y >> 3, h = blockIdx.y & 7;
  const int tid = threadIdx.x;
  const int lane = tid & 63, w = tid >> 6;
  const size_t rowbase = (size_t)b * S;

  __shared__ __align__(16) float sc[8 * 1156];
  __shared__ float pvred[(DV == 32) ? 2 * 16 * 17 : 1];

  const int jmaxBlk = MASKK ? (i0 + 7) : (i0 + 6);
  const int nT = jmaxBlk / 64 + 1;

  // ---- Q A-fragments (row = lane&15 clamped to 0..7, k-octet = lane>>4) ----
  const int qr = (lane & 15) < 8 ? (lane & 15) : 7;
  const int ko = (lane >> 4) * 8;
  bfrag qf[DK / 32];
  #pragma unroll
  for (int ks = 0; ks < DK / 32; ++ks)
    qf[ks] = *(const bfrag*)(QKb + (rowbase + i0 + qr) * DMK + h * DK + ks * 32 + ko);

  // ---- QK^T: wave w owns j-block w*16 within each 64-key tile ----
  for (int t0 = 0; t0 < nT * 64; t0 += 64) {
    int jb = t0 + w * 16 + (lane & 15);
    bfrag kf[DK / 32];
    #pragma unroll
    for (int ks = 0; ks < DK / 32; ++ks)
      kf[ks] = *(const bfrag*)(QKb + (rowbase + jb) * DMK + h * DK + ks * 32 + ko);
    f32x4 accs = {};
    #pragma unroll
    for (int ks = 0; ks < DK / 32; ++ks)
      accs = __builtin_amdgcn_mfma_f32_16x16x32_bf16(qf[ks], kf[ks], accs, 0, 0, 0);
    if ((lane >> 4) < 2) {
      int r0 = (lane >> 4) * 4;
      int ja = jb + 4 * (jb >> 5);
      #pragma unroll
      for (int q = 0; q < 4; ++q)
        sc[(r0 + q) * 1156 + ja] = accs[q];
    }
  }
  __syncthreads();

  // ---- register softmax pipeline: group g (32 lanes) owns query row g ----
  {
    const int g = tid >> 5, l = tid & 31;
    const int i = i0 + g;
    const int jmax = MASKK ? i : i - 1;
    const int sbase = g * 1156 + 36 * l;
    const int jbase = 32 * l;
    const float rscale = rsqrtf((float)DK);

    float sreg[32];
    #pragma unroll
    for (int t = 0; t < 32; ++t) {
      int j = jbase + t;
      sreg[t] = (j <= jmax) ? sc[sbase + t] * rscale : -1e30f;
    }

    float m1 = -1e30f;
    #pragma unroll
    for (int t = 0; t < 32; ++t) m1 = fmaxf(m1, sreg[t]);
    #pragma unroll
    for (int o = 16; o > 0; o >>= 1) m1 = fmaxf(m1, __shfl_xor(m1, o, 32));
    float p[32];
    float l1 = 0.f;
    #pragma unroll
    for (int t = 0; t < 32; ++t) { p[t] = __expf(sreg[t] - m1); l1 += p[t]; }
    #pragma unroll
    for (int o = 16; o > 0; o >>= 1) l1 += __shfl_xor(l1, o, 32);
    float inv1 = 1.f / l1;

    float run = 0.f;
    #pragma unroll
    for (int t = 0; t < 32; ++t) { run += p[t] * inv1; p[t] = run; }
    float scn = run;
    #pragma unroll
    for (int o = 1; o < 32; o <<= 1) {
      float u = __shfl_up(scn, o, 32);
      if (l >= o) scn += u;
    }
    float pre = scn - run;

    float gv = gamp[h];
    float sp = fmaxf(gv, 0.f) + log1pf(__expf(-fabsf(gv)));
    float gm = -sp;
    #pragma unroll
    for (int t = 0; t < 32; ++t) {
      int j = jbase + t;
      float rem = fmaxf(1.f - (pre + p[t]), 0.f);
      float dist = sqrtf(rem * fabsf((float)(j - i)));
      float eff = __expf(gm * dist);
      eff = fminf(fmaxf(eff, 1e-5f), 1e5f);
      sreg[t] = sreg[t] * eff;
    }

    float m2 = -1e30f;
    #pragma unroll
    for (int t = 0; t < 32; ++t) m2 = fmaxf(m2, sreg[t]);
    #pragma unroll
    for (int o = 16; o > 0; o >>= 1) m2 = fmaxf(m2, __shfl_xor(m2, o, 32));
    float l2 = 0.f;
    #pragma unroll
    for (int t = 0; t < 32; ++t) { p[t] = __expf(sreg[t] - m2); l2 += p[t]; }
    #pragma unroll
    for (int o = 16; o > 0; o >>= 1) l2 += __shfl_xor(l2, o, 32);
    bool validrow = (jmax >= 0) && !(ZP && i == 0);
    float wgt = validrow ? (1.f / l2) : 0.f;
    #pragma unroll
    for (int t = 0; t < 32; ++t) sc[sbase + t] = p[t] * wgt;
  }
  __syncthreads();

  // ---- PV: wave owns d-block (and tile-parity subset for DV==32) ----
  const int wd = (DV == 64) ? w : (w & 1);
  const int tpar = (DV == 64) ? -1 : (w >> 1);
  f32x4 acco = {};
  const int dcol = h * DV + wd * 16 + (lane & 15);
  for (int t0 = 0; t0 < nT * 64; t0 += 64) {
    if (DV == 32 && ((t0 >> 6) & 1) != tpar) continue;
    #pragma unroll
    for (int ks = 0; ks < 2; ++ks) {
      int jo = t0 + ks * 32 + ko;
      int pa = qr * 1156 + jo + 4 * (jo >> 5);
      f32x4 p0 = *(const f32x4*)(sc + pa);
      f32x4 p1 = *(const f32x4*)(sc + pa + 4);
      bfrag pf;
      #pragma unroll
      for (int e = 0; e < 4; ++e) { pf[e] = (__bf16)p0[e]; pf[e + 4] = (__bf16)p1[e]; }
      bfrag vf = *(const bfrag*)(Vt + (size_t)dcol * MT + rowbase + jo);
      acco = __builtin_amdgcn_mfma_f32_16x16x32_bf16(pf, vf, acco, 0, 0, 0);
    }
  }

  if (DV == 32) {
    if (w >= 2) {
      #pragma unroll
      for (int q = 0; q < 4; ++q)
        pvred[(w - 2) * 272 + ((lane >> 4) * 4 + q) * 17 + (lane & 15)] = acco[q];
    }
    __syncthreads();
    if (w < 2) {
      #pragma unroll
      for (int q = 0; q < 4; ++q)
        acco[q] += pvred[w * 272 + ((lane >> 4) * 4 + q) * 17 + (lane & 15)];
    }
  }

  if ((DV == 64 || w < 2) && (lane >> 4) < 2) {
    int r0 = (lane >> 4) * 4;
    #pragma unroll
    for (int q = 0; q < 4; ++q) {
      int r = r0 + q;
      O[(rowbase + i0 + r) * DMV + dcol] = f2bf(acco[q]);
    }
  }
}

// ---------------- LayerNorm ----------------
__global__ __launch_bounds__(256) void ln_kernel(
    const float* __restrict__ X, const float* __restrict__ R,
    const float* __restrict__ g, const float* __restrict__ be,
    float* __restrict__ Y, unsigned short* __restrict__ Yb, int D)
{
  __shared__ float red[256];
  int row = blockIdx.x, tid = threadIdx.x;
  const float* x = X + (size_t)row * D;
  const float* r = R ? R + (size_t)row * D : nullptr;
  int ne = D >> 8;
  float xl[2];
  float s = 0.f;
  for (int e = 0; e < ne; ++e) {
    int j = tid + e * 256;
    float v = x[j] + (r ? r[j] : 0.f);
    xl[e] = v; s += v;
  }
  float mean = block_reduce_sum(s, red) / (float)D;
  float vs = 0.f;
  for (int e = 0; e < ne; ++e) { float dd = xl[e] - mean; vs += dd * dd; }
  float var = block_reduce_sum(vs, red) / (float)D;
  float rstd = rsqrtf(var + 1e-5f);
  for (int e = 0; e < ne; ++e) {
    int j = tid + e * 256;
    float v = g[j] * (xl[e] - mean) * rstd + be[j];
    if (Y)  Y[(size_t)row * D + j] = v;
    if (Yb) Yb[(size_t)row * D + j] = f2bf(v);
  }
}

// ---------------- concat ----------------
__global__ __launch_bounds__(256) void concat_kernel(
    const float* __restrict__ Xh, const float* __restrict__ Qe,
    float* __restrict__ Cc)
{
  int idx = blockIdx.x * 256 + threadIdx.x;
  if (idx >= 8192 * 512) return;
  int row = idx >> 9, c = idx & 511;
  Cc[(size_t)row * 512 + c] = (c < 256) ? Xh[(size_t)row * 256 + c]
                                        : Qe[(size_t)row * 256 + (c - 256)];
}

// ---------------- final row-dot ----------------
__global__ __launch_bounds__(256) void dot_kernel(
    const float* __restrict__ X, const float* __restrict__ w,
    const float* __restrict__ b, float* __restrict__ out)
{
  __shared__ float red[256];
  int row = blockIdx.x;
  float v = X[(size_t)row * 256 + threadIdx.x] * w[threadIdx.x];
  float s = block_reduce_sum(v, red);
  if (threadIdx.x == 0) out[row] = s + b[0];
}

// ---------------- launch ----------------
extern "C" void kernel_launch(void* const* d_in, const int* in_sizes, int n_in,
                              void* d_out, int out_size, void* d_ws, size_t ws_size,
                              hipStream_t stream) {
  const int* p_data  = (const int*)d_in[0];
  const int* pa_data = (const int*)d_in[1];
  const float* pemb_W = (const float*)d_in[3];
  const float* diff_W = (const float*)d_in[4];
  const float* qemb_W = (const float*)d_in[5];
  const float* qemb_b = (const float*)d_in[6];
  const float* y_kW = (const float*)d_in[7];   const float* y_kb = (const float*)d_in[8];
  const float* y_vW = (const float*)d_in[9];   const float* y_vb = (const float*)d_in[10];
  const float* y_oW = (const float*)d_in[11];  const float* y_ob = (const float*)d_in[12];
  const float* y_gam = (const float*)d_in[13];
  const float* y_ln1g = (const float*)d_in[14]; const float* y_ln1b = (const float*)d_in[15];
  const float* y_f1W = (const float*)d_in[16]; const float* y_f1b = (const float*)d_in[17];
  const float* y_f2W = (const float*)d_in[18]; const float* y_f2b = (const float*)d_in[19];
  const float* y_ln2g = (const float*)d_in[20]; const float* y_ln2b = (const float*)d_in[21];
  const float* x_kW = (const float*)d_in[22];  const float* x_kb = (const float*)d_in[23];
  const float* x_vW = (const float*)d_in[24];  const float* x_vb = (const float*)d_in[25];
  const float* x_oW = (const float*)d_in[26];  const float* x_ob = (const float*)d_in[27];
  const float* x_gam = (const float*)d_in[28];
  const float* x_ln1g = (const float*)d_in[29]; const float* x_ln1b = (const float*)d_in[30];
  const float* h_kW = (const float*)d_in[31];  const float* h_kb = (const float*)d_in[32];
  const float* h_vW = (const float*)d_in[33];  const float* h_vb = (const float*)d_in[34];
  const float* h_oW = (const float*)d_in[35];  const float* h_ob = (const float*)d_in[36];
  const float* h_gam = (const float*)d_in[37];
  const float* h_ln1g = (const float*)d_in[38]; const float* h_ln1b = (const float*)d_in[39];
  const float* h_f1W = (const float*)d_in[40]; const float* h_f1b = (const float*)d_in[41];
  const float* h_f2W = (const float*)d_in[42]; const float* h_f2b = (const float*)d_in[43];
  const float* h_ln2g = (const float*)d_in[44]; const float* h_ln2b = (const float*)d_in[45];
  const float* oln1g = (const float*)d_in[46]; const float* oln1b = (const float*)d_in[47];
  const float* o1W = (const float*)d_in[48];   const float* o1b = (const float*)d_in[49];
  const float* oln2g = (const float*)d_in[50]; const float* oln2b = (const float*)d_in[51];
  const float* o2W = (const float*)d_in[52];   const float* o2b = (const float*)d_in[53];
  const float* oln3g = (const float*)d_in[54]; const float* oln3b = (const float*)d_in[55];
  const float* o3W = (const float*)d_in[56];   const float* o3b = (const float*)d_in[57];

  float* out_f = (float*)d_out;

  const int B = 8, S = 1024, M = B * S;
  const int R = 4097, KQ = 1025, KQP = 1056;

  float* ws = (float*)d_ws;
  size_t off = 0;
  auto alloc = [&](size_t nfloats) { size_t o = off; off += (nfloats + 255) & ~(size_t)255; return o; };
  auto allocs = [&](size_t nshorts) { return alloc((nshorts + 1) / 2); };

  size_t oE    = alloc((size_t)R * 256);
  size_t oSIGb = allocs((size_t)R * KQP);
  size_t oSSUM = alloc(R);
  size_t oQE   = alloc((size_t)M * 256);
  size_t oQEb  = allocs((size_t)M * 256);
  size_t oQA   = alloc((size_t)M * 512);
  size_t oQAb  = allocs((size_t)M * 512);
  size_t oYOb  = allocs((size_t)M * 512);
  size_t oXO   = alloc((size_t)M * 256);
  size_t oXOb  = allocs((size_t)M * 256);
  size_t oHO   = alloc((size_t)M * 256);
  size_t oS0   = alloc((size_t)M * 512);   // FFb arena (S0+S1)
  size_t oS1   = alloc((size_t)M * 512);
  size_t oS2b  = allocs((size_t)M * 512);
  size_t oS3   = alloc((size_t)M * 512);
  size_t oS4   = alloc((size_t)M * 512);
  size_t oSX   = alloc((size_t)M * 512);
  size_t oSXb  = allocs((size_t)M * 512);
  size_t oS0b  = allocs((size_t)M * 512);  // bf16 QK proj
  size_t oVt   = allocs((size_t)M * 512);  // bf16 transposed V
  // bf16 transposed weights
  size_t oWqe  = allocs((size_t)256 * KQP);
  size_t oWyk  = allocs((size_t)512 * 512);
  size_t oWyv  = allocs((size_t)512 * 512);
  size_t oWyo  = allocs((size_t)512 * 512);
  size_t oWyf1 = allocs((size_t)2048 * 512);
  size_t oWyf2 = allocs((size_t)512 * 2048);
  size_t oWxk  = allocs((size_t)256 * 256);
  size_t oWxv  = allocs((size_t)256 * 256);
  size_t oWxo  = allocs((size_t)256 * 256);
  size_t oWhk  = allocs((size_t)256 * 256);
  size_t oWhv  = allocs((size_t)512 * 512);
  size_t oWho  = allocs((size_t)256 * 512);
  size_t oWhf1 = allocs((size_t)2048 * 256);
  size_t oWhf2 = allocs((size_t)256 * 2048);
  size_t oWo1  = allocs((size_t)512 * 512);
  size_t oWo2  = allocs((size_t)256 * 512);
  (void)ws_size; (void)in_sizes; (void)n_in; (void)out_size;

  float* E    = ws + oE;
  unsigned short* SIGb = (unsigned short*)(ws + oSIGb);
  float* SSUM = ws + oSSUM;
  float* QE   = ws + oQE;   unsigned short* QEb = (unsigned short*)(ws + oQEb);
  float* QA   = ws + oQA;   unsigned short* QAb = (unsigned short*)(ws + oQAb);
  unsigned short* YOb = (unsigned short*)(ws + oYOb);
  float* XO   = ws + oXO;   unsigned short* XOb = (unsigned short*)(ws + oXOb);
  float* HO   = ws + oHO;
  float* S0   = ws + oS0;
  unsigned short* S2b = (unsigned short*)(ws + oS2b);
  float* S3   = ws + oS3;
  float* S4   = ws + oS4;
  float* SX   = ws + oSX;   unsigned short* SXb = (unsigned short*)(ws + oSXb);
  unsigned short* S0b = (unsigned short*)(ws + oS0b);
  unsigned short* Vt  = (unsigned short*)(ws + oVt);
  unsigned short* FFb = (unsigned short*)S0;

  unsigned short* Wqe  = (unsigned short*)(ws + oWqe);
  unsigned short* Wyk  = (unsigned short*)(ws + oWyk);
  unsigned short* Wyv  = (unsigned short*)(ws + oWyv);
  unsigned short* Wyo  = (unsigned short*)(ws + oWyo);
  unsigned short* Wyf1 = (unsigned short*)(ws + oWyf1);
  unsigned short* Wyf2 = (unsigned short*)(ws + oWyf2);
  unsigned short* Wxk  = (unsigned short*)(ws + oWxk);
  unsigned short* Wxv  = (unsigned short*)(ws + oWxv);
  unsigned short* Wxo  = (unsigned short*)(ws + oWxo);
  unsigned short* Whk  = (unsigned short*)(ws + oWhk);
  unsigned short* Whv  = (unsigned short*)(ws + oWhv);
  unsigned short* Who  = (unsigned short*)(ws + oWho);
  unsigned short* Whf1 = (unsigned short*)(ws + oWhf1);
  unsigned short* Whf2 = (unsigned short*)(ws + oWhf2);
  unsigned short* Wo1  = (unsigned short*)(ws + oWo1);
  unsigned short* Wo2  = (unsigned short*)(ws + oWo2);

  dim3 blk(256);
  int nElem512 = (8192 * 512 + 255) / 256;

  struct TD { const float* src; unsigned short* dst; int K, N, Kp; };
  const TD tds[] = {
    {qemb_W, Wqe, KQ, 256, KQP},
    {y_kW, Wyk, 512, 512, 512}, {y_vW, Wyv, 512, 512, 512}, {y_oW, Wyo, 512, 512, 512},
    {y_f1W, Wyf1, 512, 2048, 512}, {y_f2W, Wyf2, 2048, 512, 2048},
    {x_kW, Wxk, 256, 256, 256}, {x_vW, Wxv, 256, 256, 256}, {x_oW, Wxo, 256, 256, 256},
    {h_kW, Whk, 256, 256, 256}, {h_vW, Whv, 512, 512, 512}, {h_oW, Who, 512, 256, 512},
    {h_f1W, Whf1, 256, 2048, 256}, {h_f2W, Whf2, 2048, 256, 2048},
    {o1W, Wo1, 512, 512, 512}, {o2W, Wo2, 512, 256, 512},
  };
  for (const TD& t : tds) {
    dim3 g((t.N + 31) / 32, (t.Kp + 31) / 32);
    tconv_kernel<<<g, blk, 0, stream>>>(t.src, t.dst, t.K, t.N, t.Kp);
  }

  auto ggrid = [](int Mm, int Nn) { return dim3((unsigned)(Nn / 128), (unsigned)((Mm + 127) / 128)); };

  // 1. embedding table
  sig_kernel<<<R, blk, 0, stream>>>(pemb_W, SIGb, SSUM, KQ, KQP);
  mgemm_kernel<2, true, false, false><<<ggrid(R, 256), blk, 0, stream>>>(SIGb, Wqe, qemb_b, E, nullptr, nullptr, R, 256, KQP, SSUM);
  gather_kernel<<<nElem512, blk, 0, stream>>>(p_data, pa_data, E, diff_W, QE, QEb, QA, QAb);
  creg_kernel<<<1, blk, 0, stream>>>(p_data, diff_W, out_f + 8192);

  dim3 agrid(S / 8, B * NHEADS);

  // 2. y layer (dm=512, mask_k=1, zero_pad=0, FFN)
  mgemm_kernel<0, false, true, false><<<ggrid(M, 512), blk, 0, stream>>>(QAb, Wyk, y_kb, nullptr, S0b, nullptr, M, 512, 512, nullptr);
  mgemm_kernel<0, false, false, true><<<ggrid(M, 512), blk, 0, stream>>>(QAb, Wyv, y_vb, nullptr, nullptr, Vt, M, 512, 512, nullptr);
  attn3_kernel<64, 64, 1, 0><<<agrid, blk, 0, stream>>>(S0b, Vt, y_gam, S2b, S, M);
  mgemm_kernel<0, true, false, false><<<ggrid(M, 512), blk, 0, stream>>>(S2b, Wyo, y_ob, S3, nullptr, nullptr, M, 512, 512, nullptr);
  ln_kernel<<<M, blk, 0, stream>>>(QA, S3, y_ln1g, y_ln1b, SX, SXb, 512);
  mgemm_kernel<1, false, true, false><<<ggrid(M, 2048), blk, 0, stream>>>(SXb, Wyf1, y_f1b, nullptr, FFb, nullptr, M, 2048, 512, nullptr);
  mgemm_kernel<0, true, false, false><<<ggrid(M, 512), blk, 0, stream>>>(FFb, Wyf2, y_f2b, S4, nullptr, nullptr, M, 512, 2048, nullptr);
  ln_kernel<<<M, blk, 0, stream>>>(SX, S4, y_ln2g, y_ln2b, nullptr, YOb, 512);

  // 3. x layer (dm=256, mask_k=1, zero_pad=0, no FFN)
  mgemm_kernel<0, false, true, false><<<ggrid(M, 256), blk, 0, stream>>>(QEb, Wxk, x_kb, nullptr, S0b, nullptr, M, 256, 256, nullptr);
  mgemm_kernel<0, false, false, true><<<ggrid(M, 256), blk, 0, stream>>>(QEb, Wxv, x_vb, nullptr, nullptr, Vt, M, 256, 256, nullptr);
  attn3_kernel<32, 32, 1, 0><<<agrid, blk, 0, stream>>>(S0b, Vt, x_gam, S2b, S, M);
  mgemm_kernel<0, true, false, false><<<ggrid(M, 256), blk, 0, stream>>>(S2b, Wxo, x_ob, S3, nullptr, nullptr, M, 256, 256, nullptr);
  ln_kernel<<<M, blk, 0, stream>>>(QE, S3, x_ln1g, x_ln1b, XO, XOb, 256);

  // 4. h layer (q,k from XO; v from YO; mask_k=0, zero_pad=1, FFN)
  mgemm_kernel<0, false, true, false><<<ggrid(M, 256), blk, 0, stream>>>(XOb, Whk, h_kb, nullptr, S0b, nullptr, M, 256, 256, nullptr);
  mgemm_kernel<0, false, false, true><<<ggrid(M, 512), blk, 0, stream>>>(YOb, Whv, h_vb, nullptr, nullptr, Vt, M, 512, 512, nullptr);
  attn3_kernel<32, 64, 0, 1><<<agrid, blk, 0, stream>>>(S0b, Vt, h_gam, S2b, S, M);
  mgemm_kernel<0, true, false, false><<<ggrid(M, 256), blk, 0, stream>>>(S2b, Who, h_ob, S3, nullptr, nullptr, M, 256, 512, nullptr);
  ln_kernel<<<M, blk, 0, stream>>>(XO, S3, h_ln1g, h_ln1b, SX, SXb, 256);
  mgemm_kernel<1, false, true, false><<<ggrid(M, 2048), blk, 0, stream>>>(SXb, Whf1, h_f1b, nullptr, FFb, nullptr, M, 2048, 256, nullptr);
  mgemm_kernel<0, true, false, false><<<ggrid(M, 256), blk, 0, stream>>>(FFb, Whf2, h_f2b, S4, nullptr, nullptr, M, 256, 2048, nullptr);
  ln_kernel<<<M, blk, 0, stream>>>(SX, S4, h_ln2g, h_ln2b, HO, nullptr, 256);

  // 5. head
  concat_kernel<<<nElem512, blk, 0, stream>>>(HO, QE, S3);
  ln_kernel<<<M, blk, 0, stream>>>(S3, nullptr, oln1g, oln1b, nullptr, SXb, 512);
  mgemm_kernel<1, true, false, false><<<ggrid(M, 512), blk, 0, stream>>>(SXb, Wo1, o1b, S3, nullptr, nullptr, M, 512, 512, nullptr);
  ln_kernel<<<M, blk, 0, stream>>>(S3, nullptr, oln2g, oln2b, nullptr, SXb, 512);
  mgemm_kernel<1, true, false, false><<<ggrid(M, 256), blk, 0, stream>>>(SXb, Wo2, o2b, S4, nullptr, nullptr, M, 256, 512, nullptr);
  ln_kernel<<<M, blk, 0, stream>>>(S4, nullptr, oln3g, oln3b, SX, nullptr, 256);
  dot_kernel<<<M, blk, 0, stream>>>(SX, o3W, o3b, out_f);
}

// Round 5
// 1013.403 us; speedup vs baseline: 9.9598x; 1.1026x over previous
//
#include <hip/hip_runtime.h>
#include <hip/hip_bf16.h>
#include <math.h>

#define NHEADS 8

typedef __attribute__((ext_vector_type(8))) __bf16 bfrag;
typedef __attribute__((ext_vector_type(4))) float f32x4;

static __device__ __forceinline__ unsigned short f2bf(float f) {
  unsigned u = __float_as_uint(f);
  unsigned r = (u + 0x7fffu + ((u >> 16) & 1u)) >> 16;
  return (unsigned short)r;
}

static __device__ __forceinline__ void gload_lds16(const void* g, void* l) {
  __builtin_amdgcn_global_load_lds(
      (const __attribute__((address_space(1))) unsigned int*)g,
      (__attribute__((address_space(3))) unsigned int*)l, 16, 0, 0);
}

static __device__ __forceinline__ float block_reduce_sum(float v, float* red) {
  int t = threadIdx.x;
  red[t] = v; __syncthreads();
  for (int s = 128; s > 0; s >>= 1) {
    if (t < s) red[t] += red[t + s];
    __syncthreads();
  }
  float r = red[0];
  __syncthreads();
  return r;
}

// ---------------- sigmoid table (bf16, padded to Kp) + row sums ----------------
__global__ __launch_bounds__(256) void sig_kernel(
    const float* __restrict__ Wp, unsigned short* __restrict__ Sgb,
    float* __restrict__ Ssum, int Kd, int Kp)
{
  __shared__ float red[256];
  int row = blockIdx.x;
  float s = 0.f;
  for (int k = threadIdx.x; k < Kp; k += 256) {
    float v = 0.f;
    if (k < Kd) {
      v = 1.f / (1.f + __expf(-Wp[(size_t)row * Kd + k]));
      s += v;
    }
    Sgb[(size_t)row * Kp + k] = f2bf(v);
  }
  float tot = block_reduce_sum(s, red);
  if (threadIdx.x == 0) Ssum[row] = tot;
}

// ---------------- transpose + convert: dst[n][k] = bf16(src[k][n]) ----------------
__global__ __launch_bounds__(256) void tconv_kernel(
    const float* __restrict__ src, unsigned short* __restrict__ dst,
    int K, int N, int Kp)
{
  __shared__ float t[32][33];
  int tid = threadIdx.x;
  int tx = tid & 31, ty = tid >> 5;
  int bk = blockIdx.y * 32, bn = blockIdx.x * 32;
  #pragma unroll
  for (int u = 0; u < 4; ++u) {
    int k = bk + ty + u * 8, n = bn + tx;
    t[ty + u * 8][tx] = (k < K && n < N) ? src[(size_t)k * N + n] : 0.f;
  }
  __syncthreads();
  #pragma unroll
  for (int u = 0; u < 4; ++u) {
    int n = bn + ty + u * 8, kk = bk + tx;
    if (n < N && kk < Kp)
      dst[(size_t)n * Kp + kk] = f2bf(t[tx][ty + u * 8]);
  }
}

// ---------------- MFMA bf16 GEMM: C = epi(A @ Bt^T + bias) ----------------
template<int EPI, bool WF32, bool WBF, bool WTR>
__global__ __launch_bounds__(256) void mgemm_kernel(
    const unsigned short* __restrict__ A, const unsigned short* __restrict__ Bt,
    const float* __restrict__ bias, float* __restrict__ C,
    unsigned short* __restrict__ Cb, unsigned short* __restrict__ Ct,
    int M, int N, int K, const float* __restrict__ divv)
{
  __shared__ __align__(16) unsigned short Als[128 * 32];
  __shared__ __align__(16) unsigned short Bls[128 * 32];
  const int tid = threadIdx.x;
  const int lane = tid & 63, w = tid >> 6;
  const int wm = w >> 1, wn = w & 1;
  const int brow = blockIdx.y * 128, bcol = blockIdx.x * 128;

  f32x4 acc[4][4] = {};

  for (int k0 = 0; k0 < K; k0 += 32) {
    #pragma unroll
    for (int q = 0; q < 2; ++q) {
      int s = w * 128 + q * 64 + lane;
      int r = s >> 2, g = s & 3;
      int gs = g ^ (r & 3);
      int gr = brow + r; if (gr > M - 1) gr = M - 1;
      gload_lds16(A + (size_t)gr * K + k0 + gs * 8,
                  (char*)Als + (w * 2048 + q * 1024));
      int gc = bcol + r; if (gc > N - 1) gc = N - 1;
      gload_lds16(Bt + (size_t)gc * K + k0 + gs * 8,
                  (char*)Bls + (w * 2048 + q * 1024));
    }
    __syncthreads();

    bfrag av[4], bv[4];
    #pragma unroll
    for (int f = 0; f < 4; ++f) {
      int rA = wm * 64 + f * 16 + (lane & 15);
      av[f] = *(const bfrag*)((const char*)Als + rA * 64 + ((((lane >> 4) ^ (rA & 3))) << 4));
      int rB = wn * 64 + f * 16 + (lane & 15);
      bv[f] = *(const bfrag*)((const char*)Bls + rB * 64 + ((((lane >> 4) ^ (rB & 3))) << 4));
    }
    #pragma unroll
    for (int i = 0; i < 4; ++i)
      #pragma unroll
      for (int j = 0; j < 4; ++j)
        acc[i][j] = __builtin_amdgcn_mfma_f32_16x16x32_bf16(av[i], bv[j], acc[i][j], 0, 0, 0);
    __syncthreads();
  }

  #pragma unroll
  for (int i = 0; i < 4; ++i) {
    int gr0 = brow + wm * 64 + i * 16 + (lane >> 4) * 4;
    #pragma unroll
    for (int j = 0; j < 4; ++j) {
      int gc = bcol + wn * 64 + j * 16 + (lane & 15);
      float bsv = bias ? bias[gc] : 0.f;
      float vv[4];
      #pragma unroll
      for (int q = 0; q < 4; ++q) {
        int gr = gr0 + q;
        float v = acc[i][j][q] + bsv;
        if (EPI >= 1) v = fmaxf(v, 0.f);
        if (EPI == 2) v = (gr < M) ? v / divv[gr] : v;
        vv[q] = v;
      }
      #pragma unroll
      for (int q = 0; q < 4; ++q) {
        int gr = gr0 + q;
        if (gr >= M) continue;
        if (WF32) C[(size_t)gr * N + gc] = vv[q];
        if (WBF)  Cb[(size_t)gr * N + gc] = f2bf(vv[q]);
      }
      if (WTR) {
        ushort4 h4 = { f2bf(vv[0]), f2bf(vv[1]), f2bf(vv[2]), f2bf(vv[3]) };
        *(ushort4*)(Ct + (size_t)gc * M + gr0) = h4;
      }
    }
  }
}

// ---------------- embedding gather ----------------
__global__ __launch_bounds__(256) void gather_kernel(
    const int* __restrict__ p_data, const int* __restrict__ pa_data,
    const float* __restrict__ E, const float* __restrict__ diff_W,
    float* __restrict__ qemb, unsigned short* __restrict__ qembb,
    float* __restrict__ qaemb, unsigned short* __restrict__ qaembb)
{
  int idx = blockIdx.x * 256 + threadIdx.x;
  if (idx >= 8192 * 512) return;
  int row = idx >> 9, c = idx & 511;
  int p = p_data[row];
  float pid = diff_W[p];
  if (c < 256) {
    float v = E[(size_t)p * 256 + c] + pid;
    qemb[(size_t)row * 256 + c] = v;
    qembb[(size_t)row * 256 + c] = f2bf(v);
  }
  int pa = pa_data[row];
  int ppos = (pa > 4096) ? pa - 4096 : 0;
  int pneg = (pa <= 4096) ? pa : 0;
  float v = (c < 256) ? E[(size_t)ppos * 256 + c] : E[(size_t)pneg * 256 + (c - 256)];
  v += pid;
  qaemb[(size_t)row * 512 + c] = v;
  qaembb[(size_t)row * 512 + c] = f2bf(v);
}

// ---------------- c_reg ----------------
__global__ __launch_bounds__(256) void creg_kernel(
    const int* __restrict__ p_data, const float* __restrict__ dW,
    float* __restrict__ out)
{
  __shared__ float red[256];
  float s = 0.f;
  for (int i = threadIdx.x; i < 8192; i += 256) {
    float v = dW[p_data[i]];
    s += v * v;
  }
  float tot = block_reduce_sum(s, red);
  if (threadIdx.x == 0) out[0] = tot * 1e-5f;
}

// ---------------- MFMA distance-decay attention v4 ----------------
// 16 query rows per block, 512 threads (8 waves). Scores/P in swizzled LDS:
// addr(r,j) = r*1156 + j + 4*(j>>5). PV uses split-P (hi+lo bf16) for precision.
template<int DK, int DV, int MASKK, int ZP>
__global__ __launch_bounds__(512, 4) void attn4_kernel(
    const unsigned short* __restrict__ QKb, const unsigned short* __restrict__ Vt,
    const float* __restrict__ gamp, unsigned short* __restrict__ O,
    int S, int MT)
{
  const int DMK = NHEADS * DK, DMV = NHEADS * DV;
  const int i0 = blockIdx.x * 16;
  const int b = blockIdx.y >> 3, h = blockIdx.y & 7;
  const int tid = threadIdx.x;
  const int lane = tid & 63, w = tid >> 6;
  const size_t rowbase = (size_t)b * S;

  constexpr int NP = (DV == 32) ? 6 : 4;     // PV partials held in LDS
  __shared__ __align__(16) float sc[16 * 1156];
  __shared__ float red[NP * 16 * 17];

  const int jmaxBlk = MASKK ? (i0 + 15) : (i0 + 14);
  const int nT = jmaxBlk / 64 + 1;
  const int NK = nT * 64;

  const int qr = lane & 15;
  const int ko8 = (lane >> 4) * 8;

  bfrag qf[DK / 32];
  #pragma unroll
  for (int ks = 0; ks < DK / 32; ++ks)
    qf[ks] = *(const bfrag*)(QKb + (rowbase + i0 + qr) * DMK + h * DK + ks * 32 + ko8);

  // ---- QK^T: wave handles tile t0 + (w>>2)*64, j-block (w&3)*16 ----
  for (int t0 = 0; t0 < NK; t0 += 128) {
    int tt = t0 + (w >> 2) * 64;
    if (tt < NK) {
      int jb = tt + (w & 3) * 16 + qr;
      bfrag kf[DK / 32];
      #pragma unroll
      for (int ks = 0; ks < DK / 32; ++ks)
        kf[ks] = *(const bfrag*)(QKb + (rowbase + jb) * DMK + h * DK + ks * 32 + ko8);
      f32x4 accs = {};
      #pragma unroll
      for (int ks = 0; ks < DK / 32; ++ks)
        accs = __builtin_amdgcn_mfma_f32_16x16x32_bf16(qf[ks], kf[ks], accs, 0, 0, 0);
      int ja = jb + 4 * (jb >> 5);
      int r0 = (lane >> 4) * 4;
      #pragma unroll
      for (int q = 0; q < 4; ++q)
        sc[(r0 + q) * 1156 + ja] = accs[q];
    }
  }
  __syncthreads();

  // ---- register softmax pipeline: group g (32 lanes) owns query row g ----
  {
    const int g = tid >> 5, l = tid & 31;
    const int i = i0 + g;
    const int jmax = MASKK ? i : i - 1;
    const int sbase = g * 1156 + 36 * l;
    const int jbase = 32 * l;
    const float rscale = rsqrtf((float)DK);

    float sreg[32];
    #pragma unroll
    for (int t = 0; t < 32; ++t) {
      int j = jbase + t;
      sreg[t] = (j <= jmax) ? sc[sbase + t] * rscale : -1e30f;
    }

    float m1 = -1e30f;
    #pragma unroll
    for (int t = 0; t < 32; ++t) m1 = fmaxf(m1, sreg[t]);
    #pragma unroll
    for (int o = 16; o > 0; o >>= 1) m1 = fmaxf(m1, __shfl_xor(m1, o, 32));
    float p[32];
    float l1 = 0.f;
    #pragma unroll
    for (int t = 0; t < 32; ++t) { p[t] = __expf(sreg[t] - m1); l1 += p[t]; }
    #pragma unroll
    for (int o = 16; o > 0; o >>= 1) l1 += __shfl_xor(l1, o, 32);
    float inv1 = 1.f / l1;

    float run = 0.f;
    #pragma unroll
    for (int t = 0; t < 32; ++t) { run += p[t] * inv1; p[t] = run; }
    float scn = run;
    #pragma unroll
    for (int o = 1; o < 32; o <<= 1) {
      float u = __shfl_up(scn, o, 32);
      if (l >= o) scn += u;
    }
    float pre = scn - run;

    float gv = gamp[h];
    float sp = fmaxf(gv, 0.f) + log1pf(__expf(-fabsf(gv)));
    float gm = -sp;
    #pragma unroll
    for (int t = 0; t < 32; ++t) {
      int j = jbase + t;
      float rem = fmaxf(1.f - (pre + p[t]), 0.f);
      float dist = sqrtf(rem * fabsf((float)(j - i)));
      float eff = __expf(gm * dist);
      eff = fminf(fmaxf(eff, 1e-5f), 1e5f);
      sreg[t] = sreg[t] * eff;
    }

    float m2 = -1e30f;
    #pragma unroll
    for (int t = 0; t < 32; ++t) m2 = fmaxf(m2, sreg[t]);
    #pragma unroll
    for (int o = 16; o > 0; o >>= 1) m2 = fmaxf(m2, __shfl_xor(m2, o, 32));
    float l2 = 0.f;
    #pragma unroll
    for (int t = 0; t < 32; ++t) { p[t] = __expf(sreg[t] - m2); l2 += p[t]; }
    #pragma unroll
    for (int o = 16; o > 0; o >>= 1) l2 += __shfl_xor(l2, o, 32);
    bool validrow = (jmax >= 0) && !(ZP && i == 0);
    float wgt = validrow ? (1.f / l2) : 0.f;
    #pragma unroll
    for (int t = 0; t < 32; ++t) sc[sbase + t] = p[t] * wgt;
  }
  __syncthreads();

  // ---- PV: wave owns (d-block, tile-parity); split-P for precision ----
  const int dblk = (DV == 64) ? (w & 3) : (w & 1);
  const int par  = (DV == 64) ? (w >> 2) : (w >> 1);
  const int NPAR = (DV == 64) ? 2 : 4;
  const int NFIN = (DV == 64) ? 4 : 2;
  f32x4 acco = {};
  const int dcol = h * DV + dblk * 16 + (lane & 15);
  for (int t0 = par * 64; t0 < NK; t0 += NPAR * 64) {
    #pragma unroll
    for (int ks = 0; ks < 2; ++ks) {
      int jo = t0 + ks * 32 + ko8;
      int pa = qr * 1156 + jo + 4 * (jo >> 5);
      f32x4 p0 = *(const f32x4*)(sc + pa);
      f32x4 p1 = *(const f32x4*)(sc + pa + 4);
      bfrag ph, pl;
      #pragma unroll
      for (int e = 0; e < 4; ++e) {
        __bf16 h0 = (__bf16)p0[e];
        __bf16 h1 = (__bf16)p1[e];
        ph[e] = h0; ph[e + 4] = h1;
        pl[e] = (__bf16)(p0[e] - (float)h0);
        pl[e + 4] = (__bf16)(p1[e] - (float)h1);
      }
      bfrag vf = *(const bfrag*)(Vt + (size_t)dcol * MT + rowbase + jo);
      acco = __builtin_amdgcn_mfma_f32_16x16x32_bf16(pl, vf, acco, 0, 0, 0);
      acco = __builtin_amdgcn_mfma_f32_16x16x32_bf16(ph, vf, acco, 0, 0, 0);
    }
  }

  if (w >= NFIN) {
    #pragma unroll
    for (int q = 0; q < 4; ++q)
      red[(w - NFIN) * 272 + ((lane >> 4) * 4 + q) * 17 + (lane & 15)] = acco[q];
  }
  __syncthreads();
  if (w < NFIN) {
    for (int pp = w; pp < NP; pp += NFIN) {
      #pragma unroll
      for (int q = 0; q < 4; ++q)
        acco[q] += red[pp * 272 + ((lane >> 4) * 4 + q) * 17 + (lane & 15)];
    }
    int r0 = (lane >> 4) * 4;
    #pragma unroll
    for (int q = 0; q < 4; ++q)
      O[(rowbase + i0 + r0 + q) * DMV + dcol] = f2bf(acco[q]);
  }
}

// ---------------- LayerNorm v4: one row per wave, float4 loads ----------------
template<int D, bool WF, bool WB>
__global__ __launch_bounds__(256) void ln4_kernel(
    const float* __restrict__ X, const float* __restrict__ R,
    const float* __restrict__ g, const float* __restrict__ be,
    float* __restrict__ Y, unsigned short* __restrict__ Yb)
{
  constexpr int NC = D / 256;
  int row = blockIdx.x * 4 + (threadIdx.x >> 6);
  int lane = threadIdx.x & 63;
  const float* x = X + (size_t)row * D;
  f32x4 xv[NC];
  float s = 0.f;
  #pragma unroll
  for (int c = 0; c < NC; ++c) {
    xv[c] = *(const f32x4*)(x + c * 256 + lane * 4);
    if (R) {
      f32x4 rv = *(const f32x4*)(R + (size_t)row * D + c * 256 + lane * 4);
      #pragma unroll
      for (int k = 0; k < 4; ++k) xv[c][k] += rv[k];
    }
    #pragma unroll
    for (int k = 0; k < 4; ++k) s += xv[c][k];
  }
  #pragma unroll
  for (int o = 32; o > 0; o >>= 1) s += __shfl_xor(s, o, 64);
  float mean = s / (float)D;
  float vs = 0.f;
  #pragma unroll
  for (int c = 0; c < NC; ++c)
    #pragma unroll
    for (int k = 0; k < 4; ++k) { float d = xv[c][k] - mean; vs += d * d; }
  #pragma unroll
  for (int o = 32; o > 0; o >>= 1) vs += __shfl_xor(vs, o, 64);
  float rstd = rsqrtf(vs / (float)D + 1e-5f);
  #pragma unroll
  for (int c = 0; c < NC; ++c) {
    f32x4 gv = *(const f32x4*)(g + c * 256 + lane * 4);
    f32x4 bv = *(const f32x4*)(be + c * 256 + lane * 4);
    f32x4 ov;
    #pragma unroll
    for (int k = 0; k < 4; ++k) ov[k] = gv[k] * (xv[c][k] - mean) * rstd + bv[k];
    if (WF) *(f32x4*)(Y + (size_t)row * D + c * 256 + lane * 4) = ov;
    if (WB) {
      ushort4 h4 = { f2bf(ov[0]), f2bf(ov[1]), f2bf(ov[2]), f2bf(ov[3]) };
      *(ushort4*)(Yb + (size_t)row * D + c * 256 + lane * 4) = h4;
    }
  }
}

// ---------------- fused concat + LN (D=512): LN([Xh|Qe]) -> bf16 ----------------
__global__ __launch_bounds__(256) void lnc_kernel(
    const float* __restrict__ Xh, const float* __restrict__ Qe,
    const float* __restrict__ g, const float* __restrict__ be,
    unsigned short* __restrict__ Yb)
{
  int row = blockIdx.x * 4 + (threadIdx.x >> 6);
  int lane = threadIdx.x & 63;
  f32x4 xv[2];
  xv[0] = *(const f32x4*)(Xh + (size_t)row * 256 + lane * 4);
  xv[1] = *(const f32x4*)(Qe + (size_t)row * 256 + lane * 4);
  float s = 0.f;
  #pragma unroll
  for (int c = 0; c < 2; ++c)
    #pragma unroll
    for (int k = 0; k < 4; ++k) s += xv[c][k];
  #pragma unroll
  for (int o = 32; o > 0; o >>= 1) s += __shfl_xor(s, o, 64);
  float mean = s / 512.f;
  float vs = 0.f;
  #pragma unroll
  for (int c = 0; c < 2; ++c)
    #pragma unroll
    for (int k = 0; k < 4; ++k) { float d = xv[c][k] - mean; vs += d * d; }
  #pragma unroll
  for (int o = 32; o > 0; o >>= 1) vs += __shfl_xor(vs, o, 64);
  float rstd = rsqrtf(vs / 512.f + 1e-5f);
  #pragma unroll
  for (int c = 0; c < 2; ++c) {
    f32x4 gv = *(const f32x4*)(g + c * 256 + lane * 4);
    f32x4 bv = *(const f32x4*)(be + c * 256 + lane * 4);
    ushort4 h4;
    #pragma unroll
    for (int k = 0; k < 4; ++k) {
      float ov = gv[k] * (xv[c][k] - mean) * rstd + bv[k];
      ((unsigned short*)&h4)[k] = f2bf(ov);
    }
    *(ushort4*)(Yb + (size_t)row * 512 + c * 256 + lane * 4) = h4;
  }
}

// ---------------- fused LN(D=256) + dot with w3 ----------------
__global__ __launch_bounds__(256) void lndot_kernel(
    const float* __restrict__ X, const float* __restrict__ g,
    const float* __restrict__ be, const float* __restrict__ w3,
    const float* __restrict__ b3, float* __restrict__ out)
{
  int row = blockIdx.x * 4 + (threadIdx.x >> 6);
  int lane = threadIdx.x & 63;
  f32x4 v = *(const f32x4*)(X + (size_t)row * 256 + lane * 4);
  float s = v[0] + v[1] + v[2] + v[3];
  #pragma unroll
  for (int o = 32; o > 0; o >>= 1) s += __shfl_xor(s, o, 64);
  float mean = s / 256.f;
  float vs = 0.f;
  #pragma unroll
  for (int k = 0; k < 4; ++k) { float d = v[k] - mean; vs += d * d; }
  #pragma unroll
  for (int o = 32; o > 0; o >>= 1) vs += __shfl_xor(vs, o, 64);
  float rstd = rsqrtf(vs / 256.f + 1e-5f);
  f32x4 gv = *(const f32x4*)(g + lane * 4);
  f32x4 bv = *(const f32x4*)(be + lane * 4);
  f32x4 wv = *(const f32x4*)(w3 + lane * 4);
  float d = 0.f;
  #pragma unroll
  for (int k = 0; k < 4; ++k)
    d += (gv[k] * (v[k] - mean) * rstd + bv[k]) * wv[k];
  #pragma unroll
  for (int o = 32; o > 0; o >>= 1) d += __shfl_xor(d, o, 64);
  if (lane == 0) out[row] = d + b3[0];
}

// ---------------- launch ----------------
extern "C" void kernel_launch(void* const* d_in, const int* in_sizes, int n_in,
                              void* d_out, int out_size, void* d_ws, size_t ws_size,
                              hipStream_t stream) {
  const int* p_data  = (const int*)d_in[0];
  const int* pa_data = (const int*)d_in[1];
  const float* pemb_W = (const float*)d_in[3];
  const float* diff_W = (const float*)d_in[4];
  const float* qemb_W = (const float*)d_in[5];
  const float* qemb_b = (const float*)d_in[6];
  const float* y_kW = (const float*)d_in[7];   const float* y_kb = (const float*)d_in[8];
  const float* y_vW = (const float*)d_in[9];   const float* y_vb = (const float*)d_in[10];
  const float* y_oW = (const float*)d_in[11];  const float* y_ob = (const float*)d_in[12];
  const float* y_gam = (const float*)d_in[13];
  const float* y_ln1g = (const float*)d_in[14]; const float* y_ln1b = (const float*)d_in[15];
  const float* y_f1W = (const float*)d_in[16]; const float* y_f1b = (const float*)d_in[17];
  const float* y_f2W = (const float*)d_in[18]; const float* y_f2b = (const float*)d_in[19];
  const float* y_ln2g = (const float*)d_in[20]; const float* y_ln2b = (const float*)d_in[21];
  const float* x_kW = (const float*)d_in[22];  const float* x_kb = (const float*)d_in[23];
  const float* x_vW = (const float*)d_in[24];  const float* x_vb = (const float*)d_in[25];
  const float* x_oW = (const float*)d_in[26];  const float* x_ob = (const float*)d_in[27];
  const float* x_gam = (const float*)d_in[28];
  const float* x_ln1g = (const float*)d_in[29]; const float* x_ln1b = (const float*)d_in[30];
  const float* h_kW = (const float*)d_in[31];  const float* h_kb = (const float*)d_in[32];
  const float* h_vW = (const float*)d_in[33];  const float* h_vb = (const float*)d_in[34];
  const float* h_oW = (const float*)d_in[35];  const float* h_ob = (const float*)d_in[36];
  const float* h_gam = (const float*)d_in[37];
  const float* h_ln1g = (const float*)d_in[38]; const float* h_ln1b = (const float*)d_in[39];
  const float* h_f1W = (const float*)d_in[40]; const float* h_f1b = (const float*)d_in[41];
  const float* h_f2W = (const float*)d_in[42]; const float* h_f2b = (const float*)d_in[43];
  const float* h_ln2g = (const float*)d_in[44]; const float* h_ln2b = (const float*)d_in[45];
  const float* oln1g = (const float*)d_in[46]; const float* oln1b = (const float*)d_in[47];
  const float* o1W = (const float*)d_in[48];   const float* o1b = (const float*)d_in[49];
  const float* oln2g = (const float*)d_in[50]; const float* oln2b = (const float*)d_in[51];
  const float* o2W = (const float*)d_in[52];   const float* o2b = (const float*)d_in[53];
  const float* oln3g = (const float*)d_in[54]; const float* oln3b = (const float*)d_in[55];
  const float* o3W = (const float*)d_in[56];   const float* o3b = (const float*)d_in[57];

  float* out_f = (float*)d_out;

  const int B = 8, S = 1024, M = B * S;
  const int R = 4097, KQ = 1025, KQP = 1056;

  float* ws = (float*)d_ws;
  size_t off = 0;
  auto alloc = [&](size_t nfloats) { size_t o = off; off += (nfloats + 255) & ~(size_t)255; return o; };
  auto allocs = [&](size_t nshorts) { return alloc((nshorts + 1) / 2); };

  size_t oE    = alloc((size_t)R * 256);
  size_t oSIGb = allocs((size_t)R * KQP);
  size_t oSSUM = alloc(R);
  size_t oQE   = alloc((size_t)M * 256);
  size_t oQEb  = allocs((size_t)M * 256);
  size_t oQA   = alloc((size_t)M * 512);
  size_t oQAb  = allocs((size_t)M * 512);
  size_t oYOb  = allocs((size_t)M * 512);
  size_t oXO   = alloc((size_t)M * 256);
  size_t oXOb  = allocs((size_t)M * 256);
  size_t oHO   = alloc((size_t)M * 256);
  size_t oS0   = alloc((size_t)M * 512);   // FFb arena (S0+S1)
  size_t oS1   = alloc((size_t)M * 512);
  size_t oS2b  = allocs((size_t)M * 512);
  size_t oS3   = alloc((size_t)M * 512);
  size_t oS4   = alloc((size_t)M * 512);
  size_t oSX   = alloc((size_t)M * 512);
  size_t oSXb  = allocs((size_t)M * 512);
  size_t oS0b  = allocs((size_t)M * 512);  // bf16 QK proj
  size_t oVt   = allocs((size_t)M * 512);  // bf16 transposed V
  size_t oWqe  = allocs((size_t)256 * KQP);
  size_t oWyk  = allocs((size_t)512 * 512);
  size_t oWyv  = allocs((size_t)512 * 512);
  size_t oWyo  = allocs((size_t)512 * 512);
  size_t oWyf1 = allocs((size_t)2048 * 512);
  size_t oWyf2 = allocs((size_t)512 * 2048);
  size_t oWxk  = allocs((size_t)256 * 256);
  size_t oWxv  = allocs((size_t)256 * 256);
  size_t oWxo  = allocs((size_t)256 * 256);
  size_t oWhk  = allocs((size_t)256 * 256);
  size_t oWhv  = allocs((size_t)512 * 512);
  size_t oWho  = allocs((size_t)256 * 512);
  size_t oWhf1 = allocs((size_t)2048 * 256);
  size_t oWhf2 = allocs((size_t)256 * 2048);
  size_t oWo1  = allocs((size_t)512 * 512);
  size_t oWo2  = allocs((size_t)256 * 512);
  (void)ws_size; (void)in_sizes; (void)n_in; (void)out_size;

  float* E    = ws + oE;
  unsigned short* SIGb = (unsigned short*)(ws + oSIGb);
  float* SSUM = ws + oSSUM;
  float* QE   = ws + oQE;   unsigned short* QEb = (unsigned short*)(ws + oQEb);
  float* QA   = ws + oQA;   unsigned short* QAb = (unsigned short*)(ws + oQAb);
  unsigned short* YOb = (unsigned short*)(ws + oYOb);
  float* XO   = ws + oXO;   unsigned short* XOb = (unsigned short*)(ws + oXOb);
  float* HO   = ws + oHO;
  float* S0   = ws + oS0;
  unsigned short* S2b = (unsigned short*)(ws + oS2b);
  float* S3   = ws + oS3;
  float* S4   = ws + oS4;
  float* SX   = ws + oSX;   unsigned short* SXb = (unsigned short*)(ws + oSXb);
  unsigned short* S0b = (unsigned short*)(ws + oS0b);
  unsigned short* Vt  = (unsigned short*)(ws + oVt);
  unsigned short* FFb = (unsigned short*)S0;

  unsigned short* Wqe  = (unsigned short*)(ws + oWqe);
  unsigned short* Wyk  = (unsigned short*)(ws + oWyk);
  unsigned short* Wyv  = (unsigned short*)(ws + oWyv);
  unsigned short* Wyo  = (unsigned short*)(ws + oWyo);
  unsigned short* Wyf1 = (unsigned short*)(ws + oWyf1);
  unsigned short* Wyf2 = (unsigned short*)(ws + oWyf2);
  unsigned short* Wxk  = (unsigned short*)(ws + oWxk);
  unsigned short* Wxv  = (unsigned short*)(ws + oWxv);
  unsigned short* Wxo  = (unsigned short*)(ws + oWxo);
  unsigned short* Whk  = (unsigned short*)(ws + oWhk);
  unsigned short* Whv  = (unsigned short*)(ws + oWhv);
  unsigned short* Who  = (unsigned short*)(ws + oWho);
  unsigned short* Whf1 = (unsigned short*)(ws + oWhf1);
  unsigned short* Whf2 = (unsigned short*)(ws + oWhf2);
  unsigned short* Wo1  = (unsigned short*)(ws + oWo1);
  unsigned short* Wo2  = (unsigned short*)(ws + oWo2);

  dim3 blk(256);
  int nElem512 = (8192 * 512 + 255) / 256;

  struct TD { const float* src; unsigned short* dst; int K, N, Kp; };
  const TD tds[] = {
    {qemb_W, Wqe, KQ, 256, KQP},
    {y_kW, Wyk, 512, 512, 512}, {y_vW, Wyv, 512, 512, 512}, {y_oW, Wyo, 512, 512, 512},
    {y_f1W, Wyf1, 512, 2048, 512}, {y_f2W, Wyf2, 2048, 512, 2048},
    {x_kW, Wxk, 256, 256, 256}, {x_vW, Wxv, 256, 256, 256}, {x_oW, Wxo, 256, 256, 256},
    {h_kW, Whk, 256, 256, 256}, {h_vW, Whv, 512, 512, 512}, {h_oW, Who, 512, 256, 512},
    {h_f1W, Whf1, 256, 2048, 256}, {h_f2W, Whf2, 2048, 256, 2048},
    {o1W, Wo1, 512, 512, 512}, {o2W, Wo2, 512, 256, 512},
  };
  for (const TD& t : tds) {
    dim3 g((t.N + 31) / 32, (t.Kp + 31) / 32);
    tconv_kernel<<<g, blk, 0, stream>>>(t.src, t.dst, t.K, t.N, t.Kp);
  }

  auto ggrid = [](int Mm, int Nn) { return dim3((unsigned)(Nn / 128), (unsigned)((Mm + 127) / 128)); };

  // 1. embedding table
  sig_kernel<<<R, blk, 0, stream>>>(pemb_W, SIGb, SSUM, KQ, KQP);
  mgemm_kernel<2, true, false, false><<<ggrid(R, 256), blk, 0, stream>>>(SIGb, Wqe, qemb_b, E, nullptr, nullptr, R, 256, KQP, SSUM);
  gather_kernel<<<nElem512, blk, 0, stream>>>(p_data, pa_data, E, diff_W, QE, QEb, QA, QAb);
  creg_kernel<<<1, blk, 0, stream>>>(p_data, diff_W, out_f + 8192);

  dim3 agrid(S / 16, B * NHEADS);
  dim3 ablk(512);
  dim3 lgrid(M / 4);

  // 2. y layer (dm=512, mask_k=1, zero_pad=0, FFN)
  mgemm_kernel<0, false, true, false><<<ggrid(M, 512), blk, 0, stream>>>(QAb, Wyk, y_kb, nullptr, S0b, nullptr, M, 512, 512, nullptr);
  mgemm_kernel<0, false, false, true><<<ggrid(M, 512), blk, 0, stream>>>(QAb, Wyv, y_vb, nullptr, nullptr, Vt, M, 512, 512, nullptr);
  attn4_kernel<64, 64, 1, 0><<<agrid, ablk, 0, stream>>>(S0b, Vt, y_gam, S2b, S, M);
  mgemm_kernel<0, true, false, false><<<ggrid(M, 512), blk, 0, stream>>>(S2b, Wyo, y_ob, S3, nullptr, nullptr, M, 512, 512, nullptr);
  ln4_kernel<512, true, true><<<lgrid, blk, 0, stream>>>(QA, S3, y_ln1g, y_ln1b, SX, SXb);
  mgemm_kernel<1, false, true, false><<<ggrid(M, 2048), blk, 0, stream>>>(SXb, Wyf1, y_f1b, nullptr, FFb, nullptr, M, 2048, 512, nullptr);
  mgemm_kernel<0, true, false, false><<<ggrid(M, 512), blk, 0, stream>>>(FFb, Wyf2, y_f2b, S4, nullptr, nullptr, M, 512, 2048, nullptr);
  ln4_kernel<512, false, true><<<lgrid, blk, 0, stream>>>(SX, S4, y_ln2g, y_ln2b, nullptr, YOb);

  // 3. x layer (dm=256, mask_k=1, zero_pad=0, no FFN)
  mgemm_kernel<0, false, true, false><<<ggrid(M, 256), blk, 0, stream>>>(QEb, Wxk, x_kb, nullptr, S0b, nullptr, M, 256, 256, nullptr);
  mgemm_kernel<0, false, false, true><<<ggrid(M, 256), blk, 0, stream>>>(QEb, Wxv, x_vb, nullptr, nullptr, Vt, M, 256, 256, nullptr);
  attn4_kernel<32, 32, 1, 0><<<agrid, ablk, 0, stream>>>(S0b, Vt, x_gam, S2b, S, M);
  mgemm_kernel<0, true, false, false><<<ggrid(M, 256), blk, 0, stream>>>(S2b, Wxo, x_ob, S3, nullptr, nullptr, M, 256, 256, nullptr);
  ln4_kernel<256, true, true><<<lgrid, blk, 0, stream>>>(QE, S3, x_ln1g, x_ln1b, XO, XOb);

  // 4. h layer (q,k from XO; v from YO; mask_k=0, zero_pad=1, FFN)
  mgemm_kernel<0, false, true, false><<<ggrid(M, 256), blk, 0, stream>>>(XOb, Whk, h_kb, nullptr, S0b, nullptr, M, 256, 256, nullptr);
  mgemm_kernel<0, false, false, true><<<ggrid(M, 512), blk, 0, stream>>>(YOb, Whv, h_vb, nullptr, nullptr, Vt, M, 512, 512, nullptr);
  attn4_kernel<32, 64, 0, 1><<<agrid, ablk, 0, stream>>>(S0b, Vt, h_gam, S2b, S, M);
  mgemm_kernel<0, true, false, false><<<ggrid(M, 256), blk, 0, stream>>>(S2b, Who, h_ob, S3, nullptr, nullptr, M, 256, 512, nullptr);
  ln4_kernel<256, true, true><<<lgrid, blk, 0, stream>>>(XO, S3, h_ln1g, h_ln1b, SX, SXb);
  mgemm_kernel<1, false, true, false><<<ggrid(M, 2048), blk, 0, stream>>>(SXb, Whf1, h_f1b, nullptr, FFb, nullptr, M, 2048, 256, nullptr);
  mgemm_kernel<0, true, false, false><<<ggrid(M, 256), blk, 0, stream>>>(FFb, Whf2, h_f2b, S4, nullptr, nullptr, M, 256, 2048, nullptr);
  ln4_kernel<256, true, false><<<lgrid, blk, 0, stream>>>(SX, S4, h_ln2g, h_ln2b, HO, nullptr);

  // 5. head: LN(concat) -> o1 -> LN -> o2 -> LN+dot
  lnc_kernel<<<lgrid, blk, 0, stream>>>(HO, QE, oln1g, oln1b, SXb);
  mgemm_kernel<1, true, false, false><<<ggrid(M, 512), blk, 0, stream>>>(SXb, Wo1, o1b, S3, nullptr, nullptr, M, 512, 512, nullptr);
  ln4_kernel<512, false, true><<<lgrid, blk, 0, stream>>>(S3, nullptr, oln2g, oln2b, nullptr, SXb);
  mgemm_kernel<1, true, false, false><<<ggrid(M, 256), blk, 0, stream>>>(SXb, Wo2, o2b, S4, nullptr, nullptr, M, 256, 512, nullptr);
  lndot_kernel<<<lgrid, blk, 0, stream>>>(S4, oln3g, oln3b, o3W, o3b, out_f);
}

// Round 6
// 894.776 us; speedup vs baseline: 11.2802x; 1.1326x over previous
//
#include <hip/hip_runtime.h>
#include <hip/hip_bf16.h>
#include <math.h>

#define NHEADS 8

typedef __attribute__((ext_vector_type(8))) __bf16 bfrag;
typedef __attribute__((ext_vector_type(4))) float f32x4;

static __device__ __forceinline__ unsigned short f2bf(float f) {
  unsigned u = __float_as_uint(f);
  unsigned r = (u + 0x7fffu + ((u >> 16) & 1u)) >> 16;
  return (unsigned short)r;
}

static __device__ __forceinline__ void gload_lds16(const void* g, void* l) {
  __builtin_amdgcn_global_load_lds(
      (const __attribute__((address_space(1))) unsigned int*)g,
      (__attribute__((address_space(3))) unsigned int*)l, 16, 0, 0);
}

static __device__ __forceinline__ float block_reduce_sum(float v, float* red) {
  int t = threadIdx.x;
  red[t] = v; __syncthreads();
  for (int s = 128; s > 0; s >>= 1) {
    if (t < s) red[t] += red[t + s];
    __syncthreads();
  }
  float r = red[0];
  __syncthreads();
  return r;
}

// ---------------- sigmoid table (bf16, padded to Kp) + row sums ----------------
__global__ __launch_bounds__(256) void sig_kernel(
    const float* __restrict__ Wp, unsigned short* __restrict__ Sgb,
    float* __restrict__ Ssum, int Kd, int Kp)
{
  __shared__ float red[256];
  int row = blockIdx.x;
  float s = 0.f;
  for (int k = threadIdx.x; k < Kp; k += 256) {
    float v = 0.f;
    if (k < Kd) {
      v = 1.f / (1.f + __expf(-Wp[(size_t)row * Kd + k]));
      s += v;
    }
    Sgb[(size_t)row * Kp + k] = f2bf(v);
  }
  float tot = block_reduce_sum(s, red);
  if (threadIdx.x == 0) Ssum[row] = tot;
}

// ---------------- fused transpose+convert for all weights ----------------
struct TDesc { const float* src; unsigned short* dst; int K, N, Kp, tilesX, blk0; };
struct TPack { TDesc d[16]; };

__global__ __launch_bounds__(256) void tconv_all_kernel(TPack P) {
  __shared__ float t[32][33];
  int bid = blockIdx.x;
  int di = 0;
  #pragma unroll
  for (int k = 1; k < 16; ++k) if (bid >= P.d[k].blk0) di = k;
  const float* src = P.d[di].src;
  unsigned short* dst = P.d[di].dst;
  int K = P.d[di].K, N = P.d[di].N, Kp = P.d[di].Kp, tilesX = P.d[di].tilesX;
  int local = bid - P.d[di].blk0;
  int bn = (local % tilesX) * 32;
  int bk = (local / tilesX) * 32;
  int tid = threadIdx.x;
  int tx = tid & 31, ty = tid >> 5;
  #pragma unroll
  for (int u = 0; u < 4; ++u) {
    int k = bk + ty + u * 8, n = bn + tx;
    t[ty + u * 8][tx] = (k < K && n < N) ? src[(size_t)k * N + n] : 0.f;
  }
  __syncthreads();
  #pragma unroll
  for (int u = 0; u < 4; ++u) {
    int n = bn + ty + u * 8, kk = bk + tx;
    if (n < N && kk < Kp)
      dst[(size_t)n * Kp + kk] = f2bf(t[tx][ty + u * 8]);
  }
}

// ---------------- MFMA bf16 GEMM: C = epi(A @ Bt^T + bias) ----------------
// BM in {128, 64}; N tile is always 128 cols.
template<int BM, int EPI, bool WF32, bool WBF, bool WTR>
__global__ __launch_bounds__(256) void mgemm_kernel(
    const unsigned short* __restrict__ A, const unsigned short* __restrict__ Bt,
    const float* __restrict__ bias, float* __restrict__ C,
    unsigned short* __restrict__ Cb, unsigned short* __restrict__ Ct,
    int M, int N, int K, const float* __restrict__ divv)
{
  constexpr int NJ = (BM == 128) ? 4 : 2;     // col frags per wave
  __shared__ __align__(16) unsigned short Als[BM * 32];
  __shared__ __align__(16) unsigned short Bls[128 * 32];
  const int tid = threadIdx.x;
  const int lane = tid & 63, w = tid >> 6;
  const int wm = (BM == 128) ? (w >> 1) : 0;
  const int wn = (BM == 128) ? (w & 1) : w;
  const int brow = blockIdx.y * BM, bcol = blockIdx.x * 128;

  f32x4 acc[4][NJ] = {};

  for (int k0 = 0; k0 < K; k0 += 32) {
    #pragma unroll
    for (int q = 0; q < 2; ++q) {
      int s = w * 128 + q * 64 + lane;
      int r = s >> 2, g = s & 3;
      int gs = g ^ (r & 3);
      int gc = bcol + r; if (gc > N - 1) gc = N - 1;
      gload_lds16(Bt + (size_t)gc * K + k0 + gs * 8,
                  (char*)Bls + (w * 2048 + q * 1024));
    }
    if constexpr (BM == 128) {
      #pragma unroll
      for (int q = 0; q < 2; ++q) {
        int s = w * 128 + q * 64 + lane;
        int r = s >> 2, g = s & 3;
        int gs = g ^ (r & 3);
        int gr = brow + r; if (gr > M - 1) gr = M - 1;
        gload_lds16(A + (size_t)gr * K + k0 + gs * 8,
                    (char*)Als + (w * 2048 + q * 1024));
      }
    } else {
      int s = w * 64 + lane;
      int r = s >> 2, g = s & 3;
      int gs = g ^ (r & 3);
      int gr = brow + r; if (gr > M - 1) gr = M - 1;
      gload_lds16(A + (size_t)gr * K + k0 + gs * 8,
                  (char*)Als + w * 1024);
    }
    __syncthreads();

    bfrag av[4], bv[NJ];
    #pragma unroll
    for (int f = 0; f < 4; ++f) {
      int rA = wm * 64 + f * 16 + (lane & 15);
      av[f] = *(const bfrag*)((const char*)Als + rA * 64 + ((((lane >> 4) ^ (rA & 3))) << 4));
    }
    #pragma unroll
    for (int f = 0; f < NJ; ++f) {
      int rB = wn * (16 * NJ) + f * 16 + (lane & 15);
      bv[f] = *(const bfrag*)((const char*)Bls + rB * 64 + ((((lane >> 4) ^ (rB & 3))) << 4));
    }
    #pragma unroll
    for (int i = 0; i < 4; ++i)
      #pragma unroll
      for (int j = 0; j < NJ; ++j)
        acc[i][j] = __builtin_amdgcn_mfma_f32_16x16x32_bf16(av[i], bv[j], acc[i][j], 0, 0, 0);
    __syncthreads();
  }

  #pragma unroll
  for (int i = 0; i < 4; ++i) {
    int gr0 = brow + wm * 64 + i * 16 + (lane >> 4) * 4;
    #pragma unroll
    for (int j = 0; j < NJ; ++j) {
      int gc = bcol + wn * (16 * NJ) + j * 16 + (lane & 15);
      float bsv = bias ? bias[gc] : 0.f;
      float vv[4];
      #pragma unroll
      for (int q = 0; q < 4; ++q) {
        int gr = gr0 + q;
        float v = acc[i][j][q] + bsv;
        if (EPI >= 1) v = fmaxf(v, 0.f);
        if (EPI == 2) v = (gr < M) ? v / divv[gr] : v;
        vv[q] = v;
      }
      #pragma unroll
      for (int q = 0; q < 4; ++q) {
        int gr = gr0 + q;
        if (gr >= M) continue;
        if (WF32) C[(size_t)gr * N + gc] = vv[q];
        if (WBF)  Cb[(size_t)gr * N + gc] = f2bf(vv[q]);
      }
      if (WTR) {
        ushort4 h4 = { f2bf(vv[0]), f2bf(vv[1]), f2bf(vv[2]), f2bf(vv[3]) };
        *(ushort4*)(Ct + (size_t)gc * M + gr0) = h4;
      }
    }
  }
}

// ---------------- embedding gather ----------------
__global__ __launch_bounds__(256) void gather_kernel(
    const int* __restrict__ p_data, const int* __restrict__ pa_data,
    const float* __restrict__ E, const float* __restrict__ diff_W,
    float* __restrict__ qemb, unsigned short* __restrict__ qembb,
    float* __restrict__ qaemb, unsigned short* __restrict__ qaembb)
{
  int idx = blockIdx.x * 256 + threadIdx.x;
  if (idx >= 8192 * 512) return;
  int row = idx >> 9, c = idx & 511;
  int p = p_data[row];
  float pid = diff_W[p];
  if (c < 256) {
    float v = E[(size_t)p * 256 + c] + pid;
    qemb[(size_t)row * 256 + c] = v;
    qembb[(size_t)row * 256 + c] = f2bf(v);
  }
  int pa = pa_data[row];
  int ppos = (pa > 4096) ? pa - 4096 : 0;
  int pneg = (pa <= 4096) ? pa : 0;
  float v = (c < 256) ? E[(size_t)ppos * 256 + c] : E[(size_t)pneg * 256 + (c - 256)];
  v += pid;
  qaemb[(size_t)row * 512 + c] = v;
  qaembb[(size_t)row * 512 + c] = f2bf(v);
}

// ---------------- c_reg ----------------
__global__ __launch_bounds__(256) void creg_kernel(
    const int* __restrict__ p_data, const float* __restrict__ dW,
    float* __restrict__ out)
{
  __shared__ float red[256];
  float s = 0.f;
  for (int i = threadIdx.x; i < 8192; i += 256) {
    float v = dW[p_data[i]];
    s += v * v;
  }
  float tot = block_reduce_sum(s, red);
  if (threadIdx.x == 0) out[0] = tot * 1e-5f;
}

// ---------------- MFMA distance-decay attention v5 ----------------
// 16 query rows per block, 512 threads (8 waves). CHUNK elems/lane in softmax;
// LDS row stride RS = 36*CHUNK+4 floats; addr(r,j) = r*RS + j + 4*(j>>5).
// Split-P (hi+lo bf16) PV for precision. Grid split along diagonal by CHUNK.
template<int DK, int DV, int MASKK, int ZP, int CHUNK>
__global__ __launch_bounds__(512, 4) void attn5_kernel(
    const unsigned short* __restrict__ QKb, const unsigned short* __restrict__ Vt,
    const float* __restrict__ gamp, unsigned short* __restrict__ O,
    int S, int MT, int bxoff)
{
  constexpr int RS = 36 * CHUNK + 4;
  const int DMK = NHEADS * DK, DMV = NHEADS * DV;
  const int i0 = (blockIdx.x + bxoff) * 16;
  const int b = blockIdx.y >> 3, h = blockIdx.y & 7;
  const int tid = threadIdx.x;
  const int lane = tid & 63, w = tid >> 6;
  const size_t rowbase = (size_t)b * S;

  constexpr int NP = (DV == 32) ? 6 : 4;
  __shared__ __align__(16) float sc[16 * RS];
  __shared__ float red[NP * 16 * 17];

  const int jmaxBlk = MASKK ? (i0 + 15) : (i0 + 14);
  const int nT = jmaxBlk / 64 + 1;
  const int NK = nT * 64;

  const int qr = lane & 15;
  const int ko8 = (lane >> 4) * 8;

  bfrag qf[DK / 32];
  #pragma unroll
  for (int ks = 0; ks < DK / 32; ++ks)
    qf[ks] = *(const bfrag*)(QKb + (rowbase + i0 + qr) * DMK + h * DK + ks * 32 + ko8);

  // ---- QK^T ----
  for (int t0 = 0; t0 < NK; t0 += 128) {
    int tt = t0 + (w >> 2) * 64;
    if (tt < NK) {
      int jb = tt + (w & 3) * 16 + qr;
      bfrag kf[DK / 32];
      #pragma unroll
      for (int ks = 0; ks < DK / 32; ++ks)
        kf[ks] = *(const bfrag*)(QKb + (rowbase + jb) * DMK + h * DK + ks * 32 + ko8);
      f32x4 accs = {};
      #pragma unroll
      for (int ks = 0; ks < DK / 32; ++ks)
        accs = __builtin_amdgcn_mfma_f32_16x16x32_bf16(qf[ks], kf[ks], accs, 0, 0, 0);
      int ja = jb + 4 * (jb >> 5);
      int r0 = (lane >> 4) * 4;
      #pragma unroll
      for (int q = 0; q < 4; ++q)
        sc[(r0 + q) * RS + ja] = accs[q];
    }
  }
  __syncthreads();

  // ---- softmax pipeline: group g (32 lanes) owns query row g; CHUNK elems/lane ----
  {
    const int g = tid >> 5, l = tid & 31;
    const int i = i0 + g;
    const int jmax = MASKK ? i : i - 1;
    const int jb0 = CHUNK * l;
    const int sb = g * RS + jb0 + 4 * (jb0 >> 5);
    const float rscale = rsqrtf((float)DK);

    float p[CHUNK];
    float m1 = -1e30f;
    #pragma unroll
    for (int c = 0; c < CHUNK / 4; ++c) {
      f32x4 v = *(const f32x4*)(sc + sb + c * 4);
      #pragma unroll
      for (int k = 0; k < 4; ++k) {
        int j = jb0 + c * 4 + k;
        float s = (j <= jmax) ? v[k] * rscale : -1e30f;
        p[c * 4 + k] = s;
        m1 = fmaxf(m1, s);
      }
    }
    #pragma unroll
    for (int o = 16; o > 0; o >>= 1) m1 = fmaxf(m1, __shfl_xor(m1, o, 32));

    float lloc = 0.f;
    #pragma unroll
    for (int t = 0; t < CHUNK; ++t) lloc += __expf(p[t] - m1);
    float l1 = lloc;
    #pragma unroll
    for (int o = 16; o > 0; o >>= 1) l1 += __shfl_xor(l1, o, 32);
    float inv1 = 1.f / l1;

    // exclusive prefix of normalized lane totals
    float scn = lloc * inv1;
    #pragma unroll
    for (int o = 1; o < 32; o <<= 1) {
      float u = __shfl_up(scn, o, 32);
      if (l >= o) scn += u;
    }
    float cum = scn - lloc * inv1;

    float gv = gamp[h];
    float sp = fmaxf(gv, 0.f) + log1pf(__expf(-fabsf(gv)));
    float gm = -sp;
    float m2 = -1e30f;
    #pragma unroll
    for (int t = 0; t < CHUNK; ++t) {
      int j = jb0 + t;
      cum += __expf(p[t] - m1) * inv1;
      float rem = fmaxf(1.f - cum, 0.f);
      float dist = sqrtf(rem * fabsf((float)(j - i)));
      float eff = __expf(gm * dist);
      eff = fminf(fmaxf(eff, 1e-5f), 1e5f);
      p[t] = p[t] * eff;
      m2 = fmaxf(m2, p[t]);
    }
    #pragma unroll
    for (int o = 16; o > 0; o >>= 1) m2 = fmaxf(m2, __shfl_xor(m2, o, 32));

    float l2 = 0.f;
    #pragma unroll
    for (int t = 0; t < CHUNK; ++t) { p[t] = __expf(p[t] - m2); l2 += p[t]; }
    #pragma unroll
    for (int o = 16; o > 0; o >>= 1) l2 += __shfl_xor(l2, o, 32);
    bool validrow = (jmax >= 0) && !(ZP && i == 0);
    float wgt = validrow ? (1.f / l2) : 0.f;
    #pragma unroll
    for (int c = 0; c < CHUNK / 4; ++c) {
      f32x4 v;
      #pragma unroll
      for (int k = 0; k < 4; ++k) v[k] = p[c * 4 + k] * wgt;
      *(f32x4*)(sc + sb + c * 4) = v;
    }
  }
  __syncthreads();

  // ---- PV: wave owns (d-block, tile-parity); split-P hi+lo ----
  const int dblk = (DV == 64) ? (w & 3) : (w & 1);
  const int par  = (DV == 64) ? (w >> 2) : (w >> 1);
  const int NPAR = (DV == 64) ? 2 : 4;
  const int NFIN = (DV == 64) ? 4 : 2;
  f32x4 acco = {};
  const int dcol = h * DV + dblk * 16 + (lane & 15);
  for (int t0 = par * 64; t0 < NK; t0 += NPAR * 64) {
    #pragma unroll
    for (int ks = 0; ks < 2; ++ks) {
      int jo = t0 + ks * 32 + ko8;
      int pa = qr * RS + jo + 4 * (jo >> 5);
      f32x4 p0 = *(const f32x4*)(sc + pa);
      f32x4 p1 = *(const f32x4*)(sc + pa + 4);
      bfrag ph, pl;
      #pragma unroll
      for (int e = 0; e < 4; ++e) {
        __bf16 h0 = (__bf16)p0[e];
        __bf16 h1 = (__bf16)p1[e];
        ph[e] = h0; ph[e + 4] = h1;
        pl[e] = (__bf16)(p0[e] - (float)h0);
        pl[e + 4] = (__bf16)(p1[e] - (float)h1);
      }
      bfrag vf = *(const bfrag*)(Vt + (size_t)dcol * MT + rowbase + jo);
      acco = __builtin_amdgcn_mfma_f32_16x16x32_bf16(pl, vf, acco, 0, 0, 0);
      acco = __builtin_amdgcn_mfma_f32_16x16x32_bf16(ph, vf, acco, 0, 0, 0);
    }
  }

  if (w >= NFIN) {
    #pragma unroll
    for (int q = 0; q < 4; ++q)
      red[(w - NFIN) * 272 + ((lane >> 4) * 4 + q) * 17 + (lane & 15)] = acco[q];
  }
  __syncthreads();
  if (w < NFIN) {
    for (int pp = w; pp < NP; pp += NFIN) {
      #pragma unroll
      for (int q = 0; q < 4; ++q)
        acco[q] += red[pp * 272 + ((lane >> 4) * 4 + q) * 17 + (lane & 15)];
    }
    int r0 = (lane >> 4) * 4;
    #pragma unroll
    for (int q = 0; q < 4; ++q)
      O[(rowbase + i0 + r0 + q) * DMV + dcol] = f2bf(acco[q]);
  }
}

// ---------------- LayerNorm v4: one row per wave, float4 loads ----------------
template<int D, bool WF, bool WB>
__global__ __launch_bounds__(256) void ln4_kernel(
    const float* __restrict__ X, const float* __restrict__ R,
    const float* __restrict__ g, const float* __restrict__ be,
    float* __restrict__ Y, unsigned short* __restrict__ Yb)
{
  constexpr int NC = D / 256;
  int row = blockIdx.x * 4 + (threadIdx.x >> 6);
  int lane = threadIdx.x & 63;
  const float* x = X + (size_t)row * D;
  f32x4 xv[NC];
  float s = 0.f;
  #pragma unroll
  for (int c = 0; c < NC; ++c) {
    xv[c] = *(const f32x4*)(x + c * 256 + lane * 4);
    if (R) {
      f32x4 rv = *(const f32x4*)(R + (size_t)row * D + c * 256 + lane * 4);
      #pragma unroll
      for (int k = 0; k < 4; ++k) xv[c][k] += rv[k];
    }
    #pragma unroll
    for (int k = 0; k < 4; ++k) s += xv[c][k];
  }
  #pragma unroll
  for (int o = 32; o > 0; o >>= 1) s += __shfl_xor(s, o, 64);
  float mean = s / (float)D;
  float vs = 0.f;
  #pragma unroll
  for (int c = 0; c < NC; ++c)
    #pragma unroll
    for (int k = 0; k < 4; ++k) { float d = xv[c][k] - mean; vs += d * d; }
  #pragma unroll
  for (int o = 32; o > 0; o >>= 1) vs += __shfl_xor(vs, o, 64);
  float rstd = rsqrtf(vs / (float)D + 1e-5f);
  #pragma unroll
  for (int c = 0; c < NC; ++c) {
    f32x4 gv = *(const f32x4*)(g + c * 256 + lane * 4);
    f32x4 bv = *(const f32x4*)(be + c * 256 + lane * 4);
    f32x4 ov;
    #pragma unroll
    for (int k = 0; k < 4; ++k) ov[k] = gv[k] * (xv[c][k] - mean) * rstd + bv[k];
    if (WF) *(f32x4*)(Y + (size_t)row * D + c * 256 + lane * 4) = ov;
    if (WB) {
      ushort4 h4 = { f2bf(ov[0]), f2bf(ov[1]), f2bf(ov[2]), f2bf(ov[3]) };
      *(ushort4*)(Yb + (size_t)row * D + c * 256 + lane * 4) = h4;
    }
  }
}

// ---------------- fused concat + LN (D=512) ----------------
__global__ __launch_bounds__(256) void lnc_kernel(
    const float* __restrict__ Xh, const float* __restrict__ Qe,
    const float* __restrict__ g, const float* __restrict__ be,
    unsigned short* __restrict__ Yb)
{
  int row = blockIdx.x * 4 + (threadIdx.x >> 6);
  int lane = threadIdx.x & 63;
  f32x4 xv[2];
  xv[0] = *(const f32x4*)(Xh + (size_t)row * 256 + lane * 4);
  xv[1] = *(const f32x4*)(Qe + (size_t)row * 256 + lane * 4);
  float s = 0.f;
  #pragma unroll
  for (int c = 0; c < 2; ++c)
    #pragma unroll
    for (int k = 0; k < 4; ++k) s += xv[c][k];
  #pragma unroll
  for (int o = 32; o > 0; o >>= 1) s += __shfl_xor(s, o, 64);
  float mean = s / 512.f;
  float vs = 0.f;
  #pragma unroll
  for (int c = 0; c < 2; ++c)
    #pragma unroll
    for (int k = 0; k < 4; ++k) { float d = xv[c][k] - mean; vs += d * d; }
  #pragma unroll
  for (int o = 32; o > 0; o >>= 1) vs += __shfl_xor(vs, o, 64);
  float rstd = rsqrtf(vs / 512.f + 1e-5f);
  #pragma unroll
  for (int c = 0; c < 2; ++c) {
    f32x4 gv = *(const f32x4*)(g + c * 256 + lane * 4);
    f32x4 bv = *(const f32x4*)(be + c * 256 + lane * 4);
    ushort4 h4;
    #pragma unroll
    for (int k = 0; k < 4; ++k) {
      float ov = gv[k] * (xv[c][k] - mean) * rstd + bv[k];
      ((unsigned short*)&h4)[k] = f2bf(ov);
    }
    *(ushort4*)(Yb + (size_t)row * 512 + c * 256 + lane * 4) = h4;
  }
}

// ---------------- fused LN(D=256) + dot ----------------
__global__ __launch_bounds__(256) void lndot_kernel(
    const float* __restrict__ X, const float* __restrict__ g,
    const float* __restrict__ be, const float* __restrict__ w3,
    const float* __restrict__ b3, float* __restrict__ out)
{
  int row = blockIdx.x * 4 + (threadIdx.x >> 6);
  int lane = threadIdx.x & 63;
  f32x4 v = *(const f32x4*)(X + (size_t)row * 256 + lane * 4);
  float s = v[0] + v[1] + v[2] + v[3];
  #pragma unroll
  for (int o = 32; o > 0; o >>= 1) s += __shfl_xor(s, o, 64);
  float mean = s / 256.f;
  float vs = 0.f;
  #pragma unroll
  for (int k = 0; k < 4; ++k) { float d = v[k] - mean; vs += d * d; }
  #pragma unroll
  for (int o = 32; o > 0; o >>= 1) vs += __shfl_xor(vs, o, 64);
  float rstd = rsqrtf(vs / 256.f + 1e-5f);
  f32x4 gv = *(const f32x4*)(g + lane * 4);
  f32x4 bv = *(const f32x4*)(be + lane * 4);
  f32x4 wv = *(const f32x4*)(w3 + lane * 4);
  float d = 0.f;
  #pragma unroll
  for (int k = 0; k < 4; ++k)
    d += (gv[k] * (v[k] - mean) * rstd + bv[k]) * wv[k];
  #pragma unroll
  for (int o = 32; o > 0; o >>= 1) d += __shfl_xor(d, o, 64);
  if (lane == 0) out[row] = d + b3[0];
}

// ---------------- launch ----------------
extern "C" void kernel_launch(void* const* d_in, const int* in_sizes, int n_in,
                              void* d_out, int out_size, void* d_ws, size_t ws_size,
                              hipStream_t stream) {
  const int* p_data  = (const int*)d_in[0];
  const int* pa_data = (const int*)d_in[1];
  const float* pemb_W = (const float*)d_in[3];
  const float* diff_W = (const float*)d_in[4];
  const float* qemb_W = (const float*)d_in[5];
  const float* qemb_b = (const float*)d_in[6];
  const float* y_kW = (const float*)d_in[7];   const float* y_kb = (const float*)d_in[8];
  const float* y_vW = (const float*)d_in[9];   const float* y_vb = (const float*)d_in[10];
  const float* y_oW = (const float*)d_in[11];  const float* y_ob = (const float*)d_in[12];
  const float* y_gam = (const float*)d_in[13];
  const float* y_ln1g = (const float*)d_in[14]; const float* y_ln1b = (const float*)d_in[15];
  const float* y_f1W = (const float*)d_in[16]; const float* y_f1b = (const float*)d_in[17];
  const float* y_f2W = (const float*)d_in[18]; const float* y_f2b = (const float*)d_in[19];
  const float* y_ln2g = (const float*)d_in[20]; const float* y_ln2b = (const float*)d_in[21];
  const float* x_kW = (const float*)d_in[22];  const float* x_kb = (const float*)d_in[23];
  const float* x_vW = (const float*)d_in[24];  const float* x_vb = (const float*)d_in[25];
  const float* x_oW = (const float*)d_in[26];  const float* x_ob = (const float*)d_in[27];
  const float* x_gam = (const float*)d_in[28];
  const float* x_ln1g = (const float*)d_in[29]; const float* x_ln1b = (const float*)d_in[30];
  const float* h_kW = (const float*)d_in[31];  const float* h_kb = (const float*)d_in[32];
  const float* h_vW = (const float*)d_in[33];  const float* h_vb = (const float*)d_in[34];
  const float* h_oW = (const float*)d_in[35];  const float* h_ob = (const float*)d_in[36];
  const float* h_gam = (const float*)d_in[37];
  const float* h_ln1g = (const float*)d_in[38]; const float* h_ln1b = (const float*)d_in[39];
  const float* h_f1W = (const float*)d_in[40]; const float* h_f1b = (const float*)d_in[41];
  const float* h_f2W = (const float*)d_in[42]; const float* h_f2b = (const float*)d_in[43];
  const float* h_ln2g = (const float*)d_in[44]; const float* h_ln2b = (const float*)d_in[45];
  const float* oln1g = (const float*)d_in[46]; const float* oln1b = (const float*)d_in[47];
  const float* o1W = (const float*)d_in[48];   const float* o1b = (const float*)d_in[49];
  const float* oln2g = (const float*)d_in[50]; const float* oln2b = (const float*)d_in[51];
  const float* o2W = (const float*)d_in[52];   const float* o2b = (const float*)d_in[53];
  const float* oln3g = (const float*)d_in[54]; const float* oln3b = (const float*)d_in[55];
  const float* o3W = (const float*)d_in[56];   const float* o3b = (const float*)d_in[57];

  float* out_f = (float*)d_out;

  const int B = 8, S = 1024, M = B * S;
  const int R = 4097, KQ = 1025, KQP = 1056;

  float* ws = (float*)d_ws;
  size_t off = 0;
  auto alloc = [&](size_t nfloats) { size_t o = off; off += (nfloats + 255) & ~(size_t)255; return o; };
  auto allocs = [&](size_t nshorts) { return alloc((nshorts + 1) / 2); };

  size_t oE    = alloc((size_t)R * 256);
  size_t oSIGb = allocs((size_t)R * KQP);
  size_t oSSUM = alloc(R);
  size_t oQE   = alloc((size_t)M * 256);
  size_t oQEb  = allocs((size_t)M * 256);
  size_t oQA   = alloc((size_t)M * 512);
  size_t oQAb  = allocs((size_t)M * 512);
  size_t oYOb  = allocs((size_t)M * 512);
  size_t oXO   = alloc((size_t)M * 256);
  size_t oXOb  = allocs((size_t)M * 256);
  size_t oHO   = alloc((size_t)M * 256);
  size_t oS0   = alloc((size_t)M * 512);   // FFb arena (S0+S1)
  size_t oS1   = alloc((size_t)M * 512);
  size_t oS2b  = allocs((size_t)M * 512);
  size_t oS3   = alloc((size_t)M * 512);
  size_t oS4   = alloc((size_t)M * 512);
  size_t oSX   = alloc((size_t)M * 512);
  size_t oSXb  = allocs((size_t)M * 512);
  size_t oS0b  = allocs((size_t)M * 512);
  size_t oVt   = allocs((size_t)M * 512);
  size_t oWqe  = allocs((size_t)256 * KQP);
  size_t oWyk  = allocs((size_t)512 * 512);
  size_t oWyv  = allocs((size_t)512 * 512);
  size_t oWyo  = allocs((size_t)512 * 512);
  size_t oWyf1 = allocs((size_t)2048 * 512);
  size_t oWyf2 = allocs((size_t)512 * 2048);
  size_t oWxk  = allocs((size_t)256 * 256);
  size_t oWxv  = allocs((size_t)256 * 256);
  size_t oWxo  = allocs((size_t)256 * 256);
  size_t oWhk  = allocs((size_t)256 * 256);
  size_t oWhv  = allocs((size_t)512 * 512);
  size_t oWho  = allocs((size_t)256 * 512);
  size_t oWhf1 = allocs((size_t)2048 * 256);
  size_t oWhf2 = allocs((size_t)256 * 2048);
  size_t oWo1  = allocs((size_t)512 * 512);
  size_t oWo2  = allocs((size_t)256 * 512);
  (void)ws_size; (void)in_sizes; (void)n_in; (void)out_size;

  float* E    = ws + oE;
  unsigned short* SIGb = (unsigned short*)(ws + oSIGb);
  float* SSUM = ws + oSSUM;
  float* QE   = ws + oQE;   unsigned short* QEb = (unsigned short*)(ws + oQEb);
  float* QA   = ws + oQA;   unsigned short* QAb = (unsigned short*)(ws + oQAb);
  unsigned short* YOb = (unsigned short*)(ws + oYOb);
  float* XO   = ws + oXO;   unsigned short* XOb = (unsigned short*)(ws + oXOb);
  float* HO   = ws + oHO;
  float* S0   = ws + oS0;
  unsigned short* S2b = (unsigned short*)(ws + oS2b);
  float* S3   = ws + oS3;
  float* S4   = ws + oS4;
  float* SX   = ws + oSX;   unsigned short* SXb = (unsigned short*)(ws + oSXb);
  unsigned short* S0b = (unsigned short*)(ws + oS0b);
  unsigned short* Vt  = (unsigned short*)(ws + oVt);
  unsigned short* FFb = (unsigned short*)S0;

  unsigned short* Wqe  = (unsigned short*)(ws + oWqe);
  unsigned short* Wyk  = (unsigned short*)(ws + oWyk);
  unsigned short* Wyv  = (unsigned short*)(ws + oWyv);
  unsigned short* Wyo  = (unsigned short*)(ws + oWyo);
  unsigned short* Wyf1 = (unsigned short*)(ws + oWyf1);
  unsigned short* Wyf2 = (unsigned short*)(ws + oWyf2);
  unsigned short* Wxk  = (unsigned short*)(ws + oWxk);
  unsigned short* Wxv  = (unsigned short*)(ws + oWxv);
  unsigned short* Wxo  = (unsigned short*)(ws + oWxo);
  unsigned short* Whk  = (unsigned short*)(ws + oWhk);
  unsigned short* Whv  = (unsigned short*)(ws + oWhv);
  unsigned short* Who  = (unsigned short*)(ws + oWho);
  unsigned short* Whf1 = (unsigned short*)(ws + oWhf1);
  unsigned short* Whf2 = (unsigned short*)(ws + oWhf2);
  unsigned short* Wo1  = (unsigned short*)(ws + oWo1);
  unsigned short* Wo2  = (unsigned short*)(ws + oWo2);

  dim3 blk(256);
  int nElem512 = (8192 * 512 + 255) / 256;

  // ---- fused weight transposes ----
  {
    struct HD { const float* src; unsigned short* dst; int K, N, Kp; };
    const HD hd[16] = {
      {qemb_W, Wqe, KQ, 256, KQP},
      {y_kW, Wyk, 512, 512, 512}, {y_vW, Wyv, 512, 512, 512}, {y_oW, Wyo, 512, 512, 512},
      {y_f1W, Wyf1, 512, 2048, 512}, {y_f2W, Wyf2, 2048, 512, 2048},
      {x_kW, Wxk, 256, 256, 256}, {x_vW, Wxv, 256, 256, 256}, {x_oW, Wxo, 256, 256, 256},
      {h_kW, Whk, 256, 256, 256}, {h_vW, Whv, 512, 512, 512}, {h_oW, Who, 512, 256, 512},
      {h_f1W, Whf1, 256, 2048, 256}, {h_f2W, Whf2, 2048, 256, 2048},
      {o1W, Wo1, 512, 512, 512}, {o2W, Wo2, 512, 256, 512},
    };
    TPack P;
    int tot = 0;
    for (int k = 0; k < 16; ++k) {
      int tx = (hd[k].N + 31) / 32, ty = (hd[k].Kp + 31) / 32;
      P.d[k] = { hd[k].src, hd[k].dst, hd[k].K, hd[k].N, hd[k].Kp, tx, tot };
      tot += tx * ty;
    }
    tconv_all_kernel<<<dim3(tot), blk, 0, stream>>>(P);
  }

  auto gg128 = [](int Mm, int Nn) { return dim3((unsigned)(Nn / 128), (unsigned)((Mm + 127) / 128)); };
  auto gg64  = [](int Mm, int Nn) { return dim3((unsigned)(Nn / 128), (unsigned)((Mm + 63) / 64)); };

  // 1. embedding table
  sig_kernel<<<R, blk, 0, stream>>>(pemb_W, SIGb, SSUM, KQ, KQP);
  mgemm_kernel<64, 2, true, false, false><<<gg64(R, 256), blk, 0, stream>>>(SIGb, Wqe, qemb_b, E, nullptr, nullptr, R, 256, KQP, SSUM);
  gather_kernel<<<nElem512, blk, 0, stream>>>(p_data, pa_data, E, diff_W, QE, QEb, QA, QAb);
  creg_kernel<<<1, blk, 0, stream>>>(p_data, diff_W, out_f + 8192);

  dim3 ablk(512);
  dim3 lgrid(M / 4);
  dim3 agA(16, B * NHEADS), agB(16, B * NHEADS), agC(32, B * NHEADS);

  // 2. y layer (dm=512, mask_k=1, zero_pad=0, FFN)
  mgemm_kernel<128, 0, false, true, false><<<gg128(M, 512), blk, 0, stream>>>(QAb, Wyk, y_kb, nullptr, S0b, nullptr, M, 512, 512, nullptr);
  mgemm_kernel<128, 0, false, false, true><<<gg128(M, 512), blk, 0, stream>>>(QAb, Wyv, y_vb, nullptr, nullptr, Vt, M, 512, 512, nullptr);
  attn5_kernel<64, 64, 1, 0, 8><<<agA, ablk, 0, stream>>>(S0b, Vt, y_gam, S2b, S, M, 0);
  attn5_kernel<64, 64, 1, 0, 16><<<agB, ablk, 0, stream>>>(S0b, Vt, y_gam, S2b, S, M, 16);
  attn5_kernel<64, 64, 1, 0, 32><<<agC, ablk, 0, stream>>>(S0b, Vt, y_gam, S2b, S, M, 32);
  mgemm_kernel<128, 0, true, false, false><<<gg128(M, 512), blk, 0, stream>>>(S2b, Wyo, y_ob, S3, nullptr, nullptr, M, 512, 512, nullptr);
  ln4_kernel<512, true, true><<<lgrid, blk, 0, stream>>>(QA, S3, y_ln1g, y_ln1b, SX, SXb);
  mgemm_kernel<128, 1, false, true, false><<<gg128(M, 2048), blk, 0, stream>>>(SXb, Wyf1, y_f1b, nullptr, FFb, nullptr, M, 2048, 512, nullptr);
  mgemm_kernel<128, 0, true, false, false><<<gg128(M, 512), blk, 0, stream>>>(FFb, Wyf2, y_f2b, S4, nullptr, nullptr, M, 512, 2048, nullptr);
  ln4_kernel<512, false, true><<<lgrid, blk, 0, stream>>>(SX, S4, y_ln2g, y_ln2b, nullptr, YOb);

  // 3. x layer (dm=256, mask_k=1, zero_pad=0, no FFN)
  mgemm_kernel<64, 0, false, true, false><<<gg64(M, 256), blk, 0, stream>>>(QEb, Wxk, x_kb, nullptr, S0b, nullptr, M, 256, 256, nullptr);
  mgemm_kernel<64, 0, false, false, true><<<gg64(M, 256), blk, 0, stream>>>(QEb, Wxv, x_vb, nullptr, nullptr, Vt, M, 256, 256, nullptr);
  attn5_kernel<32, 32, 1, 0, 8><<<agA, ablk, 0, stream>>>(S0b, Vt, x_gam, S2b, S, M, 0);
  attn5_kernel<32, 32, 1, 0, 16><<<agB, ablk, 0, stream>>>(S0b, Vt, x_gam, S2b, S, M, 16);
  attn5_kernel<32, 32, 1, 0, 32><<<agC, ablk, 0, stream>>>(S0b, Vt, x_gam, S2b, S, M, 32);
  mgemm_kernel<64, 0, true, false, false><<<gg64(M, 256), blk, 0, stream>>>(S2b, Wxo, x_ob, S3, nullptr, nullptr, M, 256, 256, nullptr);
  ln4_kernel<256, true, true><<<lgrid, blk, 0, stream>>>(QE, S3, x_ln1g, x_ln1b, XO, XOb);

  // 4. h layer (q,k from XO; v from YO; mask_k=0, zero_pad=1, FFN)
  mgemm_kernel<64, 0, false, true, false><<<gg64(M, 256), blk, 0, stream>>>(XOb, Whk, h_kb, nullptr, S0b, nullptr, M, 256, 256, nullptr);
  mgemm_kernel<128, 0, false, false, true><<<gg128(M, 512), blk, 0, stream>>>(YOb, Whv, h_vb, nullptr, nullptr, Vt, M, 512, 512, nullptr);
  attn5_kernel<32, 64, 0, 1, 8><<<agA, ablk, 0, stream>>>(S0b, Vt, h_gam, S2b, S, M, 0);
  attn5_kernel<32, 64, 0, 1, 16><<<agB, ablk, 0, stream>>>(S0b, Vt, h_gam, S2b, S, M, 16);
  attn5_kernel<32, 64, 0, 1, 32><<<agC, ablk, 0, stream>>>(S0b, Vt, h_gam, S2b, S, M, 32);
  mgemm_kernel<64, 0, true, false, false><<<gg64(M, 256), blk, 0, stream>>>(S2b, Who, h_ob, S3, nullptr, nullptr, M, 256, 512, nullptr);
  ln4_kernel<256, true, true><<<lgrid, blk, 0, stream>>>(XO, S3, h_ln1g, h_ln1b, SX, SXb);
  mgemm_kernel<128, 1, false, true, false><<<gg128(M, 2048), blk, 0, stream>>>(SXb, Whf1, h_f1b, nullptr, FFb, nullptr, M, 2048, 256, nullptr);
  mgemm_kernel<64, 0, true, false, false><<<gg64(M, 256), blk, 0, stream>>>(FFb, Whf2, h_f2b, S4, nullptr, nullptr, M, 256, 2048, nullptr);
  ln4_kernel<256, true, false><<<lgrid, blk, 0, stream>>>(SX, S4, h_ln2g, h_ln2b, HO, nullptr);

  // 5. head: LN(concat) -> o1 -> LN -> o2 -> LN+dot
  lnc_kernel<<<lgrid, blk, 0, stream>>>(HO, QE, oln1g, oln1b, SXb);
  mgemm_kernel<128, 1, true, false, false><<<gg128(M, 512), blk, 0, stream>>>(SXb, Wo1, o1b, S3, nullptr, nullptr, M, 512, 512, nullptr);
  ln4_kernel<512, false, true><<<lgrid, blk, 0, stream>>>(S3, nullptr, oln2g, oln2b, nullptr, SXb);
  mgemm_kernel<64, 1, true, false, false><<<gg64(M, 256), blk, 0, stream>>>(SXb, Wo2, o2b, S4, nullptr, nullptr, M, 256, 512, nullptr);
  lndot_kernel<<<lgrid, blk, 0, stream>>>(S4, oln3g, oln3b, o3W, o3b, out_f);
}

// Round 7
// 877.494 us; speedup vs baseline: 11.5024x; 1.0197x over previous
//
#include <hip/hip_runtime.h>
#include <hip/hip_bf16.h>
#include <math.h>

#define NHEADS 8

typedef __attribute__((ext_vector_type(8))) __bf16 bfrag;
typedef __attribute__((ext_vector_type(4))) float f32x4;

static __device__ __forceinline__ unsigned short f2bf(float f) {
  unsigned u = __float_as_uint(f);
  unsigned r = (u + 0x7fffu + ((u >> 16) & 1u)) >> 16;
  return (unsigned short)r;
}

static __device__ __forceinline__ void gload_lds16(const void* g, void* l) {
  __builtin_amdgcn_global_load_lds(
      (const __attribute__((address_space(1))) unsigned int*)g,
      (__attribute__((address_space(3))) unsigned int*)l, 16, 0, 0);
}

static __device__ __forceinline__ float block_reduce_sum(float v, float* red) {
  int t = threadIdx.x;
  red[t] = v; __syncthreads();
  for (int s = 128; s > 0; s >>= 1) {
    if (t < s) red[t] += red[t + s];
    __syncthreads();
  }
  float r = red[0];
  __syncthreads();
  return r;
}

// ---------------- sigmoid table (bf16, padded to Kp) + row sums ----------------
__global__ __launch_bounds__(256) void sig_kernel(
    const float* __restrict__ Wp, unsigned short* __restrict__ Sgb,
    float* __restrict__ Ssum, int Kd, int Kp)
{
  __shared__ float red[256];
  int row = blockIdx.x;
  float s = 0.f;
  for (int k = threadIdx.x; k < Kp; k += 256) {
    float v = 0.f;
    if (k < Kd) {
      v = 1.f / (1.f + __expf(-Wp[(size_t)row * Kd + k]));
      s += v;
    }
    Sgb[(size_t)row * Kp + k] = f2bf(v);
  }
  float tot = block_reduce_sum(s, red);
  if (threadIdx.x == 0) Ssum[row] = tot;
}

// ---------------- fused transpose+convert for all weights ----------------
struct TDesc { const float* src; unsigned short* dst; int K, N, Kp, tilesX, blk0; };
struct TPack { TDesc d[16]; };

__global__ __launch_bounds__(256) void tconv_all_kernel(TPack P) {
  __shared__ float t[32][33];
  int bid = blockIdx.x;
  int di = 0;
  #pragma unroll
  for (int k = 1; k < 16; ++k) if (bid >= P.d[k].blk0) di = k;
  const float* src = P.d[di].src;
  unsigned short* dst = P.d[di].dst;
  int K = P.d[di].K, N = P.d[di].N, Kp = P.d[di].Kp, tilesX = P.d[di].tilesX;
  int local = bid - P.d[di].blk0;
  int bn = (local % tilesX) * 32;
  int bk = (local / tilesX) * 32;
  int tid = threadIdx.x;
  int tx = tid & 31, ty = tid >> 5;
  #pragma unroll
  for (int u = 0; u < 4; ++u) {
    int k = bk + ty + u * 8, n = bn + tx;
    t[ty + u * 8][tx] = (k < K && n < N) ? src[(size_t)k * N + n] : 0.f;
  }
  __syncthreads();
  #pragma unroll
  for (int u = 0; u < 4; ++u) {
    int n = bn + ty + u * 8, kk = bk + tx;
    if (n < N && kk < Kp)
      dst[(size_t)n * Kp + kk] = f2bf(t[tx][ty + u * 8]);
  }
}

// ---------------- MFMA bf16 GEMM: C = epi(A @ Bt^T + bias) ----------------
// BM in {128, 64}; N tile is always 128 cols.
// Outputs: WF32 -> C fp32; WBF -> Cb bf16; WTR -> Ct bf16 [N][M].
// WBF && WTR == split mode: cols < Nk -> Cb (stride Nk, bias), cols >= Nk -> Ct (bias2).
template<int BM, int EPI, bool WF32, bool WBF, bool WTR>
__global__ __launch_bounds__(256) void mgemm_kernel(
    const unsigned short* __restrict__ A, const unsigned short* __restrict__ Bt,
    const float* __restrict__ bias, float* __restrict__ C,
    unsigned short* __restrict__ Cb, unsigned short* __restrict__ Ct,
    int M, int N, int K, const float* __restrict__ divv,
    const float* __restrict__ bias2, int Nk)
{
  constexpr int NJ = (BM == 128) ? 4 : 2;
  constexpr bool SPLIT = WBF && WTR;
  __shared__ __align__(16) unsigned short Als[BM * 32];
  __shared__ __align__(16) unsigned short Bls[128 * 32];
  const int tid = threadIdx.x;
  const int lane = tid & 63, w = tid >> 6;
  const int wm = (BM == 128) ? (w >> 1) : 0;
  const int wn = (BM == 128) ? (w & 1) : w;
  const int brow = blockIdx.y * BM, bcol = blockIdx.x * 128;

  f32x4 acc[4][NJ] = {};

  for (int k0 = 0; k0 < K; k0 += 32) {
    #pragma unroll
    for (int q = 0; q < 2; ++q) {
      int s = w * 128 + q * 64 + lane;
      int r = s >> 2, g = s & 3;
      int gs = g ^ (r & 3);
      int gc = bcol + r; if (gc > N - 1) gc = N - 1;
      gload_lds16(Bt + (size_t)gc * K + k0 + gs * 8,
                  (char*)Bls + (w * 2048 + q * 1024));
    }
    if constexpr (BM == 128) {
      #pragma unroll
      for (int q = 0; q < 2; ++q) {
        int s = w * 128 + q * 64 + lane;
        int r = s >> 2, g = s & 3;
        int gs = g ^ (r & 3);
        int gr = brow + r; if (gr > M - 1) gr = M - 1;
        gload_lds16(A + (size_t)gr * K + k0 + gs * 8,
                    (char*)Als + (w * 2048 + q * 1024));
      }
    } else {
      int s = w * 64 + lane;
      int r = s >> 2, g = s & 3;
      int gs = g ^ (r & 3);
      int gr = brow + r; if (gr > M - 1) gr = M - 1;
      gload_lds16(A + (size_t)gr * K + k0 + gs * 8,
                  (char*)Als + w * 1024);
    }
    __syncthreads();

    bfrag av[4], bv[NJ];
    #pragma unroll
    for (int f = 0; f < 4; ++f) {
      int rA = wm * 64 + f * 16 + (lane & 15);
      av[f] = *(const bfrag*)((const char*)Als + rA * 64 + ((((lane >> 4) ^ (rA & 3))) << 4));
    }
    #pragma unroll
    for (int f = 0; f < NJ; ++f) {
      int rB = wn * (16 * NJ) + f * 16 + (lane & 15);
      bv[f] = *(const bfrag*)((const char*)Bls + rB * 64 + ((((lane >> 4) ^ (rB & 3))) << 4));
    }
    #pragma unroll
    for (int i = 0; i < 4; ++i)
      #pragma unroll
      for (int j = 0; j < NJ; ++j)
        acc[i][j] = __builtin_amdgcn_mfma_f32_16x16x32_bf16(av[i], bv[j], acc[i][j], 0, 0, 0);
    __syncthreads();
  }

  #pragma unroll
  for (int i = 0; i < 4; ++i) {
    int gr0 = brow + wm * 64 + i * 16 + (lane >> 4) * 4;
    #pragma unroll
    for (int j = 0; j < NJ; ++j) {
      int gc = bcol + wn * (16 * NJ) + j * 16 + (lane & 15);
      float bsv;
      if (SPLIT) bsv = (gc < Nk) ? bias[gc] : bias2[gc - Nk];
      else       bsv = bias ? bias[gc] : 0.f;
      float vv[4];
      #pragma unroll
      for (int q = 0; q < 4; ++q) {
        int gr = gr0 + q;
        float v = acc[i][j][q] + bsv;
        if (EPI >= 1) v = fmaxf(v, 0.f);
        if (EPI == 2) v = (gr < M) ? v / divv[gr] : v;
        vv[q] = v;
      }
      if (SPLIT) {
        if (gc < Nk) {
          #pragma unroll
          for (int q = 0; q < 4; ++q) {
            int gr = gr0 + q;
            if (gr < M) Cb[(size_t)gr * Nk + gc] = f2bf(vv[q]);
          }
        } else {
          ushort4 h4 = { f2bf(vv[0]), f2bf(vv[1]), f2bf(vv[2]), f2bf(vv[3]) };
          *(ushort4*)(Ct + (size_t)(gc - Nk) * M + gr0) = h4;
        }
      } else {
        #pragma unroll
        for (int q = 0; q < 4; ++q) {
          int gr = gr0 + q;
          if (gr >= M) continue;
          if (WF32) C[(size_t)gr * N + gc] = vv[q];
          if (WBF)  Cb[(size_t)gr * N + gc] = f2bf(vv[q]);
        }
        if (WTR) {
          ushort4 h4 = { f2bf(vv[0]), f2bf(vv[1]), f2bf(vv[2]), f2bf(vv[3]) };
          *(ushort4*)(Ct + (size_t)gc * M + gr0) = h4;
        }
      }
    }
  }
}

// ---------------- embedding gather ----------------
__global__ __launch_bounds__(256) void gather_kernel(
    const int* __restrict__ p_data, const int* __restrict__ pa_data,
    const float* __restrict__ E, const float* __restrict__ diff_W,
    float* __restrict__ qemb, unsigned short* __restrict__ qembb,
    float* __restrict__ qaemb, unsigned short* __restrict__ qaembb)
{
  int idx = blockIdx.x * 256 + threadIdx.x;
  if (idx >= 8192 * 512) return;
  int row = idx >> 9, c = idx & 511;
  int p = p_data[row];
  float pid = diff_W[p];
  if (c < 256) {
    float v = E[(size_t)p * 256 + c] + pid;
    qemb[(size_t)row * 256 + c] = v;
    qembb[(size_t)row * 256 + c] = f2bf(v);
  }
  int pa = pa_data[row];
  int ppos = (pa > 4096) ? pa - 4096 : 0;
  int pneg = (pa <= 4096) ? pa : 0;
  float v = (c < 256) ? E[(size_t)ppos * 256 + c] : E[(size_t)pneg * 256 + (c - 256)];
  v += pid;
  qaemb[(size_t)row * 512 + c] = v;
  qaembb[(size_t)row * 512 + c] = f2bf(v);
}

// ---------------- c_reg ----------------
__global__ __launch_bounds__(256) void creg_kernel(
    const int* __restrict__ p_data, const float* __restrict__ dW,
    float* __restrict__ out)
{
  __shared__ float red[256];
  float s = 0.f;
  for (int i = threadIdx.x; i < 8192; i += 256) {
    float v = dW[p_data[i]];
    s += v * v;
  }
  float tot = block_reduce_sum(s, red);
  if (threadIdx.x == 0) out[0] = tot * 1e-5f;
}

// ---------------- MFMA distance-decay attention v6 ----------------
// 16 query rows per block, 512 threads (8 waves). CHUNK elems/lane in softmax;
// LDS row stride RS = 36*CHUNK+4 floats; addr(r,j) = r*RS + j + 4*(j>>5).
// XCD-aware bijective block swizzle (each XCD owns 8 complete (b,h) pairs).
template<int DK, int DV, int MASKK, int ZP, int CHUNK>
__global__ __launch_bounds__(512, 4) void attn5_kernel(
    const unsigned short* __restrict__ QKb, const unsigned short* __restrict__ Vt,
    const float* __restrict__ gamp, unsigned short* __restrict__ O,
    int S, int MT, int bxoff)
{
  constexpr int RS = 36 * CHUNK + 4;
  const int DMK = NHEADS * DK, DMV = NHEADS * DV;
  // XCD swizzle: linear id -> (XCD chunk) so same-bh i-blocks share an XCD L2
  const int nIb = gridDim.x;
  const int id = blockIdx.x + blockIdx.y * nIb;
  const int cpx = nIb * 8;                 // nwg/8, gridDim.y == 64
  const int W = (id & 7) * cpx + (id >> 3);
  const int ib = W % nIb;
  const int bh = W / nIb;
  const int i0 = (ib + bxoff) * 16;
  const int b = bh >> 3, h = bh & 7;
  const int tid = threadIdx.x;
  const int lane = tid & 63, w = tid >> 6;
  const size_t rowbase = (size_t)b * S;

  constexpr int NP = (DV == 32) ? 6 : 4;
  __shared__ __align__(16) float sc[16 * RS];
  __shared__ float red[NP * 16 * 17];

  const int jmaxBlk = MASKK ? (i0 + 15) : (i0 + 14);
  const int nT = jmaxBlk / 64 + 1;
  const int NK = nT * 64;

  const int qr = lane & 15;
  const int ko8 = (lane >> 4) * 8;

  bfrag qf[DK / 32];
  #pragma unroll
  for (int ks = 0; ks < DK / 32; ++ks)
    qf[ks] = *(const bfrag*)(QKb + (rowbase + i0 + qr) * DMK + h * DK + ks * 32 + ko8);

  // ---- QK^T ----
  for (int t0 = 0; t0 < NK; t0 += 128) {
    int tt = t0 + (w >> 2) * 64;
    if (tt < NK) {
      int jb = tt + (w & 3) * 16 + qr;
      bfrag kf[DK / 32];
      #pragma unroll
      for (int ks = 0; ks < DK / 32; ++ks)
        kf[ks] = *(const bfrag*)(QKb + (rowbase + jb) * DMK + h * DK + ks * 32 + ko8);
      f32x4 accs = {};
      #pragma unroll
      for (int ks = 0; ks < DK / 32; ++ks)
        accs = __builtin_amdgcn_mfma_f32_16x16x32_bf16(qf[ks], kf[ks], accs, 0, 0, 0);
      int ja = jb + 4 * (jb >> 5);
      int r0 = (lane >> 4) * 4;
      #pragma unroll
      for (int q = 0; q < 4; ++q)
        sc[(r0 + q) * RS + ja] = accs[q];
    }
  }
  __syncthreads();

  // ---- softmax pipeline: group g (32 lanes) owns query row g; CHUNK elems/lane ----
  {
    const int g = tid >> 5, l = tid & 31;
    const int i = i0 + g;
    const int jmax = MASKK ? i : i - 1;
    const int jb0 = CHUNK * l;
    const int sb = g * RS + jb0 + 4 * (jb0 >> 5);
    const float rscale = rsqrtf((float)DK);

    float p[CHUNK];
    float m1 = -1e30f;
    #pragma unroll
    for (int c = 0; c < CHUNK / 4; ++c) {
      f32x4 v = *(const f32x4*)(sc + sb + c * 4);
      #pragma unroll
      for (int k = 0; k < 4; ++k) {
        int j = jb0 + c * 4 + k;
        float s = (j <= jmax) ? v[k] * rscale : -1e30f;
        p[c * 4 + k] = s;
        m1 = fmaxf(m1, s);
      }
    }
    #pragma unroll
    for (int o = 16; o > 0; o >>= 1) m1 = fmaxf(m1, __shfl_xor(m1, o, 32));

    float e1[CHUNK];
    float lloc = 0.f;
    #pragma unroll
    for (int t = 0; t < CHUNK; ++t) { e1[t] = __expf(p[t] - m1); lloc += e1[t]; }
    float l1 = lloc;
    #pragma unroll
    for (int o = 16; o > 0; o >>= 1) l1 += __shfl_xor(l1, o, 32);
    float inv1 = 1.f / l1;

    // exclusive prefix of normalized lane totals
    float scn = lloc * inv1;
    #pragma unroll
    for (int o = 1; o < 32; o <<= 1) {
      float u = __shfl_up(scn, o, 32);
      if (l >= o) scn += u;
    }
    float cum = scn - lloc * inv1;

    float gv = gamp[h];
    float sp = fmaxf(gv, 0.f) + log1pf(__expf(-fabsf(gv)));
    float gm = -sp;
    float dj = (float)(i - jb0);
    float m2 = -1e30f;
    #pragma unroll
    for (int t = 0; t < CHUNK; ++t) {
      cum += e1[t] * inv1;
      float rem = fmaxf(1.f - cum, 0.f);
      float dist = sqrtf(rem * fabsf(dj));
      dj -= 1.f;
      float eff = fmaxf(__expf(gm * dist), 1e-5f);   // gm <= 0 so eff <= 1
      p[t] = p[t] * eff;
      m2 = fmaxf(m2, p[t]);
    }
    #pragma unroll
    for (int o = 16; o > 0; o >>= 1) m2 = fmaxf(m2, __shfl_xor(m2, o, 32));

    float l2 = 0.f;
    #pragma unroll
    for (int t = 0; t < CHUNK; ++t) { p[t] = __expf(p[t] - m2); l2 += p[t]; }
    #pragma unroll
    for (int o = 16; o > 0; o >>= 1) l2 += __shfl_xor(l2, o, 32);
    bool validrow = (jmax >= 0) && !(ZP && i == 0);
    float wgt = validrow ? (1.f / l2) : 0.f;
    #pragma unroll
    for (int c = 0; c < CHUNK / 4; ++c) {
      f32x4 v;
      #pragma unroll
      for (int k = 0; k < 4; ++k) v[k] = p[c * 4 + k] * wgt;
      *(f32x4*)(sc + sb + c * 4) = v;
    }
  }
  __syncthreads();

  // ---- PV: wave owns (d-block, tile-parity); split-P hi+lo ----
  const int dblk = (DV == 64) ? (w & 3) : (w & 1);
  const int par  = (DV == 64) ? (w >> 2) : (w >> 1);
  const int NPAR = (DV == 64) ? 2 : 4;
  const int NFIN = (DV == 64) ? 4 : 2;
  f32x4 acco = {};
  const int dcol = h * DV + dblk * 16 + (lane & 15);
  for (int t0 = par * 64; t0 < NK; t0 += NPAR * 64) {
    #pragma unroll
    for (int ks = 0; ks < 2; ++ks) {
      int jo = t0 + ks * 32 + ko8;
      int pa = qr * RS + jo + 4 * (jo >> 5);
      f32x4 p0 = *(const f32x4*)(sc + pa);
      f32x4 p1 = *(const f32x4*)(sc + pa + 4);
      bfrag ph, pl;
      #pragma unroll
      for (int e = 0; e < 4; ++e) {
        __bf16 h0 = (__bf16)p0[e];
        __bf16 h1 = (__bf16)p1[e];
        ph[e] = h0; ph[e + 4] = h1;
        pl[e] = (__bf16)(p0[e] - (float)h0);
        pl[e + 4] = (__bf16)(p1[e] - (float)h1);
      }
      bfrag vf = *(const bfrag*)(Vt + (size_t)dcol * MT + rowbase + jo);
      acco = __builtin_amdgcn_mfma_f32_16x16x32_bf16(pl, vf, acco, 0, 0, 0);
      acco = __builtin_amdgcn_mfma_f32_16x16x32_bf16(ph, vf, acco, 0, 0, 0);
    }
  }

  if (w >= NFIN) {
    #pragma unroll
    for (int q = 0; q < 4; ++q)
      red[(w - NFIN) * 272 + ((lane >> 4) * 4 + q) * 17 + (lane & 15)] = acco[q];
  }
  __syncthreads();
  if (w < NFIN) {
    for (int pp = w; pp < NP; pp += NFIN) {
      #pragma unroll
      for (int q = 0; q < 4; ++q)
        acco[q] += red[pp * 272 + ((lane >> 4) * 4 + q) * 17 + (lane & 15)];
    }
    int r0 = (lane >> 4) * 4;
    #pragma unroll
    for (int q = 0; q < 4; ++q)
      O[(rowbase + i0 + r0 + q) * DMV + dcol] = f2bf(acco[q]);
  }
}

// ---------------- LayerNorm v4: one row per wave, float4 loads ----------------
template<int D, bool WF, bool WB>
__global__ __launch_bounds__(256) void ln4_kernel(
    const float* __restrict__ X, const float* __restrict__ R,
    const float* __restrict__ g, const float* __restrict__ be,
    float* __restrict__ Y, unsigned short* __restrict__ Yb)
{
  constexpr int NC = D / 256;
  int row = blockIdx.x * 4 + (threadIdx.x >> 6);
  int lane = threadIdx.x & 63;
  const float* x = X + (size_t)row * D;
  f32x4 xv[NC];
  float s = 0.f;
  #pragma unroll
  for (int c = 0; c < NC; ++c) {
    xv[c] = *(const f32x4*)(x + c * 256 + lane * 4);
    if (R) {
      f32x4 rv = *(const f32x4*)(R + (size_t)row * D + c * 256 + lane * 4);
      #pragma unroll
      for (int k = 0; k < 4; ++k) xv[c][k] += rv[k];
    }
    #pragma unroll
    for (int k = 0; k < 4; ++k) s += xv[c][k];
  }
  #pragma unroll
  for (int o = 32; o > 0; o >>= 1) s += __shfl_xor(s, o, 64);
  float mean = s / (float)D;
  float vs = 0.f;
  #pragma unroll
  for (int c = 0; c < NC; ++c)
    #pragma unroll
    for (int k = 0; k < 4; ++k) { float d = xv[c][k] - mean; vs += d * d; }
  #pragma unroll
  for (int o = 32; o > 0; o >>= 1) vs += __shfl_xor(vs, o, 64);
  float rstd = rsqrtf(vs / (float)D + 1e-5f);
  #pragma unroll
  for (int c = 0; c < NC; ++c) {
    f32x4 gv = *(const f32x4*)(g + c * 256 + lane * 4);
    f32x4 bv = *(const f32x4*)(be + c * 256 + lane * 4);
    f32x4 ov;
    #pragma unroll
    for (int k = 0; k < 4; ++k) ov[k] = gv[k] * (xv[c][k] - mean) * rstd + bv[k];
    if (WF) *(f32x4*)(Y + (size_t)row * D + c * 256 + lane * 4) = ov;
    if (WB) {
      ushort4 h4 = { f2bf(ov[0]), f2bf(ov[1]), f2bf(ov[2]), f2bf(ov[3]) };
      *(ushort4*)(Yb + (size_t)row * D + c * 256 + lane * 4) = h4;
    }
  }
}

// ---------------- fused concat + LN (D=512) ----------------
__global__ __launch_bounds__(256) void lnc_kernel(
    const float* __restrict__ Xh, const float* __restrict__ Qe,
    const float* __restrict__ g, const float* __restrict__ be,
    unsigned short* __restrict__ Yb)
{
  int row = blockIdx.x * 4 + (threadIdx.x >> 6);
  int lane = threadIdx.x & 63;
  f32x4 xv[2];
  xv[0] = *(const f32x4*)(Xh + (size_t)row * 256 + lane * 4);
  xv[1] = *(const f32x4*)(Qe + (size_t)row * 256 + lane * 4);
  float s = 0.f;
  #pragma unroll
  for (int c = 0; c < 2; ++c)
    #pragma unroll
    for (int k = 0; k < 4; ++k) s += xv[c][k];
  #pragma unroll
  for (int o = 32; o > 0; o >>= 1) s += __shfl_xor(s, o, 64);
  float mean = s / 512.f;
  float vs = 0.f;
  #pragma unroll
  for (int c = 0; c < 2; ++c)
    #pragma unroll
    for (int k = 0; k < 4; ++k) { float d = xv[c][k] - mean; vs += d * d; }
  #pragma unroll
  for (int o = 32; o > 0; o >>= 1) vs += __shfl_xor(vs, o, 64);
  float rstd = rsqrtf(vs / 512.f + 1e-5f);
  #pragma unroll
  for (int c = 0; c < 2; ++c) {
    f32x4 gv = *(const f32x4*)(g + c * 256 + lane * 4);
    f32x4 bv = *(const f32x4*)(be + c * 256 + lane * 4);
    ushort4 h4;
    #pragma unroll
    for (int k = 0; k < 4; ++k) {
      float ov = gv[k] * (xv[c][k] - mean) * rstd + bv[k];
      ((unsigned short*)&h4)[k] = f2bf(ov);
    }
    *(ushort4*)(Yb + (size_t)row * 512 + c * 256 + lane * 4) = h4;
  }
}

// ---------------- fused LN(D=256) + dot ----------------
__global__ __launch_bounds__(256) void lndot_kernel(
    const float* __restrict__ X, const float* __restrict__ g,
    const float* __restrict__ be, const float* __restrict__ w3,
    const float* __restrict__ b3, float* __restrict__ out)
{
  int row = blockIdx.x * 4 + (threadIdx.x >> 6);
  int lane = threadIdx.x & 63;
  f32x4 v = *(const f32x4*)(X + (size_t)row * 256 + lane * 4);
  float s = v[0] + v[1] + v[2] + v[3];
  #pragma unroll
  for (int o = 32; o > 0; o >>= 1) s += __shfl_xor(s, o, 64);
  float mean = s / 256.f;
  float vs = 0.f;
  #pragma unroll
  for (int k = 0; k < 4; ++k) { float d = v[k] - mean; vs += d * d; }
  #pragma unroll
  for (int o = 32; o > 0; o >>= 1) vs += __shfl_xor(vs, o, 64);
  float rstd = rsqrtf(vs / 256.f + 1e-5f);
  f32x4 gv = *(const f32x4*)(g + lane * 4);
  f32x4 bv = *(const f32x4*)(be + lane * 4);
  f32x4 wv = *(const f32x4*)(w3 + lane * 4);
  float d = 0.f;
  #pragma unroll
  for (int k = 0; k < 4; ++k)
    d += (gv[k] * (v[k] - mean) * rstd + bv[k]) * wv[k];
  #pragma unroll
  for (int o = 32; o > 0; o >>= 1) d += __shfl_xor(d, o, 64);
  if (lane == 0) out[row] = d + b3[0];
}

// ---------------- launch ----------------
extern "C" void kernel_launch(void* const* d_in, const int* in_sizes, int n_in,
                              void* d_out, int out_size, void* d_ws, size_t ws_size,
                              hipStream_t stream) {
  const int* p_data  = (const int*)d_in[0];
  const int* pa_data = (const int*)d_in[1];
  const float* pemb_W = (const float*)d_in[3];
  const float* diff_W = (const float*)d_in[4];
  const float* qemb_W = (const float*)d_in[5];
  const float* qemb_b = (const float*)d_in[6];
  const float* y_kW = (const float*)d_in[7];   const float* y_kb = (const float*)d_in[8];
  const float* y_vW = (const float*)d_in[9];   const float* y_vb = (const float*)d_in[10];
  const float* y_oW = (const float*)d_in[11];  const float* y_ob = (const float*)d_in[12];
  const float* y_gam = (const float*)d_in[13];
  const float* y_ln1g = (const float*)d_in[14]; const float* y_ln1b = (const float*)d_in[15];
  const float* y_f1W = (const float*)d_in[16]; const float* y_f1b = (const float*)d_in[17];
  const float* y_f2W = (const float*)d_in[18]; const float* y_f2b = (const float*)d_in[19];
  const float* y_ln2g = (const float*)d_in[20]; const float* y_ln2b = (const float*)d_in[21];
  const float* x_kW = (const float*)d_in[22];  const float* x_kb = (const float*)d_in[23];
  const float* x_vW = (const float*)d_in[24];  const float* x_vb = (const float*)d_in[25];
  const float* x_oW = (const float*)d_in[26];  const float* x_ob = (const float*)d_in[27];
  const float* x_gam = (const float*)d_in[28];
  const float* x_ln1g = (const float*)d_in[29]; const float* x_ln1b = (const float*)d_in[30];
  const float* h_kW = (const float*)d_in[31];  const float* h_kb = (const float*)d_in[32];
  const float* h_vW = (const float*)d_in[33];  const float* h_vb = (const float*)d_in[34];
  const float* h_oW = (const float*)d_in[35];  const float* h_ob = (const float*)d_in[36];
  const float* h_gam = (const float*)d_in[37];
  const float* h_ln1g = (const float*)d_in[38]; const float* h_ln1b = (const float*)d_in[39];
  const float* h_f1W = (const float*)d_in[40]; const float* h_f1b = (const float*)d_in[41];
  const float* h_f2W = (const float*)d_in[42]; const float* h_f2b = (const float*)d_in[43];
  const float* h_ln2g = (const float*)d_in[44]; const float* h_ln2b = (const float*)d_in[45];
  const float* oln1g = (const float*)d_in[46]; const float* oln1b = (const float*)d_in[47];
  const float* o1W = (const float*)d_in[48];   const float* o1b = (const float*)d_in[49];
  const float* oln2g = (const float*)d_in[50]; const float* oln2b = (const float*)d_in[51];
  const float* o2W = (const float*)d_in[52];   const float* o2b = (const float*)d_in[53];
  const float* oln3g = (const float*)d_in[54]; const float* oln3b = (const float*)d_in[55];
  const float* o3W = (const float*)d_in[56];   const float* o3b = (const float*)d_in[57];

  float* out_f = (float*)d_out;

  const int B = 8, S = 1024, M = B * S;
  const int R = 4097, KQ = 1025, KQP = 1056;

  float* ws = (float*)d_ws;
  size_t off = 0;
  auto alloc = [&](size_t nfloats) { size_t o = off; off += (nfloats + 255) & ~(size_t)255; return o; };
  auto allocs = [&](size_t nshorts) { return alloc((nshorts + 1) / 2); };

  size_t oE    = alloc((size_t)R * 256);
  size_t oSIGb = allocs((size_t)R * KQP);
  size_t oSSUM = alloc(R);
  size_t oQE   = alloc((size_t)M * 256);
  size_t oQEb  = allocs((size_t)M * 256);
  size_t oQA   = alloc((size_t)M * 512);
  size_t oQAb  = allocs((size_t)M * 512);
  size_t oYOb  = allocs((size_t)M * 512);
  size_t oXO   = alloc((size_t)M * 256);
  size_t oXOb  = allocs((size_t)M * 256);
  size_t oHO   = alloc((size_t)M * 256);
  size_t oS0   = alloc((size_t)M * 512);   // FFb arena (S0+S1)
  size_t oS1   = alloc((size_t)M * 512);
  size_t oS2b  = allocs((size_t)M * 512);
  size_t oS3   = alloc((size_t)M * 512);
  size_t oS4   = alloc((size_t)M * 512);
  size_t oSX   = alloc((size_t)M * 512);
  size_t oSXb  = allocs((size_t)M * 512);
  size_t oS0b  = allocs((size_t)M * 512);
  size_t oVt   = allocs((size_t)M * 512);
  // NOTE: Wyk/Wyv adjacent (concatenated KV weights), same for Wxk/Wxv.
  size_t oWqe  = allocs((size_t)256 * KQP);
  size_t oWyk  = allocs((size_t)512 * 512);
  size_t oWyv  = allocs((size_t)512 * 512);
  size_t oWyo  = allocs((size_t)512 * 512);
  size_t oWyf1 = allocs((size_t)2048 * 512);
  size_t oWyf2 = allocs((size_t)512 * 2048);
  size_t oWxk  = allocs((size_t)256 * 256);
  size_t oWxv  = allocs((size_t)256 * 256);
  size_t oWxo  = allocs((size_t)256 * 256);
  size_t oWhk  = allocs((size_t)256 * 256);
  size_t oWhv  = allocs((size_t)512 * 512);
  size_t oWho  = allocs((size_t)256 * 512);
  size_t oWhf1 = allocs((size_t)2048 * 256);
  size_t oWhf2 = allocs((size_t)256 * 2048);
  size_t oWo1  = allocs((size_t)512 * 512);
  size_t oWo2  = allocs((size_t)256 * 512);
  (void)ws_size; (void)in_sizes; (void)n_in; (void)out_size;

  float* E    = ws + oE;
  unsigned short* SIGb = (unsigned short*)(ws + oSIGb);
  float* SSUM = ws + oSSUM;
  float* QE   = ws + oQE;   unsigned short* QEb = (unsigned short*)(ws + oQEb);
  float* QA   = ws + oQA;   unsigned short* QAb = (unsigned short*)(ws + oQAb);
  unsigned short* YOb = (unsigned short*)(ws + oYOb);
  float* XO   = ws + oXO;   unsigned short* XOb = (unsigned short*)(ws + oXOb);
  float* HO   = ws + oHO;
  float* S0   = ws + oS0;
  unsigned short* S2b = (unsigned short*)(ws + oS2b);
  float* S3   = ws + oS3;
  float* S4   = ws + oS4;
  float* SX   = ws + oSX;   unsigned short* SXb = (unsigned short*)(ws + oSXb);
  unsigned short* S0b = (unsigned short*)(ws + oS0b);
  unsigned short* Vt  = (unsigned short*)(ws + oVt);
  unsigned short* FFb = (unsigned short*)S0;

  unsigned short* Wqe  = (unsigned short*)(ws + oWqe);
  unsigned short* Wyk  = (unsigned short*)(ws + oWyk);
  unsigned short* Wyv  = (unsigned short*)(ws + oWyv);
  unsigned short* Wyo  = (unsigned short*)(ws + oWyo);
  unsigned short* Wyf1 = (unsigned short*)(ws + oWyf1);
  unsigned short* Wyf2 = (unsigned short*)(ws + oWyf2);
  unsigned short* Wxk  = (unsigned short*)(ws + oWxk);
  unsigned short* Wxv  = (unsigned short*)(ws + oWxv);
  unsigned short* Wxo  = (unsigned short*)(ws + oWxo);
  unsigned short* Whk  = (unsigned short*)(ws + oWhk);
  unsigned short* Whv  = (unsigned short*)(ws + oWhv);
  unsigned short* Who  = (unsigned short*)(ws + oWho);
  unsigned short* Whf1 = (unsigned short*)(ws + oWhf1);
  unsigned short* Whf2 = (unsigned short*)(ws + oWhf2);
  unsigned short* Wo1  = (unsigned short*)(ws + oWo1);
  unsigned short* Wo2  = (unsigned short*)(ws + oWo2);

  dim3 blk(256);
  int nElem512 = (8192 * 512 + 255) / 256;

  // ---- fused weight transposes ----
  {
    struct HD { const float* src; unsigned short* dst; int K, N, Kp; };
    const HD hd[16] = {
      {qemb_W, Wqe, KQ, 256, KQP},
      {y_kW, Wyk, 512, 512, 512}, {y_vW, Wyv, 512, 512, 512}, {y_oW, Wyo, 512, 512, 512},
      {y_f1W, Wyf1, 512, 2048, 512}, {y_f2W, Wyf2, 2048, 512, 2048},
      {x_kW, Wxk, 256, 256, 256}, {x_vW, Wxv, 256, 256, 256}, {x_oW, Wxo, 256, 256, 256},
      {h_kW, Whk, 256, 256, 256}, {h_vW, Whv, 512, 512, 512}, {h_oW, Who, 512, 256, 512},
      {h_f1W, Whf1, 256, 2048, 256}, {h_f2W, Whf2, 2048, 256, 2048},
      {o1W, Wo1, 512, 512, 512}, {o2W, Wo2, 512, 256, 512},
    };
    TPack P;
    int tot = 0;
    for (int k = 0; k < 16; ++k) {
      int tx = (hd[k].N + 31) / 32, ty = (hd[k].Kp + 31) / 32;
      P.d[k] = { hd[k].src, hd[k].dst, hd[k].K, hd[k].N, hd[k].Kp, tx, tot };
      tot += tx * ty;
    }
    tconv_all_kernel<<<dim3(tot), blk, 0, stream>>>(P);
  }

  auto gg128 = [](int Mm, int Nn) { return dim3((unsigned)(Nn / 128), (unsigned)((Mm + 127) / 128)); };
  auto gg64  = [](int Mm, int Nn) { return dim3((unsigned)(Nn / 128), (unsigned)((Mm + 63) / 64)); };

  // 1. embedding table
  sig_kernel<<<R, blk, 0, stream>>>(pemb_W, SIGb, SSUM, KQ, KQP);
  mgemm_kernel<64, 2, true, false, false><<<gg64(R, 256), blk, 0, stream>>>(SIGb, Wqe, qemb_b, E, nullptr, nullptr, R, 256, KQP, SSUM, nullptr, 0);
  gather_kernel<<<nElem512, blk, 0, stream>>>(p_data, pa_data, E, diff_W, QE, QEb, QA, QAb);
  creg_kernel<<<1, blk, 0, stream>>>(p_data, diff_W, out_f + 8192);

  dim3 ablk(512);
  dim3 lgrid(M / 4);
  dim3 agA(16, B * NHEADS), agB(16, B * NHEADS), agC(32, B * NHEADS);

  // 2. y layer (dm=512, mask_k=1, zero_pad=0, FFN). Fused KV proj (Wyk|Wyv adjacent).
  mgemm_kernel<128, 0, false, true, true><<<dim3(8, 64), blk, 0, stream>>>(QAb, Wyk, y_kb, nullptr, S0b, Vt, M, 1024, 512, nullptr, y_vb, 512);
  attn5_kernel<64, 64, 1, 0, 8><<<agA, ablk, 0, stream>>>(S0b, Vt, y_gam, S2b, S, M, 0);
  attn5_kernel<64, 64, 1, 0, 16><<<agB, ablk, 0, stream>>>(S0b, Vt, y_gam, S2b, S, M, 16);
  attn5_kernel<64, 64, 1, 0, 32><<<agC, ablk, 0, stream>>>(S0b, Vt, y_gam, S2b, S, M, 32);
  mgemm_kernel<128, 0, true, false, false><<<gg128(M, 512), blk, 0, stream>>>(S2b, Wyo, y_ob, S3, nullptr, nullptr, M, 512, 512, nullptr, nullptr, 0);
  ln4_kernel<512, true, true><<<lgrid, blk, 0, stream>>>(QA, S3, y_ln1g, y_ln1b, SX, SXb);
  mgemm_kernel<128, 1, false, true, false><<<gg128(M, 2048), blk, 0, stream>>>(SXb, Wyf1, y_f1b, nullptr, FFb, nullptr, M, 2048, 512, nullptr, nullptr, 0);
  mgemm_kernel<128, 0, true, false, false><<<gg128(M, 512), blk, 0, stream>>>(FFb, Wyf2, y_f2b, S4, nullptr, nullptr, M, 512, 2048, nullptr, nullptr, 0);
  ln4_kernel<512, false, true><<<lgrid, blk, 0, stream>>>(SX, S4, y_ln2g, y_ln2b, nullptr, YOb);

  // 3. x layer (dm=256, mask_k=1, zero_pad=0, no FFN). Fused KV proj (Wxk|Wxv adjacent).
  mgemm_kernel<128, 0, false, true, true><<<dim3(4, 64), blk, 0, stream>>>(QEb, Wxk, x_kb, nullptr, S0b, Vt, M, 512, 256, nullptr, x_vb, 256);
  attn5_kernel<32, 32, 1, 0, 8><<<agA, ablk, 0, stream>>>(S0b, Vt, x_gam, S2b, S, M, 0);
  attn5_kernel<32, 32, 1, 0, 16><<<agB, ablk, 0, stream>>>(S0b, Vt, x_gam, S2b, S, M, 16);
  attn5_kernel<32, 32, 1, 0, 32><<<agC, ablk, 0, stream>>>(S0b, Vt, x_gam, S2b, S, M, 32);
  mgemm_kernel<64, 0, true, false, false><<<gg64(M, 256), blk, 0, stream>>>(S2b, Wxo, x_ob, S3, nullptr, nullptr, M, 256, 256, nullptr, nullptr, 0);
  ln4_kernel<256, true, true><<<lgrid, blk, 0, stream>>>(QE, S3, x_ln1g, x_ln1b, XO, XOb);

  // 4. h layer (q,k from XO; v from YO; mask_k=0, zero_pad=1, FFN)
  mgemm_kernel<64, 0, false, true, false><<<gg64(M, 256), blk, 0, stream>>>(XOb, Whk, h_kb, nullptr, S0b, nullptr, M, 256, 256, nullptr, nullptr, 0);
  mgemm_kernel<128, 0, false, false, true><<<gg128(M, 512), blk, 0, stream>>>(YOb, Whv, h_vb, nullptr, nullptr, Vt, M, 512, 512, nullptr, nullptr, 0);
  attn5_kernel<32, 64, 0, 1, 8><<<agA, ablk, 0, stream>>>(S0b, Vt, h_gam, S2b, S, M, 0);
  attn5_kernel<32, 64, 0, 1, 16><<<agB, ablk, 0, stream>>>(S0b, Vt, h_gam, S2b, S, M, 16);
  attn5_kernel<32, 64, 0, 1, 32><<<agC, ablk, 0, stream>>>(S0b, Vt, h_gam, S2b, S, M, 32);
  mgemm_kernel<64, 0, true, false, false><<<gg64(M, 256), blk, 0, stream>>>(S2b, Who, h_ob, S3, nullptr, nullptr, M, 256, 512, nullptr, nullptr, 0);
  ln4_kernel<256, true, true><<<lgrid, blk, 0, stream>>>(XO, S3, h_ln1g, h_ln1b, SX, SXb);
  mgemm_kernel<128, 1, false, true, false><<<gg128(M, 2048), blk, 0, stream>>>(SXb, Whf1, h_f1b, nullptr, FFb, nullptr, M, 2048, 256, nullptr, nullptr, 0);
  mgemm_kernel<64, 0, true, false, false><<<gg64(M, 256), blk, 0, stream>>>(FFb, Whf2, h_f2b, S4, nullptr, nullptr, M, 256, 2048, nullptr, nullptr, 0);
  ln4_kernel<256, true, false><<<lgrid, blk, 0, stream>>>(SX, S4, h_ln2g, h_ln2b, HO, nullptr);

  // 5. head: LN(concat) -> o1 -> LN -> o2 -> LN+dot
  lnc_kernel<<<lgrid, blk, 0, stream>>>(HO, QE, oln1g, oln1b, SXb);
  mgemm_kernel<128, 1, true, false, false><<<gg128(M, 512), blk, 0, stream>>>(SXb, Wo1, o1b, S3, nullptr, nullptr, M, 512, 512, nullptr, nullptr, 0);
  ln4_kernel<512, false, true><<<lgrid, blk, 0, stream>>>(S3, nullptr, oln2g, oln2b, nullptr, SXb);
  mgemm_kernel<64, 1, true, false, false><<<gg64(M, 256), blk, 0, stream>>>(SXb, Wo2, o2b, S4, nullptr, nullptr, M, 256, 512, nullptr, nullptr, 0);
  lndot_kernel<<<lgrid, blk, 0, stream>>>(S4, oln3g, oln3b, o3W, o3b, out_f);
}

// Round 8
// 868.471 us; speedup vs baseline: 11.6219x; 1.0104x over previous
//
#include <hip/hip_runtime.h>
#include <hip/hip_bf16.h>
#include <math.h>

#define NHEADS 8

typedef __attribute__((ext_vector_type(8))) __bf16 bfrag;
typedef __attribute__((ext_vector_type(4))) float f32x4;
typedef __attribute__((ext_vector_type(8))) unsigned short u16x8;

static __device__ __forceinline__ unsigned short f2bf(float f) {
  unsigned u = __float_as_uint(f);
  unsigned r = (u + 0x7fffu + ((u >> 16) & 1u)) >> 16;
  return (unsigned short)r;
}

static __device__ __forceinline__ void gload_lds16(const void* g, void* l) {
  __builtin_amdgcn_global_load_lds(
      (const __attribute__((address_space(1))) unsigned int*)g,
      (__attribute__((address_space(3))) unsigned int*)l, 16, 0, 0);
}

static __device__ __forceinline__ float block_reduce_sum(float v, float* red) {
  int t = threadIdx.x;
  red[t] = v; __syncthreads();
  for (int s = 128; s > 0; s >>= 1) {
    if (t < s) red[t] += red[t + s];
    __syncthreads();
  }
  float r = red[0];
  __syncthreads();
  return r;
}

// ---------------- sigmoid table (bf16, padded to Kp) + row sums ----------------
__global__ __launch_bounds__(256) void sig_kernel(
    const float* __restrict__ Wp, unsigned short* __restrict__ Sgb,
    float* __restrict__ Ssum, int Kd, int Kp)
{
  __shared__ float red[256];
  int row = blockIdx.x;
  float s = 0.f;
  for (int k = threadIdx.x; k < Kp; k += 256) {
    float v = 0.f;
    if (k < Kd) {
      v = 1.f / (1.f + __expf(-Wp[(size_t)row * Kd + k]));
      s += v;
    }
    Sgb[(size_t)row * Kp + k] = f2bf(v);
  }
  float tot = block_reduce_sum(s, red);
  if (threadIdx.x == 0) Ssum[row] = tot;
}

// ---------------- fused transpose+convert for all weights ----------------
struct TDesc { const float* src; unsigned short* dst; int K, N, Kp, tilesX, blk0; };
struct TPack { TDesc d[16]; };

__global__ __launch_bounds__(256) void tconv_all_kernel(TPack P) {
  __shared__ float t[32][33];
  int bid = blockIdx.x;
  int di = 0;
  #pragma unroll
  for (int k = 1; k < 16; ++k) if (bid >= P.d[k].blk0) di = k;
  const float* src = P.d[di].src;
  unsigned short* dst = P.d[di].dst;
  int K = P.d[di].K, N = P.d[di].N, Kp = P.d[di].Kp, tilesX = P.d[di].tilesX;
  int local = bid - P.d[di].blk0;
  int bn = (local % tilesX) * 32;
  int bk = (local / tilesX) * 32;
  int tid = threadIdx.x;
  int tx = tid & 31, ty = tid >> 5;
  #pragma unroll
  for (int u = 0; u < 4; ++u) {
    int k = bk + ty + u * 8, n = bn + tx;
    t[ty + u * 8][tx] = (k < K && n < N) ? src[(size_t)k * N + n] : 0.f;
  }
  __syncthreads();
  #pragma unroll
  for (int u = 0; u < 4; ++u) {
    int n = bn + ty + u * 8, kk = bk + tx;
    if (n < N && kk < Kp)
      dst[(size_t)n * Kp + kk] = f2bf(t[tx][ty + u * 8]);
  }
}

// ---------------- MFMA bf16 GEMM: C = epi(A @ Bt^T + bias) ----------------
template<int BM, int EPI, bool WF32, bool WBF, bool WTR>
__global__ __launch_bounds__(256) void mgemm_kernel(
    const unsigned short* __restrict__ A, const unsigned short* __restrict__ Bt,
    const float* __restrict__ bias, float* __restrict__ C,
    unsigned short* __restrict__ Cb, unsigned short* __restrict__ Ct,
    int M, int N, int K, const float* __restrict__ divv,
    const float* __restrict__ bias2, int Nk)
{
  constexpr int NJ = (BM == 128) ? 4 : 2;
  constexpr bool SPLIT = WBF && WTR;
  __shared__ __align__(16) unsigned short Als[BM * 32];
  __shared__ __align__(16) unsigned short Bls[128 * 32];
  const int tid = threadIdx.x;
  const int lane = tid & 63, w = tid >> 6;
  const int wm = (BM == 128) ? (w >> 1) : 0;
  const int wn = (BM == 128) ? (w & 1) : w;
  const int brow = blockIdx.y * BM, bcol = blockIdx.x * 128;

  f32x4 acc[4][NJ] = {};

  for (int k0 = 0; k0 < K; k0 += 32) {
    #pragma unroll
    for (int q = 0; q < 2; ++q) {
      int s = w * 128 + q * 64 + lane;
      int r = s >> 2, g = s & 3;
      int gs = g ^ (r & 3);
      int gc = bcol + r; if (gc > N - 1) gc = N - 1;
      gload_lds16(Bt + (size_t)gc * K + k0 + gs * 8,
                  (char*)Bls + (w * 2048 + q * 1024));
    }
    if constexpr (BM == 128) {
      #pragma unroll
      for (int q = 0; q < 2; ++q) {
        int s = w * 128 + q * 64 + lane;
        int r = s >> 2, g = s & 3;
        int gs = g ^ (r & 3);
        int gr = brow + r; if (gr > M - 1) gr = M - 1;
        gload_lds16(A + (size_t)gr * K + k0 + gs * 8,
                    (char*)Als + (w * 2048 + q * 1024));
      }
    } else {
      int s = w * 64 + lane;
      int r = s >> 2, g = s & 3;
      int gs = g ^ (r & 3);
      int gr = brow + r; if (gr > M - 1) gr = M - 1;
      gload_lds16(A + (size_t)gr * K + k0 + gs * 8,
                  (char*)Als + w * 1024);
    }
    __syncthreads();

    bfrag av[4], bv[NJ];
    #pragma unroll
    for (int f = 0; f < 4; ++f) {
      int rA = wm * 64 + f * 16 + (lane & 15);
      av[f] = *(const bfrag*)((const char*)Als + rA * 64 + ((((lane >> 4) ^ (rA & 3))) << 4));
    }
    #pragma unroll
    for (int f = 0; f < NJ; ++f) {
      int rB = wn * (16 * NJ) + f * 16 + (lane & 15);
      bv[f] = *(const bfrag*)((const char*)Bls + rB * 64 + ((((lane >> 4) ^ (rB & 3))) << 4));
    }
    #pragma unroll
    for (int i = 0; i < 4; ++i)
      #pragma unroll
      for (int j = 0; j < NJ; ++j)
        acc[i][j] = __builtin_amdgcn_mfma_f32_16x16x32_bf16(av[i], bv[j], acc[i][j], 0, 0, 0);
    __syncthreads();
  }

  #pragma unroll
  for (int i = 0; i < 4; ++i) {
    int gr0 = brow + wm * 64 + i * 16 + (lane >> 4) * 4;
    #pragma unroll
    for (int j = 0; j < NJ; ++j) {
      int gc = bcol + wn * (16 * NJ) + j * 16 + (lane & 15);
      float bsv;
      if (SPLIT) bsv = (gc < Nk) ? bias[gc] : bias2[gc - Nk];
      else       bsv = bias ? bias[gc] : 0.f;
      float vv[4];
      #pragma unroll
      for (int q = 0; q < 4; ++q) {
        int gr = gr0 + q;
        float v = acc[i][j][q] + bsv;
        if (EPI >= 1) v = fmaxf(v, 0.f);
        if (EPI == 2) v = (gr < M) ? v / divv[gr] : v;
        vv[q] = v;
      }
      if (SPLIT) {
        if (gc < Nk) {
          #pragma unroll
          for (int q = 0; q < 4; ++q) {
            int gr = gr0 + q;
            if (gr < M) Cb[(size_t)gr * Nk + gc] = f2bf(vv[q]);
          }
        } else {
          ushort4 h4 = { f2bf(vv[0]), f2bf(vv[1]), f2bf(vv[2]), f2bf(vv[3]) };
          *(ushort4*)(Ct + (size_t)(gc - Nk) * M + gr0) = h4;
        }
      } else {
        #pragma unroll
        for (int q = 0; q < 4; ++q) {
          int gr = gr0 + q;
          if (gr >= M) continue;
          if (WF32) C[(size_t)gr * N + gc] = vv[q];
          if (WBF)  Cb[(size_t)gr * N + gc] = f2bf(vv[q]);
        }
        if (WTR) {
          ushort4 h4 = { f2bf(vv[0]), f2bf(vv[1]), f2bf(vv[2]), f2bf(vv[3]) };
          *(ushort4*)(Ct + (size_t)gc * M + gr0) = h4;
        }
      }
    }
  }
}

// ---------------- embedding gather ----------------
__global__ __launch_bounds__(256) void gather_kernel(
    const int* __restrict__ p_data, const int* __restrict__ pa_data,
    const float* __restrict__ E, const float* __restrict__ diff_W,
    float* __restrict__ qemb, unsigned short* __restrict__ qembb,
    float* __restrict__ qaemb, unsigned short* __restrict__ qaembb)
{
  int idx = blockIdx.x * 256 + threadIdx.x;
  if (idx >= 8192 * 512) return;
  int row = idx >> 9, c = idx & 511;
  int p = p_data[row];
  float pid = diff_W[p];
  if (c < 256) {
    float v = E[(size_t)p * 256 + c] + pid;
    qemb[(size_t)row * 256 + c] = v;
    qembb[(size_t)row * 256 + c] = f2bf(v);
  }
  int pa = pa_data[row];
  int ppos = (pa > 4096) ? pa - 4096 : 0;
  int pneg = (pa <= 4096) ? pa : 0;
  float v = (c < 256) ? E[(size_t)ppos * 256 + c] : E[(size_t)pneg * 256 + (c - 256)];
  v += pid;
  qaemb[(size_t)row * 512 + c] = v;
  qaembb[(size_t)row * 512 + c] = f2bf(v);
}

// ---------------- c_reg ----------------
__global__ __launch_bounds__(256) void creg_kernel(
    const int* __restrict__ p_data, const float* __restrict__ dW,
    float* __restrict__ out)
{
  __shared__ float red[256];
  float s = 0.f;
  for (int i = threadIdx.x; i < 8192; i += 256) {
    float v = dW[p_data[i]];
    s += v * v;
  }
  float tot = block_reduce_sum(s, red);
  if (threadIdx.x == 0) out[0] = tot * 1e-5f;
}

// ---------------- MFMA distance-decay attention v7 ----------------
// 16 query rows/block, 512 threads (8 waves). CHUNK elems/lane in softmax.
// f32 scores in swizzled LDS: addr(r,j) = r*RS + j + 4*(j>>5), RS = 36*CHUNK+4.
// Softmax pre-splits P into bf16 hi/lo planes (block-permuted, conflict-free);
// PV is pure ds_read_b128 + MFMA. XCD-aware bijective block swizzle.
template<int DK, int DV, int MASKK, int ZP, int CHUNK>
__global__ __launch_bounds__(512, 4) void attn5_kernel(
    const unsigned short* __restrict__ QKb, const unsigned short* __restrict__ Vt,
    const float* __restrict__ gamp, unsigned short* __restrict__ O,
    int S, int MT, int bxoff)
{
  constexpr int RS = 36 * CHUNK + 4;
  constexpr int LBITS = (CHUNK == 32) ? 2 : 1;      // log2(CHUNK/8)
  constexpr int LM = (1 << LBITS) - 1;
  constexpr int HIOFF = 64 * CHUNK;                  // hi-plane bytes per row
  const int DMK = NHEADS * DK, DMV = NHEADS * DV;
  const int nIb = gridDim.x;
  const int id = blockIdx.x + blockIdx.y * nIb;
  const int cpx = nIb * 8;
  const int W = (id & 7) * cpx + (id >> 3);
  const int ib = W % nIb;
  const int bh = W / nIb;
  const int i0 = (ib + bxoff) * 16;
  const int b = bh >> 3, h = bh & 7;
  const int tid = threadIdx.x;
  const int lane = tid & 63, w = tid >> 6;
  const size_t rowbase = (size_t)b * S;

  constexpr int NP = (DV == 32) ? 6 : 4;
  __shared__ __align__(16) float sc[16 * RS];
  __shared__ float red[NP * 16 * 17];

  const int jmaxBlk = MASKK ? (i0 + 15) : (i0 + 14);
  const int nT = jmaxBlk / 64 + 1;
  const int NK = nT * 64;

  const int qr = lane & 15;
  const int ko8 = (lane >> 4) * 8;
  const float rscale = rsqrtf((float)DK);

  bfrag qf[DK / 32];
  #pragma unroll
  for (int ks = 0; ks < DK / 32; ++ks)
    qf[ks] = *(const bfrag*)(QKb + (rowbase + i0 + qr) * DMK + h * DK + ks * 32 + ko8);

  // ---- QK^T (rscale folded into scatter) ----
  for (int t0 = 0; t0 < NK; t0 += 128) {
    int tt = t0 + (w >> 2) * 64;
    if (tt < NK) {
      int jb = tt + (w & 3) * 16 + qr;
      bfrag kf[DK / 32];
      #pragma unroll
      for (int ks = 0; ks < DK / 32; ++ks)
        kf[ks] = *(const bfrag*)(QKb + (rowbase + jb) * DMK + h * DK + ks * 32 + ko8);
      f32x4 accs = {};
      #pragma unroll
      for (int ks = 0; ks < DK / 32; ++ks)
        accs = __builtin_amdgcn_mfma_f32_16x16x32_bf16(qf[ks], kf[ks], accs, 0, 0, 0);
      int ja = jb + 4 * (jb >> 5);
      int r0 = (lane >> 4) * 4;
      #pragma unroll
      for (int q = 0; q < 4; ++q)
        sc[(r0 + q) * RS + ja] = accs[q] * rscale;
    }
  }
  __syncthreads();

  // ---- softmax pipeline: group g (32 lanes) owns query row g; CHUNK elems/lane ----
  {
    const int g = tid >> 5, l = tid & 31;
    const int i = i0 + g;
    const int jmax = MASKK ? i : i - 1;
    const int jb0 = CHUNK * l;
    const int sb = g * RS + jb0 + 4 * (jb0 >> 5);

    float p[CHUNK];
    float m1 = -1e30f;
    #pragma unroll
    for (int c = 0; c < CHUNK / 4; ++c) {
      f32x4 v = *(const f32x4*)(sc + sb + c * 4);
      #pragma unroll
      for (int k = 0; k < 4; ++k) {
        int j = jb0 + c * 4 + k;
        float s = (j <= jmax) ? v[k] : -1e30f;
        p[c * 4 + k] = s;
        m1 = fmaxf(m1, s);
      }
    }
    #pragma unroll
    for (int o = 16; o > 0; o >>= 1) m1 = fmaxf(m1, __shfl_xor(m1, o, 32));

    float e1[CHUNK];
    float lloc = 0.f;
    #pragma unroll
    for (int t = 0; t < CHUNK; ++t) { e1[t] = __expf(p[t] - m1); lloc += e1[t]; }
    float l1 = lloc;
    #pragma unroll
    for (int o = 16; o > 0; o >>= 1) l1 += __shfl_xor(l1, o, 32);
    float inv1 = 1.f / l1;

    float scn = lloc * inv1;
    #pragma unroll
    for (int o = 1; o < 32; o <<= 1) {
      float u = __shfl_up(scn, o, 32);
      if (l >= o) scn += u;
    }
    float cum = scn - lloc * inv1;

    float gv = gamp[h];
    float sp = fmaxf(gv, 0.f) + log1pf(__expf(-fabsf(gv)));
    float gm = -sp;
    float dj = (float)(i - jb0);
    float m2 = -1e30f;
    #pragma unroll
    for (int t = 0; t < CHUNK; ++t) {
      cum += e1[t] * inv1;
      float rem = fmaxf(1.f - cum, 0.f);
      float dist = sqrtf(rem * fabsf(dj));
      dj -= 1.f;
      float eff = fmaxf(__expf(gm * dist), 1e-5f);
      p[t] = p[t] * eff;
      m2 = fmaxf(m2, p[t]);
    }
    #pragma unroll
    for (int o = 16; o > 0; o >>= 1) m2 = fmaxf(m2, __shfl_xor(m2, o, 32));

    float l2 = 0.f;
    #pragma unroll
    for (int t = 0; t < CHUNK; ++t) { p[t] = __expf(p[t] - m2); l2 += p[t]; }
    #pragma unroll
    for (int o = 16; o > 0; o >>= 1) l2 += __shfl_xor(l2, o, 32);
    bool validrow = (jmax >= 0) && !(ZP && i == 0);
    float wgt = validrow ? (1.f / l2) : 0.f;

    // convert to bf16 hi/lo planes once (PV consumes without conversion)
    char* rowB = (char*)sc + (size_t)g * (RS * 4);
    #pragma unroll
    for (int k = 0; k < CHUNK / 8; ++k) {
      int bb = (CHUNK / 8) * l + k;
      int pb = ((bb & LM) << 5) | (bb >> LBITS);
      u16x8 hi8, lo8;
      #pragma unroll
      for (int e = 0; e < 8; ++e) {
        float v = p[8 * k + e] * wgt;
        __bf16 hb = (__bf16)v;
        hi8[e] = __builtin_bit_cast(unsigned short, hb);
        lo8[e] = __builtin_bit_cast(unsigned short, (__bf16)(v - (float)hb));
      }
      *(u16x8*)(rowB + 16 * pb) = hi8;
      *(u16x8*)(rowB + HIOFF + 16 * pb) = lo8;
    }
  }
  __syncthreads();

  // ---- PV: wave owns (d-block, tile-parity); pure loads + MFMA ----
  const int dblk = (DV == 64) ? (w & 3) : (w & 1);
  const int par  = (DV == 64) ? (w >> 2) : (w >> 1);
  const int NPAR = (DV == 64) ? 2 : 4;
  const int NFIN = (DV == 64) ? 4 : 2;
  f32x4 acco = {};
  const int dcol = h * DV + dblk * 16 + (lane & 15);
  const char* rowB = (const char*)sc + (size_t)qr * (RS * 4);
  const unsigned short* vrow = Vt + (size_t)dcol * MT + rowbase;
  for (int t0 = par * 64; t0 < NK; t0 += NPAR * 64) {
    #pragma unroll
    for (int ks = 0; ks < 2; ++ks) {
      int jo = t0 + ks * 32 + ko8;
      int bb = jo >> 3;
      int pb = ((bb & LM) << 5) | (bb >> LBITS);
      bfrag ph = *(const bfrag*)(rowB + 16 * pb);
      bfrag pl = *(const bfrag*)(rowB + HIOFF + 16 * pb);
      bfrag vf = *(const bfrag*)(vrow + jo);
      acco = __builtin_amdgcn_mfma_f32_16x16x32_bf16(pl, vf, acco, 0, 0, 0);
      acco = __builtin_amdgcn_mfma_f32_16x16x32_bf16(ph, vf, acco, 0, 0, 0);
    }
  }

  if (w >= NFIN) {
    #pragma unroll
    for (int q = 0; q < 4; ++q)
      red[(w - NFIN) * 272 + ((lane >> 4) * 4 + q) * 17 + (lane & 15)] = acco[q];
  }
  __syncthreads();
  if (w < NFIN) {
    for (int pp = w; pp < NP; pp += NFIN) {
      #pragma unroll
      for (int q = 0; q < 4; ++q)
        acco[q] += red[pp * 272 + ((lane >> 4) * 4 + q) * 17 + (lane & 15)];
    }
    int r0 = (lane >> 4) * 4;
    #pragma unroll
    for (int q = 0; q < 4; ++q)
      O[(rowbase + i0 + r0 + q) * DMV + dcol] = f2bf(acco[q]);
  }
}

// ---------------- LayerNorm v4: one row per wave, float4 loads ----------------
template<int D, bool WF, bool WB>
__global__ __launch_bounds__(256) void ln4_kernel(
    const float* __restrict__ X, const float* __restrict__ R,
    const float* __restrict__ g, const float* __restrict__ be,
    float* __restrict__ Y, unsigned short* __restrict__ Yb)
{
  constexpr int NC = D / 256;
  int row = blockIdx.x * 4 + (threadIdx.x >> 6);
  int lane = threadIdx.x & 63;
  const float* x = X + (size_t)row * D;
  f32x4 xv[NC];
  float s = 0.f;
  #pragma unroll
  for (int c = 0; c < NC; ++c) {
    xv[c] = *(const f32x4*)(x + c * 256 + lane * 4);
    if (R) {
      f32x4 rv = *(const f32x4*)(R + (size_t)row * D + c * 256 + lane * 4);
      #pragma unroll
      for (int k = 0; k < 4; ++k) xv[c][k] += rv[k];
    }
    #pragma unroll
    for (int k = 0; k < 4; ++k) s += xv[c][k];
  }
  #pragma unroll
  for (int o = 32; o > 0; o >>= 1) s += __shfl_xor(s, o, 64);
  float mean = s / (float)D;
  float vs = 0.f;
  #pragma unroll
  for (int c = 0; c < NC; ++c)
    #pragma unroll
    for (int k = 0; k < 4; ++k) { float d = xv[c][k] - mean; vs += d * d; }
  #pragma unroll
  for (int o = 32; o > 0; o >>= 1) vs += __shfl_xor(vs, o, 64);
  float rstd = rsqrtf(vs / (float)D + 1e-5f);
  #pragma unroll
  for (int c = 0; c < NC; ++c) {
    f32x4 gv = *(const f32x4*)(g + c * 256 + lane * 4);
    f32x4 bv = *(const f32x4*)(be + c * 256 + lane * 4);
    f32x4 ov;
    #pragma unroll
    for (int k = 0; k < 4; ++k) ov[k] = gv[k] * (xv[c][k] - mean) * rstd + bv[k];
    if (WF) *(f32x4*)(Y + (size_t)row * D + c * 256 + lane * 4) = ov;
    if (WB) {
      ushort4 h4 = { f2bf(ov[0]), f2bf(ov[1]), f2bf(ov[2]), f2bf(ov[3]) };
      *(ushort4*)(Yb + (size_t)row * D + c * 256 + lane * 4) = h4;
    }
  }
}

// ---------------- fused concat + LN (D=512) ----------------
__global__ __launch_bounds__(256) void lnc_kernel(
    const float* __restrict__ Xh, const float* __restrict__ Qe,
    const float* __restrict__ g, const float* __restrict__ be,
    unsigned short* __restrict__ Yb)
{
  int row = blockIdx.x * 4 + (threadIdx.x >> 6);
  int lane = threadIdx.x & 63;
  f32x4 xv[2];
  xv[0] = *(const f32x4*)(Xh + (size_t)row * 256 + lane * 4);
  xv[1] = *(const f32x4*)(Qe + (size_t)row * 256 + lane * 4);
  float s = 0.f;
  #pragma unroll
  for (int c = 0; c < 2; ++c)
    #pragma unroll
    for (int k = 0; k < 4; ++k) s += xv[c][k];
  #pragma unroll
  for (int o = 32; o > 0; o >>= 1) s += __shfl_xor(s, o, 64);
  float mean = s / 512.f;
  float vs = 0.f;
  #pragma unroll
  for (int c = 0; c < 2; ++c)
    #pragma unroll
    for (int k = 0; k < 4; ++k) { float d = xv[c][k] - mean; vs += d * d; }
  #pragma unroll
  for (int o = 32; o > 0; o >>= 1) vs += __shfl_xor(vs, o, 64);
  float rstd = rsqrtf(vs / 512.f + 1e-5f);
  #pragma unroll
  for (int c = 0; c < 2; ++c) {
    f32x4 gv = *(const f32x4*)(g + c * 256 + lane * 4);
    f32x4 bv = *(const f32x4*)(be + c * 256 + lane * 4);
    ushort4 h4;
    #pragma unroll
    for (int k = 0; k < 4; ++k) {
      float ov = gv[k] * (xv[c][k] - mean) * rstd + bv[k];
      ((unsigned short*)&h4)[k] = f2bf(ov);
    }
    *(ushort4*)(Yb + (size_t)row * 512 + c * 256 + lane * 4) = h4;
  }
}

// ---------------- fused LN(D=256) + dot ----------------
__global__ __launch_bounds__(256) void lndot_kernel(
    const float* __restrict__ X, const float* __restrict__ g,
    const float* __restrict__ be, const float* __restrict__ w3,
    const float* __restrict__ b3, float* __restrict__ out)
{
  int row = blockIdx.x * 4 + (threadIdx.x >> 6);
  int lane = threadIdx.x & 63;
  f32x4 v = *(const f32x4*)(X + (size_t)row * 256 + lane * 4);
  float s = v[0] + v[1] + v[2] + v[3];
  #pragma unroll
  for (int o = 32; o > 0; o >>= 1) s += __shfl_xor(s, o, 64);
  float mean = s / 256.f;
  float vs = 0.f;
  #pragma unroll
  for (int k = 0; k < 4; ++k) { float d = v[k] - mean; vs += d * d; }
  #pragma unroll
  for (int o = 32; o > 0; o >>= 1) vs += __shfl_xor(vs, o, 64);
  float rstd = rsqrtf(vs / 256.f + 1e-5f);
  f32x4 gv = *(const f32x4*)(g + lane * 4);
  f32x4 bv = *(const f32x4*)(be + lane * 4);
  f32x4 wv = *(const f32x4*)(w3 + lane * 4);
  float d = 0.f;
  #pragma unroll
  for (int k = 0; k < 4; ++k)
    d += (gv[k] * (v[k] - mean) * rstd + bv[k]) * wv[k];
  #pragma unroll
  for (int o = 32; o > 0; o >>= 1) d += __shfl_xor(d, o, 64);
  if (lane == 0) out[row] = d + b3[0];
}

// ---------------- launch ----------------
extern "C" void kernel_launch(void* const* d_in, const int* in_sizes, int n_in,
                              void* d_out, int out_size, void* d_ws, size_t ws_size,
                              hipStream_t stream) {
  const int* p_data  = (const int*)d_in[0];
  const int* pa_data = (const int*)d_in[1];
  const float* pemb_W = (const float*)d_in[3];
  const float* diff_W = (const float*)d_in[4];
  const float* qemb_W = (const float*)d_in[5];
  const float* qemb_b = (const float*)d_in[6];
  const float* y_kW = (const float*)d_in[7];   const float* y_kb = (const float*)d_in[8];
  const float* y_vW = (const float*)d_in[9];   const float* y_vb = (const float*)d_in[10];
  const float* y_oW = (const float*)d_in[11];  const float* y_ob = (const float*)d_in[12];
  const float* y_gam = (const float*)d_in[13];
  const float* y_ln1g = (const float*)d_in[14]; const float* y_ln1b = (const float*)d_in[15];
  const float* y_f1W = (const float*)d_in[16]; const float* y_f1b = (const float*)d_in[17];
  const float* y_f2W = (const float*)d_in[18]; const float* y_f2b = (const float*)d_in[19];
  const float* y_ln2g = (const float*)d_in[20]; const float* y_ln2b = (const float*)d_in[21];
  const float* x_kW = (const float*)d_in[22];  const float* x_kb = (const float*)d_in[23];
  const float* x_vW = (const float*)d_in[24];  const float* x_vb = (const float*)d_in[25];
  const float* x_oW = (const float*)d_in[26];  const float* x_ob = (const float*)d_in[27];
  const float* x_gam = (const float*)d_in[28];
  const float* x_ln1g = (const float*)d_in[29]; const float* x_ln1b = (const float*)d_in[30];
  const float* h_kW = (const float*)d_in[31];  const float* h_kb = (const float*)d_in[32];
  const float* h_vW = (const float*)d_in[33];  const float* h_vb = (const float*)d_in[34];
  const float* h_oW = (const float*)d_in[35];  const float* h_ob = (const float*)d_in[36];
  const float* h_gam = (const float*)d_in[37];
  const float* h_ln1g = (const float*)d_in[38]; const float* h_ln1b = (const float*)d_in[39];
  const float* h_f1W = (const float*)d_in[40]; const float* h_f1b = (const float*)d_in[41];
  const float* h_f2W = (const float*)d_in[42]; const float* h_f2b = (const float*)d_in[43];
  const float* h_ln2g = (const float*)d_in[44]; const float* h_ln2b = (const float*)d_in[45];
  const float* oln1g = (const float*)d_in[46]; const float* oln1b = (const float*)d_in[47];
  const float* o1W = (const float*)d_in[48];   const float* o1b = (const float*)d_in[49];
  const float* oln2g = (const float*)d_in[50]; const float* oln2b = (const float*)d_in[51];
  const float* o2W = (const float*)d_in[52];   const float* o2b = (const float*)d_in[53];
  const float* oln3g = (const float*)d_in[54]; const float* oln3b = (const float*)d_in[55];
  const float* o3W = (const float*)d_in[56];   const float* o3b = (const float*)d_in[57];

  float* out_f = (float*)d_out;

  const int B = 8, S = 1024, M = B * S;
  const int R = 4097, KQ = 1025, KQP = 1056;

  float* ws = (float*)d_ws;
  size_t off = 0;
  auto alloc = [&](size_t nfloats) { size_t o = off; off += (nfloats + 255) & ~(size_t)255; return o; };
  auto allocs = [&](size_t nshorts) { return alloc((nshorts + 1) / 2); };

  size_t oE    = alloc((size_t)R * 256);
  size_t oSIGb = allocs((size_t)R * KQP);
  size_t oSSUM = alloc(R);
  size_t oQE   = alloc((size_t)M * 256);
  size_t oQEb  = allocs((size_t)M * 256);
  size_t oQA   = alloc((size_t)M * 512);
  size_t oQAb  = allocs((size_t)M * 512);
  size_t oYOb  = allocs((size_t)M * 512);
  size_t oXO   = alloc((size_t)M * 256);
  size_t oXOb  = allocs((size_t)M * 256);
  size_t oHO   = alloc((size_t)M * 256);
  size_t oS0   = alloc((size_t)M * 512);   // FFb arena (S0+S1)
  size_t oS1   = alloc((size_t)M * 512);
  size_t oS2b  = allocs((size_t)M * 512);
  size_t oS3   = alloc((size_t)M * 512);
  size_t oS4   = alloc((size_t)M * 512);
  size_t oSX   = alloc((size_t)M * 512);
  size_t oSXb  = allocs((size_t)M * 512);
  size_t oS0b  = allocs((size_t)M * 512);
  size_t oVt   = allocs((size_t)M * 512);
  size_t oWqe  = allocs((size_t)256 * KQP);
  size_t oWyk  = allocs((size_t)512 * 512);
  size_t oWyv  = allocs((size_t)512 * 512);
  size_t oWyo  = allocs((size_t)512 * 512);
  size_t oWyf1 = allocs((size_t)2048 * 512);
  size_t oWyf2 = allocs((size_t)512 * 2048);
  size_t oWxk  = allocs((size_t)256 * 256);
  size_t oWxv  = allocs((size_t)256 * 256);
  size_t oWxo  = allocs((size_t)256 * 256);
  size_t oWhk  = allocs((size_t)256 * 256);
  size_t oWhv  = allocs((size_t)512 * 512);
  size_t oWho  = allocs((size_t)256 * 512);
  size_t oWhf1 = allocs((size_t)2048 * 256);
  size_t oWhf2 = allocs((size_t)256 * 2048);
  size_t oWo1  = allocs((size_t)512 * 512);
  size_t oWo2  = allocs((size_t)256 * 512);
  (void)ws_size; (void)in_sizes; (void)n_in; (void)out_size;

  float* E    = ws + oE;
  unsigned short* SIGb = (unsigned short*)(ws + oSIGb);
  float* SSUM = ws + oSSUM;
  float* QE   = ws + oQE;   unsigned short* QEb = (unsigned short*)(ws + oQEb);
  float* QA   = ws + oQA;   unsigned short* QAb = (unsigned short*)(ws + oQAb);
  unsigned short* YOb = (unsigned short*)(ws + oYOb);
  float* XO   = ws + oXO;   unsigned short* XOb = (unsigned short*)(ws + oXOb);
  float* HO   = ws + oHO;
  float* S0   = ws + oS0;
  unsigned short* S2b = (unsigned short*)(ws + oS2b);
  float* S3   = ws + oS3;
  float* S4   = ws + oS4;
  float* SX   = ws + oSX;   unsigned short* SXb = (unsigned short*)(ws + oSXb);
  unsigned short* S0b = (unsigned short*)(ws + oS0b);
  unsigned short* Vt  = (unsigned short*)(ws + oVt);
  unsigned short* FFb = (unsigned short*)S0;

  unsigned short* Wqe  = (unsigned short*)(ws + oWqe);
  unsigned short* Wyk  = (unsigned short*)(ws + oWyk);
  unsigned short* Wyv  = (unsigned short*)(ws + oWyv);
  unsigned short* Wyo  = (unsigned short*)(ws + oWyo);
  unsigned short* Wyf1 = (unsigned short*)(ws + oWyf1);
  unsigned short* Wyf2 = (unsigned short*)(ws + oWyf2);
  unsigned short* Wxk  = (unsigned short*)(ws + oWxk);
  unsigned short* Wxv  = (unsigned short*)(ws + oWxv);
  unsigned short* Wxo  = (unsigned short*)(ws + oWxo);
  unsigned short* Whk  = (unsigned short*)(ws + oWhk);
  unsigned short* Whv  = (unsigned short*)(ws + oWhv);
  unsigned short* Who  = (unsigned short*)(ws + oWho);
  unsigned short* Whf1 = (unsigned short*)(ws + oWhf1);
  unsigned short* Whf2 = (unsigned short*)(ws + oWhf2);
  unsigned short* Wo1  = (unsigned short*)(ws + oWo1);
  unsigned short* Wo2  = (unsigned short*)(ws + oWo2);

  dim3 blk(256);
  int nElem512 = (8192 * 512 + 255) / 256;

  // ---- fused weight transposes ----
  {
    struct HD { const float* src; unsigned short* dst; int K, N, Kp; };
    const HD hd[16] = {
      {qemb_W, Wqe, KQ, 256, KQP},
      {y_kW, Wyk, 512, 512, 512}, {y_vW, Wyv, 512, 512, 512}, {y_oW, Wyo, 512, 512, 512},
      {y_f1W, Wyf1, 512, 2048, 512}, {y_f2W, Wyf2, 2048, 512, 2048},
      {x_kW, Wxk, 256, 256, 256}, {x_vW, Wxv, 256, 256, 256}, {x_oW, Wxo, 256, 256, 256},
      {h_kW, Whk, 256, 256, 256}, {h_vW, Whv, 512, 512, 512}, {h_oW, Who, 512, 256, 512},
      {h_f1W, Whf1, 256, 2048, 256}, {h_f2W, Whf2, 2048, 256, 2048},
      {o1W, Wo1, 512, 512, 512}, {o2W, Wo2, 512, 256, 512},
    };
    TPack P;
    int tot = 0;
    for (int k = 0; k < 16; ++k) {
      int tx = (hd[k].N + 31) / 32, ty = (hd[k].Kp + 31) / 32;
      P.d[k] = { hd[k].src, hd[k].dst, hd[k].K, hd[k].N, hd[k].Kp, tx, tot };
      tot += tx * ty;
    }
    tconv_all_kernel<<<dim3(tot), blk, 0, stream>>>(P);
  }

  auto gg128 = [](int Mm, int Nn) { return dim3((unsigned)(Nn / 128), (unsigned)((Mm + 127) / 128)); };
  auto gg64  = [](int Mm, int Nn) { return dim3((unsigned)(Nn / 128), (unsigned)((Mm + 63) / 64)); };

  // 1. embedding table
  sig_kernel<<<R, blk, 0, stream>>>(pemb_W, SIGb, SSUM, KQ, KQP);
  mgemm_kernel<64, 2, true, false, false><<<gg64(R, 256), blk, 0, stream>>>(SIGb, Wqe, qemb_b, E, nullptr, nullptr, R, 256, KQP, SSUM, nullptr, 0);
  gather_kernel<<<nElem512, blk, 0, stream>>>(p_data, pa_data, E, diff_W, QE, QEb, QA, QAb);
  creg_kernel<<<1, blk, 0, stream>>>(p_data, diff_W, out_f + 8192);

  dim3 ablk(512);
  dim3 lgrid(M / 4);
  dim3 agB(32, B * NHEADS), agC(32, B * NHEADS);   // CHUNK16: ib 0-31, CHUNK32: ib 32-63

  // 2. y layer (dm=512, mask_k=1, zero_pad=0, FFN). Fused KV proj.
  mgemm_kernel<128, 0, false, true, true><<<dim3(8, 64), blk, 0, stream>>>(QAb, Wyk, y_kb, nullptr, S0b, Vt, M, 1024, 512, nullptr, y_vb, 512);
  attn5_kernel<64, 64, 1, 0, 16><<<agB, ablk, 0, stream>>>(S0b, Vt, y_gam, S2b, S, M, 0);
  attn5_kernel<64, 64, 1, 0, 32><<<agC, ablk, 0, stream>>>(S0b, Vt, y_gam, S2b, S, M, 32);
  mgemm_kernel<128, 0, true, false, false><<<gg128(M, 512), blk, 0, stream>>>(S2b, Wyo, y_ob, S3, nullptr, nullptr, M, 512, 512, nullptr, nullptr, 0);
  ln4_kernel<512, true, true><<<lgrid, blk, 0, stream>>>(QA, S3, y_ln1g, y_ln1b, SX, SXb);
  mgemm_kernel<128, 1, false, true, false><<<gg128(M, 2048), blk, 0, stream>>>(SXb, Wyf1, y_f1b, nullptr, FFb, nullptr, M, 2048, 512, nullptr, nullptr, 0);
  mgemm_kernel<128, 0, true, false, false><<<gg128(M, 512), blk, 0, stream>>>(FFb, Wyf2, y_f2b, S4, nullptr, nullptr, M, 512, 2048, nullptr, nullptr, 0);
  ln4_kernel<512, false, true><<<lgrid, blk, 0, stream>>>(SX, S4, y_ln2g, y_ln2b, nullptr, YOb);

  // 3. x layer (dm=256, mask_k=1, zero_pad=0, no FFN). Fused KV proj.
  mgemm_kernel<128, 0, false, true, true><<<dim3(4, 64), blk, 0, stream>>>(QEb, Wxk, x_kb, nullptr, S0b, Vt, M, 512, 256, nullptr, x_vb, 256);
  attn5_kernel<32, 32, 1, 0, 16><<<agB, ablk, 0, stream>>>(S0b, Vt, x_gam, S2b, S, M, 0);
  attn5_kernel<32, 32, 1, 0, 32><<<agC, ablk, 0, stream>>>(S0b, Vt, x_gam, S2b, S, M, 32);
  mgemm_kernel<64, 0, true, false, false><<<gg64(M, 256), blk, 0, stream>>>(S2b, Wxo, x_ob, S3, nullptr, nullptr, M, 256, 256, nullptr, nullptr, 0);
  ln4_kernel<256, true, true><<<lgrid, blk, 0, stream>>>(QE, S3, x_ln1g, x_ln1b, XO, XOb);

  // 4. h layer (q,k from XO; v from YO; mask_k=0, zero_pad=1, FFN)
  mgemm_kernel<64, 0, false, true, false><<<gg64(M, 256), blk, 0, stream>>>(XOb, Whk, h_kb, nullptr, S0b, nullptr, M, 256, 256, nullptr, nullptr, 0);
  mgemm_kernel<128, 0, false, false, true><<<gg128(M, 512), blk, 0, stream>>>(YOb, Whv, h_vb, nullptr, nullptr, Vt, M, 512, 512, nullptr, nullptr, 0);
  attn5_kernel<32, 64, 0, 1, 16><<<agB, ablk, 0, stream>>>(S0b, Vt, h_gam, S2b, S, M, 0);
  attn5_kernel<32, 64, 0, 1, 32><<<agC, ablk, 0, stream>>>(S0b, Vt, h_gam, S2b, S, M, 32);
  mgemm_kernel<64, 0, true, false, false><<<gg64(M, 256), blk, 0, stream>>>(S2b, Who, h_ob, S3, nullptr, nullptr, M, 256, 512, nullptr, nullptr, 0);
  ln4_kernel<256, true, true><<<lgrid, blk, 0, stream>>>(XO, S3, h_ln1g, h_ln1b, SX, SXb);
  mgemm_kernel<128, 1, false, true, false><<<gg128(M, 2048), blk, 0, stream>>>(SXb, Whf1, h_f1b, nullptr, FFb, nullptr, M, 2048, 256, nullptr, nullptr, 0);
  mgemm_kernel<64, 0, true, false, false><<<gg64(M, 256), blk, 0, stream>>>(FFb, Whf2, h_f2b, S4, nullptr, nullptr, M, 256, 2048, nullptr, nullptr, 0);
  ln4_kernel<256, true, false><<<lgrid, blk, 0, stream>>>(SX, S4, h_ln2g, h_ln2b, HO, nullptr);

  // 5. head: LN(concat) -> o1 -> LN -> o2 -> LN+dot
  lnc_kernel<<<lgrid, blk, 0, stream>>>(HO, QE, oln1g, oln1b, SXb);
  mgemm_kernel<128, 1, true, false, false><<<gg128(M, 512), blk, 0, stream>>>(SXb, Wo1, o1b, S3, nullptr, nullptr, M, 512, 512, nullptr, nullptr, 0);
  ln4_kernel<512, false, true><<<lgrid, blk, 0, stream>>>(S3, nullptr, oln2g, oln2b, nullptr, SXb);
  mgemm_kernel<64, 1, true, false, false><<<gg64(M, 256), blk, 0, stream>>>(SXb, Wo2, o2b, S4, nullptr, nullptr, M, 256, 512, nullptr, nullptr, 0);
  lndot_kernel<<<lgrid, blk, 0, stream>>>(S4, oln3g, oln3b, o3W, o3b, out_f);
}

// Round 9
// 850.737 us; speedup vs baseline: 11.8641x; 1.0208x over previous
//
#include <hip/hip_runtime.h>
#include <hip/hip_bf16.h>
#include <math.h>

#define NHEADS 8

typedef __attribute__((ext_vector_type(8))) __bf16 bfrag;
typedef __attribute__((ext_vector_type(4))) float f32x4;
typedef __attribute__((ext_vector_type(8))) unsigned short u16x8;

static __device__ __forceinline__ unsigned short f2bf(float f) {
  unsigned u = __float_as_uint(f);
  unsigned r = (u + 0x7fffu + ((u >> 16) & 1u)) >> 16;
  return (unsigned short)r;
}

static __device__ __forceinline__ void gload_lds16(const void* g, void* l) {
  __builtin_amdgcn_global_load_lds(
      (const __attribute__((address_space(1))) unsigned int*)g,
      (__attribute__((address_space(3))) unsigned int*)l, 16, 0, 0);
}

static __device__ __forceinline__ float block_reduce_sum(float v, float* red) {
  int t = threadIdx.x;
  red[t] = v; __syncthreads();
  for (int s = 128; s > 0; s >>= 1) {
    if (t < s) red[t] += red[t + s];
    __syncthreads();
  }
  float r = red[0];
  __syncthreads();
  return r;
}

// ---------------- sigmoid table (bf16, padded to Kp) + row sums ----------------
__global__ __launch_bounds__(256) void sig_kernel(
    const float* __restrict__ Wp, unsigned short* __restrict__ Sgb,
    float* __restrict__ Ssum, int Kd, int Kp)
{
  __shared__ float red[256];
  int row = blockIdx.x;
  float s = 0.f;
  for (int k = threadIdx.x; k < Kp; k += 256) {
    float v = 0.f;
    if (k < Kd) {
      v = 1.f / (1.f + __expf(-Wp[(size_t)row * Kd + k]));
      s += v;
    }
    Sgb[(size_t)row * Kp + k] = f2bf(v);
  }
  float tot = block_reduce_sum(s, red);
  if (threadIdx.x == 0) Ssum[row] = tot;
}

// ---------------- fused transpose+convert for all weights ----------------
struct TDesc { const float* src; unsigned short* dst; int K, N, Kp, tilesX, blk0; };
struct TPack { TDesc d[16]; };

__global__ __launch_bounds__(256) void tconv_all_kernel(TPack P) {
  __shared__ float t[32][33];
  int bid = blockIdx.x;
  int di = 0;
  #pragma unroll
  for (int k = 1; k < 16; ++k) if (bid >= P.d[k].blk0) di = k;
  const float* src = P.d[di].src;
  unsigned short* dst = P.d[di].dst;
  int K = P.d[di].K, N = P.d[di].N, Kp = P.d[di].Kp, tilesX = P.d[di].tilesX;
  int local = bid - P.d[di].blk0;
  int bn = (local % tilesX) * 32;
  int bk = (local / tilesX) * 32;
  int tid = threadIdx.x;
  int tx = tid & 31, ty = tid >> 5;
  #pragma unroll
  for (int u = 0; u < 4; ++u) {
    int k = bk + ty + u * 8, n = bn + tx;
    t[ty + u * 8][tx] = (k < K && n < N) ? src[(size_t)k * N + n] : 0.f;
  }
  __syncthreads();
  #pragma unroll
  for (int u = 0; u < 4; ++u) {
    int n = bn + ty + u * 8, kk = bk + tx;
    if (n < N && kk < Kp)
      dst[(size_t)n * Kp + kk] = f2bf(t[tx][ty + u * 8]);
  }
}

// ---------------- MFMA bf16 GEMM: C = epi(A @ Bt^T + bias) ----------------
template<int BM, int EPI, bool WF32, bool WBF, bool WTR>
__global__ __launch_bounds__(256) void mgemm_kernel(
    const unsigned short* __restrict__ A, const unsigned short* __restrict__ Bt,
    const float* __restrict__ bias, float* __restrict__ C,
    unsigned short* __restrict__ Cb, unsigned short* __restrict__ Ct,
    int M, int N, int K, const float* __restrict__ divv,
    const float* __restrict__ bias2, int Nk)
{
  constexpr int NJ = (BM == 128) ? 4 : 2;
  constexpr bool SPLIT = WBF && WTR;
  __shared__ __align__(16) unsigned short Als[BM * 32];
  __shared__ __align__(16) unsigned short Bls[128 * 32];
  const int tid = threadIdx.x;
  const int lane = tid & 63, w = tid >> 6;
  const int wm = (BM == 128) ? (w >> 1) : 0;
  const int wn = (BM == 128) ? (w & 1) : w;
  const int brow = blockIdx.y * BM, bcol = blockIdx.x * 128;

  f32x4 acc[4][NJ] = {};

  for (int k0 = 0; k0 < K; k0 += 32) {
    #pragma unroll
    for (int q = 0; q < 2; ++q) {
      int s = w * 128 + q * 64 + lane;
      int r = s >> 2, g = s & 3;
      int gs = g ^ (r & 3);
      int gc = bcol + r; if (gc > N - 1) gc = N - 1;
      gload_lds16(Bt + (size_t)gc * K + k0 + gs * 8,
                  (char*)Bls + (w * 2048 + q * 1024));
    }
    if constexpr (BM == 128) {
      #pragma unroll
      for (int q = 0; q < 2; ++q) {
        int s = w * 128 + q * 64 + lane;
        int r = s >> 2, g = s & 3;
        int gs = g ^ (r & 3);
        int gr = brow + r; if (gr > M - 1) gr = M - 1;
        gload_lds16(A + (size_t)gr * K + k0 + gs * 8,
                    (char*)Als + (w * 2048 + q * 1024));
      }
    } else {
      int s = w * 64 + lane;
      int r = s >> 2, g = s & 3;
      int gs = g ^ (r & 3);
      int gr = brow + r; if (gr > M - 1) gr = M - 1;
      gload_lds16(A + (size_t)gr * K + k0 + gs * 8,
                  (char*)Als + w * 1024);
    }
    __syncthreads();

    bfrag av[4], bv[NJ];
    #pragma unroll
    for (int f = 0; f < 4; ++f) {
      int rA = wm * 64 + f * 16 + (lane & 15);
      av[f] = *(const bfrag*)((const char*)Als + rA * 64 + ((((lane >> 4) ^ (rA & 3))) << 4));
    }
    #pragma unroll
    for (int f = 0; f < NJ; ++f) {
      int rB = wn * (16 * NJ) + f * 16 + (lane & 15);
      bv[f] = *(const bfrag*)((const char*)Bls + rB * 64 + ((((lane >> 4) ^ (rB & 3))) << 4));
    }
    #pragma unroll
    for (int i = 0; i < 4; ++i)
      #pragma unroll
      for (int j = 0; j < NJ; ++j)
        acc[i][j] = __builtin_amdgcn_mfma_f32_16x16x32_bf16(av[i], bv[j], acc[i][j], 0, 0, 0);
    __syncthreads();
  }

  #pragma unroll
  for (int i = 0; i < 4; ++i) {
    int gr0 = brow + wm * 64 + i * 16 + (lane >> 4) * 4;
    #pragma unroll
    for (int j = 0; j < NJ; ++j) {
      int gc = bcol + wn * (16 * NJ) + j * 16 + (lane & 15);
      float bsv;
      if (SPLIT) bsv = (gc < Nk) ? bias[gc] : bias2[gc - Nk];
      else       bsv = bias ? bias[gc] : 0.f;
      float vv[4];
      #pragma unroll
      for (int q = 0; q < 4; ++q) {
        int gr = gr0 + q;
        float v = acc[i][j][q] + bsv;
        if (EPI >= 1) v = fmaxf(v, 0.f);
        if (EPI == 2) v = (gr < M) ? v / divv[gr] : v;
        vv[q] = v;
      }
      if (SPLIT) {
        if (gc < Nk) {
          #pragma unroll
          for (int q = 0; q < 4; ++q) {
            int gr = gr0 + q;
            if (gr < M) Cb[(size_t)gr * Nk + gc] = f2bf(vv[q]);
          }
        } else {
          ushort4 h4 = { f2bf(vv[0]), f2bf(vv[1]), f2bf(vv[2]), f2bf(vv[3]) };
          *(ushort4*)(Ct + (size_t)(gc - Nk) * M + gr0) = h4;
        }
      } else {
        #pragma unroll
        for (int q = 0; q < 4; ++q) {
          int gr = gr0 + q;
          if (gr >= M) continue;
          if (WF32) C[(size_t)gr * N + gc] = vv[q];
          if (WBF)  Cb[(size_t)gr * N + gc] = f2bf(vv[q]);
        }
        if (WTR) {
          ushort4 h4 = { f2bf(vv[0]), f2bf(vv[1]), f2bf(vv[2]), f2bf(vv[3]) };
          *(ushort4*)(Ct + (size_t)gc * M + gr0) = h4;
        }
      }
    }
  }
}

// ---------------- embedding gather ----------------
__global__ __launch_bounds__(256) void gather_kernel(
    const int* __restrict__ p_data, const int* __restrict__ pa_data,
    const float* __restrict__ E, const float* __restrict__ diff_W,
    float* __restrict__ qemb, unsigned short* __restrict__ qembb,
    float* __restrict__ qaemb, unsigned short* __restrict__ qaembb)
{
  int idx = blockIdx.x * 256 + threadIdx.x;
  if (idx >= 8192 * 512) return;
  int row = idx >> 9, c = idx & 511;
  int p = p_data[row];
  float pid = diff_W[p];
  if (c < 256) {
    float v = E[(size_t)p * 256 + c] + pid;
    qemb[(size_t)row * 256 + c] = v;
    qembb[(size_t)row * 256 + c] = f2bf(v);
  }
  int pa = pa_data[row];
  int ppos = (pa > 4096) ? pa - 4096 : 0;
  int pneg = (pa <= 4096) ? pa : 0;
  float v = (c < 256) ? E[(size_t)ppos * 256 + c] : E[(size_t)pneg * 256 + (c - 256)];
  v += pid;
  qaemb[(size_t)row * 512 + c] = v;
  qaembb[(size_t)row * 512 + c] = f2bf(v);
}

// ---------------- c_reg ----------------
__global__ __launch_bounds__(256) void creg_kernel(
    const int* __restrict__ p_data, const float* __restrict__ dW,
    float* __restrict__ out)
{
  __shared__ float red[256];
  float s = 0.f;
  for (int i = threadIdx.x; i < 8192; i += 256) {
    float v = dW[p_data[i]];
    s += v * v;
  }
  float tot = block_reduce_sum(s, red);
  if (threadIdx.x == 0) out[0] = tot * 1e-5f;
}

// ---------------- MFMA distance-decay attention v8 ----------------
// 16 query rows/block, 512 threads (8 waves). CHUNK elems/lane in softmax.
// f32 scores in swizzled LDS: addr(r,j) = r*RS + j + 4*(j>>5), RS = 36*CHUNK+4.
// Softmax pre-splits P into bf16 hi/lo planes; PV V-fragments prefetched into
// registers under the softmax tail (static-indexed). Descending-NK block order.
template<int DK, int DV, int MASKK, int ZP, int CHUNK>
__global__ __launch_bounds__(512, 4) void attn6_kernel(
    const unsigned short* __restrict__ QKb, const unsigned short* __restrict__ Vt,
    const float* __restrict__ gamp, unsigned short* __restrict__ O,
    int S, int MT, int bxoff)
{
  constexpr int RS = 36 * CHUNK + 4;
  constexpr int LBITS = (CHUNK == 32) ? 2 : 1;
  constexpr int LM = (1 << LBITS) - 1;
  constexpr int HIOFF = 64 * CHUNK;
  constexpr int NPAR = (DV == 64) ? 2 : 4;
  constexpr int NFIN = (DV == 64) ? 4 : 2;
  constexpr int NP   = (DV == 32) ? 6 : 4;
  constexpr int MAXIT = (DV == 64) ? (CHUNK == 32 ? 8 : 4) : (CHUNK == 32 ? 4 : 2);
  const int DMK = NHEADS * DK, DMV = NHEADS * DV;
  const int nIb = gridDim.x;
  const int id = blockIdx.x + blockIdx.y * nIb;
  const int cpx = nIb * 8;
  const int W = (id & 7) * cpx + (id >> 3);
  const int ib = (nIb - 1) - (W % nIb);     // descending-NK launch order
  const int bh = W / nIb;
  const int i0 = (ib + bxoff) * 16;
  const int b = bh >> 3, h = bh & 7;
  const int tid = threadIdx.x;
  const int lane = tid & 63, w = tid >> 6;
  const size_t rowbase = (size_t)b * S;

  __shared__ __align__(16) float sc[16 * RS];
  __shared__ float red[NP * 16 * 17];

  const int jmaxBlk = MASKK ? (i0 + 15) : (i0 + 14);
  const int nT = jmaxBlk / 64 + 1;
  const int NK = nT * 64;

  const int qr = lane & 15;
  const int ko8 = (lane >> 4) * 8;
  const float rscale = rsqrtf((float)DK);

  // PV role constants (needed early for prefetch)
  const int dblk = (DV == 64) ? (w & 3) : (w & 1);
  const int par  = (DV == 64) ? (w >> 2) : (w >> 1);
  const int dcol = h * DV + dblk * 16 + (lane & 15);
  const unsigned short* vrow = Vt + (size_t)dcol * MT + rowbase;
  bfrag vpre[2 * MAXIT];

  bfrag qf[DK / 32];
  #pragma unroll
  for (int ks = 0; ks < DK / 32; ++ks)
    qf[ks] = *(const bfrag*)(QKb + (rowbase + i0 + qr) * DMK + h * DK + ks * 32 + ko8);

  // ---- QK^T (rscale folded into scatter) ----
  for (int t0 = 0; t0 < NK; t0 += 128) {
    int tt = t0 + (w >> 2) * 64;
    if (tt < NK) {
      int jb = tt + (w & 3) * 16 + qr;
      bfrag kf[DK / 32];
      #pragma unroll
      for (int ks = 0; ks < DK / 32; ++ks)
        kf[ks] = *(const bfrag*)(QKb + (rowbase + jb) * DMK + h * DK + ks * 32 + ko8);
      f32x4 accs = {};
      #pragma unroll
      for (int ks = 0; ks < DK / 32; ++ks)
        accs = __builtin_amdgcn_mfma_f32_16x16x32_bf16(qf[ks], kf[ks], accs, 0, 0, 0);
      int ja = jb + 4 * (jb >> 5);
      int r0 = (lane >> 4) * 4;
      #pragma unroll
      for (int q = 0; q < 4; ++q)
        sc[(r0 + q) * RS + ja] = accs[q] * rscale;
    }
  }
  __syncthreads();

  // ---- softmax pipeline: group g (32 lanes) owns query row g; CHUNK elems/lane ----
  {
    const int g = tid >> 5, l = tid & 31;
    const int i = i0 + g;
    const int jmax = MASKK ? i : i - 1;
    const int jb0 = CHUNK * l;
    const int sb = g * RS + jb0 + 4 * (jb0 >> 5);

    float p[CHUNK];
    float m1 = -1e30f;
    #pragma unroll
    for (int c = 0; c < CHUNK / 4; ++c) {
      f32x4 v = *(const f32x4*)(sc + sb + c * 4);
      #pragma unroll
      for (int k = 0; k < 4; ++k) {
        int j = jb0 + c * 4 + k;
        float s = (j <= jmax) ? v[k] : -1e30f;
        p[c * 4 + k] = s;
        m1 = fmaxf(m1, s);
      }
    }
    #pragma unroll
    for (int o = 16; o > 0; o >>= 1) m1 = fmaxf(m1, __shfl_xor(m1, o, 32));

    float e1[CHUNK];
    float lloc = 0.f;
    #pragma unroll
    for (int t = 0; t < CHUNK; ++t) { e1[t] = __expf(p[t] - m1); lloc += e1[t]; }
    float l1 = lloc;
    #pragma unroll
    for (int o = 16; o > 0; o >>= 1) l1 += __shfl_xor(l1, o, 32);
    float inv1 = 1.f / l1;

    float scn = lloc * inv1;
    #pragma unroll
    for (int o = 1; o < 32; o <<= 1) {
      float u = __shfl_up(scn, o, 32);
      if (l >= o) scn += u;
    }
    float cum = scn - lloc * inv1;

    float gv = gamp[h];
    float sp = fmaxf(gv, 0.f) + log1pf(__expf(-fabsf(gv)));
    float gm = -sp;
    float dj = (float)(i - jb0);
    float m2 = -1e30f;
    #pragma unroll
    for (int t = 0; t < CHUNK; ++t) {
      cum += e1[t] * inv1;
      float rem = fmaxf(1.f - cum, 0.f);
      float dist = sqrtf(rem * fabsf(dj));
      dj -= 1.f;
      float eff = fmaxf(__expf(gm * dist), 1e-5f);
      p[t] = p[t] * eff;
      m2 = fmaxf(m2, p[t]);
    }
    #pragma unroll
    for (int o = 16; o > 0; o >>= 1) m2 = fmaxf(m2, __shfl_xor(m2, o, 32));

    float l2 = 0.f;
    #pragma unroll
    for (int t = 0; t < CHUNK; ++t) { p[t] = __expf(p[t] - m2); l2 += p[t]; }
    #pragma unroll
    for (int o = 16; o > 0; o >>= 1) l2 += __shfl_xor(l2, o, 32);
    bool validrow = (jmax >= 0) && !(ZP && i == 0);
    float wgt = validrow ? (1.f / l2) : 0.f;

    // ---- issue PV V-fragment prefetch; latency hides under plane conversion ----
    #pragma unroll
    for (int it = 0; it < MAXIT; ++it) {
      int t0 = (par + it * NPAR) * 64;
      int t0c = (t0 < NK) ? t0 : 0;
      #pragma unroll
      for (int ks = 0; ks < 2; ++ks)
        vpre[it * 2 + ks] = *(const bfrag*)(vrow + t0c + ks * 32 + ko8);
    }

    // convert to bf16 hi/lo planes once (PV consumes without conversion)
    char* rowB = (char*)sc + (size_t)g * (RS * 4);
    #pragma unroll
    for (int k = 0; k < CHUNK / 8; ++k) {
      int bb = (CHUNK / 8) * l + k;
      int pb = ((bb & LM) << 5) | (bb >> LBITS);
      u16x8 hi8, lo8;
      #pragma unroll
      for (int e = 0; e < 8; ++e) {
        float v = p[8 * k + e] * wgt;
        __bf16 hb = (__bf16)v;
        hi8[e] = __builtin_bit_cast(unsigned short, hb);
        lo8[e] = __builtin_bit_cast(unsigned short, (__bf16)(v - (float)hb));
      }
      *(u16x8*)(rowB + 16 * pb) = hi8;
      *(u16x8*)(rowB + HIOFF + 16 * pb) = lo8;
    }
  }
  __syncthreads();

  // ---- PV: LDS plane reads + prefetched V + MFMA ----
  f32x4 acco = {};
  const char* rowB = (const char*)sc + (size_t)qr * (RS * 4);
  #pragma unroll
  for (int it = 0; it < MAXIT; ++it) {
    int t0 = (par + it * NPAR) * 64;
    if (t0 < NK) {
      #pragma unroll
      for (int ks = 0; ks < 2; ++ks) {
        int jo = t0 + ks * 32 + ko8;
        int bb = jo >> 3;
        int pb = ((bb & LM) << 5) | (bb >> LBITS);
        bfrag ph = *(const bfrag*)(rowB + 16 * pb);
        bfrag pl = *(const bfrag*)(rowB + HIOFF + 16 * pb);
        bfrag vf = vpre[it * 2 + ks];
        acco = __builtin_amdgcn_mfma_f32_16x16x32_bf16(pl, vf, acco, 0, 0, 0);
        acco = __builtin_amdgcn_mfma_f32_16x16x32_bf16(ph, vf, acco, 0, 0, 0);
      }
    }
  }

  if (w >= NFIN) {
    #pragma unroll
    for (int q = 0; q < 4; ++q)
      red[(w - NFIN) * 272 + ((lane >> 4) * 4 + q) * 17 + (lane & 15)] = acco[q];
  }
  __syncthreads();
  if (w < NFIN) {
    for (int pp = w; pp < NP; pp += NFIN) {
      #pragma unroll
      for (int q = 0; q < 4; ++q)
        acco[q] += red[pp * 272 + ((lane >> 4) * 4 + q) * 17 + (lane & 15)];
    }
    int r0 = (lane >> 4) * 4;
    #pragma unroll
    for (int q = 0; q < 4; ++q)
      O[(rowbase + i0 + r0 + q) * DMV + dcol] = f2bf(acco[q]);
  }
}

// ---------------- LayerNorm v4: one row per wave, float4 loads ----------------
template<int D, bool WF, bool WB>
__global__ __launch_bounds__(256) void ln4_kernel(
    const float* __restrict__ X, const float* __restrict__ R,
    const float* __restrict__ g, const float* __restrict__ be,
    float* __restrict__ Y, unsigned short* __restrict__ Yb)
{
  constexpr int NC = D / 256;
  int row = blockIdx.x * 4 + (threadIdx.x >> 6);
  int lane = threadIdx.x & 63;
  const float* x = X + (size_t)row * D;
  f32x4 xv[NC];
  float s = 0.f;
  #pragma unroll
  for (int c = 0; c < NC; ++c) {
    xv[c] = *(const f32x4*)(x + c * 256 + lane * 4);
    if (R) {
      f32x4 rv = *(const f32x4*)(R + (size_t)row * D + c * 256 + lane * 4);
      #pragma unroll
      for (int k = 0; k < 4; ++k) xv[c][k] += rv[k];
    }
    #pragma unroll
    for (int k = 0; k < 4; ++k) s += xv[c][k];
  }
  #pragma unroll
  for (int o = 32; o > 0; o >>= 1) s += __shfl_xor(s, o, 64);
  float mean = s / (float)D;
  float vs = 0.f;
  #pragma unroll
  for (int c = 0; c < NC; ++c)
    #pragma unroll
    for (int k = 0; k < 4; ++k) { float d = xv[c][k] - mean; vs += d * d; }
  #pragma unroll
  for (int o = 32; o > 0; o >>= 1) vs += __shfl_xor(vs, o, 64);
  float rstd = rsqrtf(vs / (float)D + 1e-5f);
  #pragma unroll
  for (int c = 0; c < NC; ++c) {
    f32x4 gv = *(const f32x4*)(g + c * 256 + lane * 4);
    f32x4 bv = *(const f32x4*)(be + c * 256 + lane * 4);
    f32x4 ov;
    #pragma unroll
    for (int k = 0; k < 4; ++k) ov[k] = gv[k] * (xv[c][k] - mean) * rstd + bv[k];
    if (WF) *(f32x4*)(Y + (size_t)row * D + c * 256 + lane * 4) = ov;
    if (WB) {
      ushort4 h4 = { f2bf(ov[0]), f2bf(ov[1]), f2bf(ov[2]), f2bf(ov[3]) };
      *(ushort4*)(Yb + (size_t)row * D + c * 256 + lane * 4) = h4;
    }
  }
}

// ---------------- fused concat + LN (D=512) ----------------
__global__ __launch_bounds__(256) void lnc_kernel(
    const float* __restrict__ Xh, const float* __restrict__ Qe,
    const float* __restrict__ g, const float* __restrict__ be,
    unsigned short* __restrict__ Yb)
{
  int row = blockIdx.x * 4 + (threadIdx.x >> 6);
  int lane = threadIdx.x & 63;
  f32x4 xv[2];
  xv[0] = *(const f32x4*)(Xh + (size_t)row * 256 + lane * 4);
  xv[1] = *(const f32x4*)(Qe + (size_t)row * 256 + lane * 4);
  float s = 0.f;
  #pragma unroll
  for (int c = 0; c < 2; ++c)
    #pragma unroll
    for (int k = 0; k < 4; ++k) s += xv[c][k];
  #pragma unroll
  for (int o = 32; o > 0; o >>= 1) s += __shfl_xor(s, o, 64);
  float mean = s / 512.f;
  float vs = 0.f;
  #pragma unroll
  for (int c = 0; c < 2; ++c)
    #pragma unroll
    for (int k = 0; k < 4; ++k) { float d = xv[c][k] - mean; vs += d * d; }
  #pragma unroll
  for (int o = 32; o > 0; o >>= 1) vs += __shfl_xor(vs, o, 64);
  float rstd = rsqrtf(vs / 512.f + 1e-5f);
  #pragma unroll
  for (int c = 0; c < 2; ++c) {
    f32x4 gv = *(const f32x4*)(g + c * 256 + lane * 4);
    f32x4 bv = *(const f32x4*)(be + c * 256 + lane * 4);
    ushort4 h4;
    #pragma unroll
    for (int k = 0; k < 4; ++k) {
      float ov = gv[k] * (xv[c][k] - mean) * rstd + bv[k];
      ((unsigned short*)&h4)[k] = f2bf(ov);
    }
    *(ushort4*)(Yb + (size_t)row * 512 + c * 256 + lane * 4) = h4;
  }
}

// ---------------- fused LN(D=256) + dot ----------------
__global__ __launch_bounds__(256) void lndot_kernel(
    const float* __restrict__ X, const float* __restrict__ g,
    const float* __restrict__ be, const float* __restrict__ w3,
    const float* __restrict__ b3, float* __restrict__ out)
{
  int row = blockIdx.x * 4 + (threadIdx.x >> 6);
  int lane = threadIdx.x & 63;
  f32x4 v = *(const f32x4*)(X + (size_t)row * 256 + lane * 4);
  float s = v[0] + v[1] + v[2] + v[3];
  #pragma unroll
  for (int o = 32; o > 0; o >>= 1) s += __shfl_xor(s, o, 64);
  float mean = s / 256.f;
  float vs = 0.f;
  #pragma unroll
  for (int k = 0; k < 4; ++k) { float d = v[k] - mean; vs += d * d; }
  #pragma unroll
  for (int o = 32; o > 0; o >>= 1) vs += __shfl_xor(vs, o, 64);
  float rstd = rsqrtf(vs / 256.f + 1e-5f);
  f32x4 gv = *(const f32x4*)(g + lane * 4);
  f32x4 bv = *(const f32x4*)(be + lane * 4);
  f32x4 wv = *(const f32x4*)(w3 + lane * 4);
  float d = 0.f;
  #pragma unroll
  for (int k = 0; k < 4; ++k)
    d += (gv[k] * (v[k] - mean) * rstd + bv[k]) * wv[k];
  #pragma unroll
  for (int o = 32; o > 0; o >>= 1) d += __shfl_xor(d, o, 64);
  if (lane == 0) out[row] = d + b3[0];
}

// ---------------- launch ----------------
extern "C" void kernel_launch(void* const* d_in, const int* in_sizes, int n_in,
                              void* d_out, int out_size, void* d_ws, size_t ws_size,
                              hipStream_t stream) {
  const int* p_data  = (const int*)d_in[0];
  const int* pa_data = (const int*)d_in[1];
  const float* pemb_W = (const float*)d_in[3];
  const float* diff_W = (const float*)d_in[4];
  const float* qemb_W = (const float*)d_in[5];
  const float* qemb_b = (const float*)d_in[6];
  const float* y_kW = (const float*)d_in[7];   const float* y_kb = (const float*)d_in[8];
  const float* y_vW = (const float*)d_in[9];   const float* y_vb = (const float*)d_in[10];
  const float* y_oW = (const float*)d_in[11];  const float* y_ob = (const float*)d_in[12];
  const float* y_gam = (const float*)d_in[13];
  const float* y_ln1g = (const float*)d_in[14]; const float* y_ln1b = (const float*)d_in[15];
  const float* y_f1W = (const float*)d_in[16]; const float* y_f1b = (const float*)d_in[17];
  const float* y_f2W = (const float*)d_in[18]; const float* y_f2b = (const float*)d_in[19];
  const float* y_ln2g = (const float*)d_in[20]; const float* y_ln2b = (const float*)d_in[21];
  const float* x_kW = (const float*)d_in[22];  const float* x_kb = (const float*)d_in[23];
  const float* x_vW = (const float*)d_in[24];  const float* x_vb = (const float*)d_in[25];
  const float* x_oW = (const float*)d_in[26];  const float* x_ob = (const float*)d_in[27];
  const float* x_gam = (const float*)d_in[28];
  const float* x_ln1g = (const float*)d_in[29]; const float* x_ln1b = (const float*)d_in[30];
  const float* h_kW = (const float*)d_in[31];  const float* h_kb = (const float*)d_in[32];
  const float* h_vW = (const float*)d_in[33];  const float* h_vb = (const float*)d_in[34];
  const float* h_oW = (const float*)d_in[35];  const float* h_ob = (const float*)d_in[36];
  const float* h_gam = (const float*)d_in[37];
  const float* h_ln1g = (const float*)d_in[38]; const float* h_ln1b = (const float*)d_in[39];
  const float* h_f1W = (const float*)d_in[40]; const float* h_f1b = (const float*)d_in[41];
  const float* h_f2W = (const float*)d_in[42]; const float* h_f2b = (const float*)d_in[43];
  const float* h_ln2g = (const float*)d_in[44]; const float* h_ln2b = (const float*)d_in[45];
  const float* oln1g = (const float*)d_in[46]; const float* oln1b = (const float*)d_in[47];
  const float* o1W = (const float*)d_in[48];   const float* o1b = (const float*)d_in[49];
  const float* oln2g = (const float*)d_in[50]; const float* oln2b = (const float*)d_in[51];
  const float* o2W = (const float*)d_in[52];   const float* o2b = (const float*)d_in[53];
  const float* oln3g = (const float*)d_in[54]; const float* oln3b = (const float*)d_in[55];
  const float* o3W = (const float*)d_in[56];   const float* o3b = (const float*)d_in[57];

  float* out_f = (float*)d_out;

  const int B = 8, S = 1024, M = B * S;
  const int R = 4097, KQ = 1025, KQP = 1056;

  float* ws = (float*)d_ws;
  size_t off = 0;
  auto alloc = [&](size_t nfloats) { size_t o = off; off += (nfloats + 255) & ~(size_t)255; return o; };
  auto allocs = [&](size_t nshorts) { return alloc((nshorts + 1) / 2); };

  size_t oE    = alloc((size_t)R * 256);
  size_t oSIGb = allocs((size_t)R * KQP);
  size_t oSSUM = alloc(R);
  size_t oQE   = alloc((size_t)M * 256);
  size_t oQEb  = allocs((size_t)M * 256);
  size_t oQA   = alloc((size_t)M * 512);
  size_t oQAb  = allocs((size_t)M * 512);
  size_t oYOb  = allocs((size_t)M * 512);
  size_t oXO   = alloc((size_t)M * 256);
  size_t oXOb  = allocs((size_t)M * 256);
  size_t oHO   = alloc((size_t)M * 256);
  size_t oS0   = alloc((size_t)M * 512);   // FFb arena (S0+S1)
  size_t oS1   = alloc((size_t)M * 512);
  size_t oS2b  = allocs((size_t)M * 512);
  size_t oS3   = alloc((size_t)M * 512);
  size_t oS4   = alloc((size_t)M * 512);
  size_t oSX   = alloc((size_t)M * 512);
  size_t oSXb  = allocs((size_t)M * 512);
  size_t oS0b  = allocs((size_t)M * 512);
  size_t oVt   = allocs((size_t)M * 512);
  size_t oWqe  = allocs((size_t)256 * KQP);
  size_t oWyk  = allocs((size_t)512 * 512);
  size_t oWyv  = allocs((size_t)512 * 512);
  size_t oWyo  = allocs((size_t)512 * 512);
  size_t oWyf1 = allocs((size_t)2048 * 512);
  size_t oWyf2 = allocs((size_t)512 * 2048);
  size_t oWxk  = allocs((size_t)256 * 256);
  size_t oWxv  = allocs((size_t)256 * 256);
  size_t oWxo  = allocs((size_t)256 * 256);
  size_t oWhk  = allocs((size_t)256 * 256);
  size_t oWhv  = allocs((size_t)512 * 512);
  size_t oWho  = allocs((size_t)256 * 512);
  size_t oWhf1 = allocs((size_t)2048 * 256);
  size_t oWhf2 = allocs((size_t)256 * 2048);
  size_t oWo1  = allocs((size_t)512 * 512);
  size_t oWo2  = allocs((size_t)256 * 512);
  (void)ws_size; (void)in_sizes; (void)n_in; (void)out_size;

  float* E    = ws + oE;
  unsigned short* SIGb = (unsigned short*)(ws + oSIGb);
  float* SSUM = ws + oSSUM;
  float* QE   = ws + oQE;   unsigned short* QEb = (unsigned short*)(ws + oQEb);
  float* QA   = ws + oQA;   unsigned short* QAb = (unsigned short*)(ws + oQAb);
  unsigned short* YOb = (unsigned short*)(ws + oYOb);
  float* XO   = ws + oXO;   unsigned short* XOb = (unsigned short*)(ws + oXOb);
  float* HO   = ws + oHO;
  float* S0   = ws + oS0;
  unsigned short* S2b = (unsigned short*)(ws + oS2b);
  float* S3   = ws + oS3;
  float* S4   = ws + oS4;
  float* SX   = ws + oSX;   unsigned short* SXb = (unsigned short*)(ws + oSXb);
  unsigned short* S0b = (unsigned short*)(ws + oS0b);
  unsigned short* Vt  = (unsigned short*)(ws + oVt);
  unsigned short* FFb = (unsigned short*)S0;

  unsigned short* Wqe  = (unsigned short*)(ws + oWqe);
  unsigned short* Wyk  = (unsigned short*)(ws + oWyk);
  unsigned short* Wyv  = (unsigned short*)(ws + oWyv);
  unsigned short* Wyo  = (unsigned short*)(ws + oWyo);
  unsigned short* Wyf1 = (unsigned short*)(ws + oWyf1);
  unsigned short* Wyf2 = (unsigned short*)(ws + oWyf2);
  unsigned short* Wxk  = (unsigned short*)(ws + oWxk);
  unsigned short* Wxv  = (unsigned short*)(ws + oWxv);
  unsigned short* Wxo  = (unsigned short*)(ws + oWxo);
  unsigned short* Whk  = (unsigned short*)(ws + oWhk);
  unsigned short* Whv  = (unsigned short*)(ws + oWhv);
  unsigned short* Who  = (unsigned short*)(ws + oWho);
  unsigned short* Whf1 = (unsigned short*)(ws + oWhf1);
  unsigned short* Whf2 = (unsigned short*)(ws + oWhf2);
  unsigned short* Wo1  = (unsigned short*)(ws + oWo1);
  unsigned short* Wo2  = (unsigned short*)(ws + oWo2);

  dim3 blk(256);
  int nElem512 = (8192 * 512 + 255) / 256;

  // ---- fused weight transposes ----
  {
    struct HD { const float* src; unsigned short* dst; int K, N, Kp; };
    const HD hd[16] = {
      {qemb_W, Wqe, KQ, 256, KQP},
      {y_kW, Wyk, 512, 512, 512}, {y_vW, Wyv, 512, 512, 512}, {y_oW, Wyo, 512, 512, 512},
      {y_f1W, Wyf1, 512, 2048, 512}, {y_f2W, Wyf2, 2048, 512, 2048},
      {x_kW, Wxk, 256, 256, 256}, {x_vW, Wxv, 256, 256, 256}, {x_oW, Wxo, 256, 256, 256},
      {h_kW, Whk, 256, 256, 256}, {h_vW, Whv, 512, 512, 512}, {h_oW, Who, 512, 256, 512},
      {h_f1W, Whf1, 256, 2048, 256}, {h_f2W, Whf2, 2048, 256, 2048},
      {o1W, Wo1, 512, 512, 512}, {o2W, Wo2, 512, 256, 512},
    };
    TPack P;
    int tot = 0;
    for (int k = 0; k < 16; ++k) {
      int tx = (hd[k].N + 31) / 32, ty = (hd[k].Kp + 31) / 32;
      P.d[k] = { hd[k].src, hd[k].dst, hd[k].K, hd[k].N, hd[k].Kp, tx, tot };
      tot += tx * ty;
    }
    tconv_all_kernel<<<dim3(tot), blk, 0, stream>>>(P);
  }

  auto gg128 = [](int Mm, int Nn) { return dim3((unsigned)(Nn / 128), (unsigned)((Mm + 127) / 128)); };
  auto gg64  = [](int Mm, int Nn) { return dim3((unsigned)(Nn / 128), (unsigned)((Mm + 63) / 64)); };

  // 1. embedding table
  sig_kernel<<<R, blk, 0, stream>>>(pemb_W, SIGb, SSUM, KQ, KQP);
  mgemm_kernel<64, 2, true, false, false><<<gg64(R, 256), blk, 0, stream>>>(SIGb, Wqe, qemb_b, E, nullptr, nullptr, R, 256, KQP, SSUM, nullptr, 0);
  gather_kernel<<<nElem512, blk, 0, stream>>>(p_data, pa_data, E, diff_W, QE, QEb, QA, QAb);
  creg_kernel<<<1, blk, 0, stream>>>(p_data, diff_W, out_f + 8192);

  dim3 ablk(512);
  dim3 lgrid(M / 4);
  dim3 agB(32, B * NHEADS), agC(32, B * NHEADS);   // CHUNK16: ib 0-31, CHUNK32: ib 32-63

  // 2. y layer (dm=512, mask_k=1, zero_pad=0, FFN). Fused KV proj.
  mgemm_kernel<128, 0, false, true, true><<<dim3(8, 64), blk, 0, stream>>>(QAb, Wyk, y_kb, nullptr, S0b, Vt, M, 1024, 512, nullptr, y_vb, 512);
  attn6_kernel<64, 64, 1, 0, 16><<<agB, ablk, 0, stream>>>(S0b, Vt, y_gam, S2b, S, M, 0);
  attn6_kernel<64, 64, 1, 0, 32><<<agC, ablk, 0, stream>>>(S0b, Vt, y_gam, S2b, S, M, 32);
  mgemm_kernel<128, 0, true, false, false><<<gg128(M, 512), blk, 0, stream>>>(S2b, Wyo, y_ob, S3, nullptr, nullptr, M, 512, 512, nullptr, nullptr, 0);
  ln4_kernel<512, true, true><<<lgrid, blk, 0, stream>>>(QA, S3, y_ln1g, y_ln1b, SX, SXb);
  mgemm_kernel<128, 1, false, true, false><<<gg128(M, 2048), blk, 0, stream>>>(SXb, Wyf1, y_f1b, nullptr, FFb, nullptr, M, 2048, 512, nullptr, nullptr, 0);
  mgemm_kernel<128, 0, true, false, false><<<gg128(M, 512), blk, 0, stream>>>(FFb, Wyf2, y_f2b, S4, nullptr, nullptr, M, 512, 2048, nullptr, nullptr, 0);
  ln4_kernel<512, false, true><<<lgrid, blk, 0, stream>>>(SX, S4, y_ln2g, y_ln2b, nullptr, YOb);

  // 3. x layer (dm=256, mask_k=1, zero_pad=0, no FFN). Fused KV proj.
  mgemm_kernel<128, 0, false, true, true><<<dim3(4, 64), blk, 0, stream>>>(QEb, Wxk, x_kb, nullptr, S0b, Vt, M, 512, 256, nullptr, x_vb, 256);
  attn6_kernel<32, 32, 1, 0, 16><<<agB, ablk, 0, stream>>>(S0b, Vt, x_gam, S2b, S, M, 0);
  attn6_kernel<32, 32, 1, 0, 32><<<agC, ablk, 0, stream>>>(S0b, Vt, x_gam, S2b, S, M, 32);
  mgemm_kernel<64, 0, true, false, false><<<gg64(M, 256), blk, 0, stream>>>(S2b, Wxo, x_ob, S3, nullptr, nullptr, M, 256, 256, nullptr, nullptr, 0);
  ln4_kernel<256, true, true><<<lgrid, blk, 0, stream>>>(QE, S3, x_ln1g, x_ln1b, XO, XOb);

  // 4. h layer (q,k from XO; v from YO; mask_k=0, zero_pad=1, FFN)
  mgemm_kernel<64, 0, false, true, false><<<gg64(M, 256), blk, 0, stream>>>(XOb, Whk, h_kb, nullptr, S0b, nullptr, M, 256, 256, nullptr, nullptr, 0);
  mgemm_kernel<128, 0, false, false, true><<<gg128(M, 512), blk, 0, stream>>>(YOb, Whv, h_vb, nullptr, nullptr, Vt, M, 512, 512, nullptr, nullptr, 0);
  attn6_kernel<32, 64, 0, 1, 16><<<agB, ablk, 0, stream>>>(S0b, Vt, h_gam, S2b, S, M, 0);
  attn6_kernel<32, 64, 0, 1, 32><<<agC, ablk, 0, stream>>>(S0b, Vt, h_gam, S2b, S, M, 32);
  mgemm_kernel<64, 0, true, false, false><<<gg64(M, 256), blk, 0, stream>>>(S2b, Who, h_ob, S3, nullptr, nullptr, M, 256, 512, nullptr, nullptr, 0);
  ln4_kernel<256, true, true><<<lgrid, blk, 0, stream>>>(XO, S3, h_ln1g, h_ln1b, SX, SXb);
  mgemm_kernel<128, 1, false, true, false><<<gg128(M, 2048), blk, 0, stream>>>(SXb, Whf1, h_f1b, nullptr, FFb, nullptr, M, 2048, 256, nullptr, nullptr, 0);
  mgemm_kernel<64, 0, true, false, false><<<gg64(M, 256), blk, 0, stream>>>(FFb, Whf2, h_f2b, S4, nullptr, nullptr, M, 256, 2048, nullptr, nullptr, 0);
  ln4_kernel<256, true, false><<<lgrid, blk, 0, stream>>>(SX, S4, h_ln2g, h_ln2b, HO, nullptr);

  // 5. head: LN(concat) -> o1 -> LN -> o2 -> LN+dot
  lnc_kernel<<<lgrid, blk, 0, stream>>>(HO, QE, oln1g, oln1b, SXb);
  mgemm_kernel<128, 1, true, false, false><<<gg128(M, 512), blk, 0, stream>>>(SXb, Wo1, o1b, S3, nullptr, nullptr, M, 512, 512, nullptr, nullptr, 0);
  ln4_kernel<512, false, true><<<lgrid, blk, 0, stream>>>(S3, nullptr, oln2g, oln2b, nullptr, SXb);
  mgemm_kernel<64, 1, true, false, false><<<gg64(M, 256), blk, 0, stream>>>(SXb, Wo2, o2b, S4, nullptr, nullptr, M, 256, 512, nullptr, nullptr, 0);
  lndot_kernel<<<lgrid, blk, 0, stream>>>(S4, oln3g, oln3b, o3W, o3b, out_f);
}

// Round 10
// 836.756 us; speedup vs baseline: 12.0623x; 1.0167x over previous
//
#include <hip/hip_runtime.h>
#include <hip/hip_bf16.h>
#include <math.h>

#define NHEADS 8
#define L2E 1.44269504f

typedef __attribute__((ext_vector_type(8))) __bf16 bfrag;
typedef __attribute__((ext_vector_type(4))) float f32x4;
typedef __attribute__((ext_vector_type(8))) unsigned short u16x8;

static __device__ __forceinline__ unsigned short f2bf(float f) {
  unsigned u = __float_as_uint(f);
  unsigned r = (u + 0x7fffu + ((u >> 16) & 1u)) >> 16;
  return (unsigned short)r;
}

static __device__ __forceinline__ void gload_lds16(const void* g, void* l) {
  __builtin_amdgcn_global_load_lds(
      (const __attribute__((address_space(1))) unsigned int*)g,
      (__attribute__((address_space(3))) unsigned int*)l, 16, 0, 0);
}

static __device__ __forceinline__ float block_reduce_sum(float v, float* red) {
  int t = threadIdx.x;
  red[t] = v; __syncthreads();
  for (int s = 128; s > 0; s >>= 1) {
    if (t < s) red[t] += red[t + s];
    __syncthreads();
  }
  float r = red[0];
  __syncthreads();
  return r;
}

// ---------------- sigmoid table (bf16, padded to Kp) + row sums ----------------
__global__ __launch_bounds__(256) void sig_kernel(
    const float* __restrict__ Wp, unsigned short* __restrict__ Sgb,
    float* __restrict__ Ssum, int Kd, int Kp)
{
  __shared__ float red[256];
  int row = blockIdx.x;
  float s = 0.f;
  for (int k = threadIdx.x; k < Kp; k += 256) {
    float v = 0.f;
    if (k < Kd) {
      v = 1.f / (1.f + __expf(-Wp[(size_t)row * Kd + k]));
      s += v;
    }
    Sgb[(size_t)row * Kp + k] = f2bf(v);
  }
  float tot = block_reduce_sum(s, red);
  if (threadIdx.x == 0) Ssum[row] = tot;
}

// ---------------- fused transpose+convert for all weights ----------------
struct TDesc { const float* src; unsigned short* dst; int K, N, Kp, tilesX, blk0; };
struct TPack { TDesc d[16]; };

__global__ __launch_bounds__(256) void tconv_all_kernel(TPack P) {
  __shared__ float t[32][33];
  int bid = blockIdx.x;
  int di = 0;
  #pragma unroll
  for (int k = 1; k < 16; ++k) if (bid >= P.d[k].blk0) di = k;
  const float* src = P.d[di].src;
  unsigned short* dst = P.d[di].dst;
  int K = P.d[di].K, N = P.d[di].N, Kp = P.d[di].Kp, tilesX = P.d[di].tilesX;
  int local = bid - P.d[di].blk0;
  int bn = (local % tilesX) * 32;
  int bk = (local / tilesX) * 32;
  int tid = threadIdx.x;
  int tx = tid & 31, ty = tid >> 5;
  #pragma unroll
  for (int u = 0; u < 4; ++u) {
    int k = bk + ty + u * 8, n = bn + tx;
    t[ty + u * 8][tx] = (k < K && n < N) ? src[(size_t)k * N + n] : 0.f;
  }
  __syncthreads();
  #pragma unroll
  for (int u = 0; u < 4; ++u) {
    int n = bn + ty + u * 8, kk = bk + tx;
    if (n < N && kk < Kp)
      dst[(size_t)n * Kp + kk] = f2bf(t[tx][ty + u * 8]);
  }
}

// ---------------- MFMA bf16 GEMM: C = epi(A @ Bt^T + bias) ----------------
template<int BM, int EPI, bool WF32, bool WBF, bool WTR>
__global__ __launch_bounds__(256) void mgemm_kernel(
    const unsigned short* __restrict__ A, const unsigned short* __restrict__ Bt,
    const float* __restrict__ bias, float* __restrict__ C,
    unsigned short* __restrict__ Cb, unsigned short* __restrict__ Ct,
    int M, int N, int K, const float* __restrict__ divv,
    const float* __restrict__ bias2, int Nk)
{
  constexpr int NJ = (BM == 128) ? 4 : 2;
  constexpr bool SPLIT = WBF && WTR;
  __shared__ __align__(16) unsigned short Als[BM * 32];
  __shared__ __align__(16) unsigned short Bls[128 * 32];
  const int tid = threadIdx.x;
  const int lane = tid & 63, w = tid >> 6;
  const int wm = (BM == 128) ? (w >> 1) : 0;
  const int wn = (BM == 128) ? (w & 1) : w;
  const int brow = blockIdx.y * BM, bcol = blockIdx.x * 128;

  f32x4 acc[4][NJ] = {};

  for (int k0 = 0; k0 < K; k0 += 32) {
    #pragma unroll
    for (int q = 0; q < 2; ++q) {
      int s = w * 128 + q * 64 + lane;
      int r = s >> 2, g = s & 3;
      int gs = g ^ (r & 3);
      int gc = bcol + r; if (gc > N - 1) gc = N - 1;
      gload_lds16(Bt + (size_t)gc * K + k0 + gs * 8,
                  (char*)Bls + (w * 2048 + q * 1024));
    }
    if constexpr (BM == 128) {
      #pragma unroll
      for (int q = 0; q < 2; ++q) {
        int s = w * 128 + q * 64 + lane;
        int r = s >> 2, g = s & 3;
        int gs = g ^ (r & 3);
        int gr = brow + r; if (gr > M - 1) gr = M - 1;
        gload_lds16(A + (size_t)gr * K + k0 + gs * 8,
                    (char*)Als + (w * 2048 + q * 1024));
      }
    } else {
      int s = w * 64 + lane;
      int r = s >> 2, g = s & 3;
      int gs = g ^ (r & 3);
      int gr = brow + r; if (gr > M - 1) gr = M - 1;
      gload_lds16(A + (size_t)gr * K + k0 + gs * 8,
                  (char*)Als + w * 1024);
    }
    __syncthreads();

    bfrag av[4], bv[NJ];
    #pragma unroll
    for (int f = 0; f < 4; ++f) {
      int rA = wm * 64 + f * 16 + (lane & 15);
      av[f] = *(const bfrag*)((const char*)Als + rA * 64 + ((((lane >> 4) ^ (rA & 3))) << 4));
    }
    #pragma unroll
    for (int f = 0; f < NJ; ++f) {
      int rB = wn * (16 * NJ) + f * 16 + (lane & 15);
      bv[f] = *(const bfrag*)((const char*)Bls + rB * 64 + ((((lane >> 4) ^ (rB & 3))) << 4));
    }
    #pragma unroll
    for (int i = 0; i < 4; ++i)
      #pragma unroll
      for (int j = 0; j < NJ; ++j)
        acc[i][j] = __builtin_amdgcn_mfma_f32_16x16x32_bf16(av[i], bv[j], acc[i][j], 0, 0, 0);
    __syncthreads();
  }

  #pragma unroll
  for (int i = 0; i < 4; ++i) {
    int gr0 = brow + wm * 64 + i * 16 + (lane >> 4) * 4;
    #pragma unroll
    for (int j = 0; j < NJ; ++j) {
      int gc = bcol + wn * (16 * NJ) + j * 16 + (lane & 15);
      float bsv;
      if (SPLIT) bsv = (gc < Nk) ? bias[gc] : bias2[gc - Nk];
      else       bsv = bias ? bias[gc] : 0.f;
      float vv[4];
      #pragma unroll
      for (int q = 0; q < 4; ++q) {
        int gr = gr0 + q;
        float v = acc[i][j][q] + bsv;
        if (EPI >= 1) v = fmaxf(v, 0.f);
        if (EPI == 2) v = (gr < M) ? v / divv[gr] : v;
        vv[q] = v;
      }
      if (SPLIT) {
        if (gc < Nk) {
          #pragma unroll
          for (int q = 0; q < 4; ++q) {
            int gr = gr0 + q;
            if (gr < M) Cb[(size_t)gr * Nk + gc] = f2bf(vv[q]);
          }
        } else {
          ushort4 h4 = { f2bf(vv[0]), f2bf(vv[1]), f2bf(vv[2]), f2bf(vv[3]) };
          *(ushort4*)(Ct + (size_t)(gc - Nk) * M + gr0) = h4;
        }
      } else {
        #pragma unroll
        for (int q = 0; q < 4; ++q) {
          int gr = gr0 + q;
          if (gr >= M) continue;
          if (WF32) C[(size_t)gr * N + gc] = vv[q];
          if (WBF)  Cb[(size_t)gr * N + gc] = f2bf(vv[q]);
        }
        if (WTR) {
          ushort4 h4 = { f2bf(vv[0]), f2bf(vv[1]), f2bf(vv[2]), f2bf(vv[3]) };
          *(ushort4*)(Ct + (size_t)gc * M + gr0) = h4;
        }
      }
    }
  }
}

// ---------------- embedding gather ----------------
__global__ __launch_bounds__(256) void gather_kernel(
    const int* __restrict__ p_data, const int* __restrict__ pa_data,
    const float* __restrict__ E, const float* __restrict__ diff_W,
    float* __restrict__ qemb, unsigned short* __restrict__ qembb,
    float* __restrict__ qaemb, unsigned short* __restrict__ qaembb)
{
  int idx = blockIdx.x * 256 + threadIdx.x;
  if (idx >= 8192 * 512) return;
  int row = idx >> 9, c = idx & 511;
  int p = p_data[row];
  float pid = diff_W[p];
  if (c < 256) {
    float v = E[(size_t)p * 256 + c] + pid;
    qemb[(size_t)row * 256 + c] = v;
    qembb[(size_t)row * 256 + c] = f2bf(v);
  }
  int pa = pa_data[row];
  int ppos = (pa > 4096) ? pa - 4096 : 0;
  int pneg = (pa <= 4096) ? pa : 0;
  float v = (c < 256) ? E[(size_t)ppos * 256 + c] : E[(size_t)pneg * 256 + (c - 256)];
  v += pid;
  qaemb[(size_t)row * 512 + c] = v;
  qaembb[(size_t)row * 512 + c] = f2bf(v);
}

// ---------------- c_reg ----------------
__global__ __launch_bounds__(256) void creg_kernel(
    const int* __restrict__ p_data, const float* __restrict__ dW,
    float* __restrict__ out)
{
  __shared__ float red[256];
  float s = 0.f;
  for (int i = threadIdx.x; i < 8192; i += 256) {
    float v = dW[p_data[i]];
    s += v * v;
  }
  float tot = block_reduce_sum(s, red);
  if (threadIdx.x == 0) out[0] = tot * 1e-5f;
}

// ---------------- MFMA distance-decay attention v9 ----------------
// 16 query rows/block, 512 threads (8 waves). CHUNK elems/lane in softmax.
// exp2-domain softmax (L2E folded into QK scatter); unnormalized cumsum with
// rsqrt(l1) folded into the gamma coefficient; wgt=1/l2 deferred to PV epilogue.
// f32 scores in swizzled LDS: addr(r,j) = r*RS + j + 4*(j>>5), RS = 36*CHUNK+4.
// Split-P bf16 hi/lo planes; V prefetched; descending-NK block order; XCD swizzle.
template<int DK, int DV, int MASKK, int ZP, int CHUNK>
__global__ __launch_bounds__(512, 4) void attn7_kernel(
    const unsigned short* __restrict__ QKb, const unsigned short* __restrict__ Vt,
    const float* __restrict__ gamp, unsigned short* __restrict__ O,
    int S, int MT, int bxoff)
{
  constexpr int RS = 36 * CHUNK + 4;
  constexpr int LBITS = (CHUNK == 32) ? 2 : 1;
  constexpr int LM = (1 << LBITS) - 1;
  constexpr int HIOFF = 64 * CHUNK;
  constexpr int NPAR = (DV == 64) ? 2 : 4;
  constexpr int NFIN = (DV == 64) ? 4 : 2;
  constexpr int NP   = (DV == 32) ? 6 : 4;
  constexpr int MAXIT = (DV == 64) ? (CHUNK == 32 ? 8 : 4) : (CHUNK == 32 ? 4 : 2);
  const int DMK = NHEADS * DK, DMV = NHEADS * DV;
  const int nIb = gridDim.x;
  const int id = blockIdx.x + blockIdx.y * nIb;
  const int cpx = nIb * 8;
  const int W = (id & 7) * cpx + (id >> 3);
  const int ib = (nIb - 1) - (W % nIb);     // descending-NK launch order
  const int bh = W / nIb;
  const int i0 = (ib + bxoff) * 16;
  const int b = bh >> 3, h = bh & 7;
  const int tid = threadIdx.x;
  const int lane = tid & 63, w = tid >> 6;
  const size_t rowbase = (size_t)b * S;

  __shared__ __align__(16) float sc[16 * RS];
  __shared__ float red[NP * 16 * 17];
  __shared__ float wrow[16];

  const int jmaxBlk = MASKK ? (i0 + 15) : (i0 + 14);
  const int nT = jmaxBlk / 64 + 1;
  const int NK = nT * 64;

  const int qr = lane & 15;
  const int ko8 = (lane >> 4) * 8;
  const float rscale = rsqrtf((float)DK) * L2E;   // exp2 domain

  // PV role constants (needed early for prefetch)
  const int dblk = (DV == 64) ? (w & 3) : (w & 1);
  const int par  = (DV == 64) ? (w >> 2) : (w >> 1);
  const int dcol = h * DV + dblk * 16 + (lane & 15);
  const unsigned short* vrow = Vt + (size_t)dcol * MT + rowbase;
  bfrag vpre[2 * MAXIT];

  bfrag qf[DK / 32];
  #pragma unroll
  for (int ks = 0; ks < DK / 32; ++ks)
    qf[ks] = *(const bfrag*)(QKb + (rowbase + i0 + qr) * DMK + h * DK + ks * 32 + ko8);

  // ---- QK^T (rscale*L2E folded into scatter) ----
  for (int t0 = 0; t0 < NK; t0 += 128) {
    int tt = t0 + (w >> 2) * 64;
    if (tt < NK) {
      int jb = tt + (w & 3) * 16 + qr;
      bfrag kf[DK / 32];
      #pragma unroll
      for (int ks = 0; ks < DK / 32; ++ks)
        kf[ks] = *(const bfrag*)(QKb + (rowbase + jb) * DMK + h * DK + ks * 32 + ko8);
      f32x4 accs = {};
      #pragma unroll
      for (int ks = 0; ks < DK / 32; ++ks)
        accs = __builtin_amdgcn_mfma_f32_16x16x32_bf16(qf[ks], kf[ks], accs, 0, 0, 0);
      int ja = jb + 4 * (jb >> 5);
      int r0 = (lane >> 4) * 4;
      #pragma unroll
      for (int q = 0; q < 4; ++q)
        sc[(r0 + q) * RS + ja] = accs[q] * rscale;
    }
  }
  __syncthreads();

  // ---- softmax pipeline (exp2 domain): group g owns query row g ----
  {
    const int g = tid >> 5, l = tid & 31;
    const int i = i0 + g;
    const int jmax = MASKK ? i : i - 1;
    const int jb0 = CHUNK * l;
    const int sb = g * RS + jb0 + 4 * (jb0 >> 5);

    float p[CHUNK];
    float m1 = -1e30f;
    #pragma unroll
    for (int c = 0; c < CHUNK / 4; ++c) {
      f32x4 v = *(const f32x4*)(sc + sb + c * 4);
      #pragma unroll
      for (int k = 0; k < 4; ++k) {
        int j = jb0 + c * 4 + k;
        float s = (j <= jmax) ? v[k] : -1e30f;
        p[c * 4 + k] = s;
        m1 = fmaxf(m1, s);
      }
    }
    #pragma unroll
    for (int o = 16; o > 0; o >>= 1) m1 = fmaxf(m1, __shfl_xor(m1, o, 32));

    float e1[CHUNK];
    float lloc = 0.f;
    #pragma unroll
    for (int t = 0; t < CHUNK; ++t) { e1[t] = __builtin_amdgcn_exp2f(p[t] - m1); lloc += e1[t]; }
    float l1 = lloc;
    #pragma unroll
    for (int o = 16; o > 0; o >>= 1) l1 += __shfl_xor(l1, o, 32);

    // exclusive cross-lane prefix of unnormalized lane totals
    float scn = lloc;
    #pragma unroll
    for (int o = 1; o < 32; o <<= 1) {
      float u = __shfl_up(scn, o, 32);
      if (l >= o) scn += u;
    }
    float cum = scn - lloc;

    // gamma coefficient with 1/sqrt(l1) and L2E folded in
    float gv = gamp[h];
    float sp = fmaxf(gv, 0.f) + log1pf(__expf(-fabsf(gv)));
    float gmr = -sp * L2E * rsqrtf(l1);
    float dj = (float)(i - jb0);
    float m2 = -1e30f;
    #pragma unroll
    for (int t = 0; t < CHUNK; ++t) {
      cum += e1[t];
      float rem = fmaxf(l1 - cum, 0.f);
      float dsq = sqrtf(rem * fabsf(dj));
      dj -= 1.f;
      float eff = fmaxf(__builtin_amdgcn_exp2f(gmr * dsq), 1e-5f);
      p[t] = p[t] * eff;
      m2 = fmaxf(m2, p[t]);
    }
    #pragma unroll
    for (int o = 16; o > 0; o >>= 1) m2 = fmaxf(m2, __shfl_xor(m2, o, 32));

    float l2 = 0.f;
    #pragma unroll
    for (int t = 0; t < CHUNK; ++t) { p[t] = __builtin_amdgcn_exp2f(p[t] - m2); l2 += p[t]; }
    #pragma unroll
    for (int o = 16; o > 0; o >>= 1) l2 += __shfl_xor(l2, o, 32);
    bool validrow = (jmax >= 0) && !(ZP && i == 0);
    float wgt = validrow ? (1.f / l2) : 0.f;
    if (l == 0) wrow[g] = wgt;

    // ---- issue PV V-fragment prefetch; latency hides under plane conversion ----
    #pragma unroll
    for (int it = 0; it < MAXIT; ++it) {
      int t0 = (par + it * NPAR) * 64;
      int t0c = (t0 < NK) ? t0 : 0;
      #pragma unroll
      for (int ks = 0; ks < 2; ++ks)
        vpre[it * 2 + ks] = *(const bfrag*)(vrow + t0c + ks * 32 + ko8);
    }

    // convert to bf16 hi/lo planes (unweighted; wgt applied in epilogue)
    char* rowB = (char*)sc + (size_t)g * (RS * 4);
    #pragma unroll
    for (int k = 0; k < CHUNK / 8; ++k) {
      int bb = (CHUNK / 8) * l + k;
      int pb = ((bb & LM) << 5) | (bb >> LBITS);
      u16x8 hi8, lo8;
      #pragma unroll
      for (int e = 0; e < 8; ++e) {
        float v = p[8 * k + e];
        __bf16 hb = (__bf16)v;
        hi8[e] = __builtin_bit_cast(unsigned short, hb);
        lo8[e] = __builtin_bit_cast(unsigned short, (__bf16)(v - (float)hb));
      }
      *(u16x8*)(rowB + 16 * pb) = hi8;
      *(u16x8*)(rowB + HIOFF + 16 * pb) = lo8;
    }
  }
  __syncthreads();

  // ---- PV: LDS plane reads + prefetched V + MFMA ----
  f32x4 acco = {};
  const char* rowB = (const char*)sc + (size_t)qr * (RS * 4);
  #pragma unroll
  for (int it = 0; it < MAXIT; ++it) {
    int t0 = (par + it * NPAR) * 64;
    if (t0 < NK) {
      #pragma unroll
      for (int ks = 0; ks < 2; ++ks) {
        int jo = t0 + ks * 32 + ko8;
        int bb = jo >> 3;
        int pb = ((bb & LM) << 5) | (bb >> LBITS);
        bfrag ph = *(const bfrag*)(rowB + 16 * pb);
        bfrag pl = *(const bfrag*)(rowB + HIOFF + 16 * pb);
        bfrag vf = vpre[it * 2 + ks];
        acco = __builtin_amdgcn_mfma_f32_16x16x32_bf16(pl, vf, acco, 0, 0, 0);
        acco = __builtin_amdgcn_mfma_f32_16x16x32_bf16(ph, vf, acco, 0, 0, 0);
      }
    }
  }

  if (w >= NFIN) {
    #pragma unroll
    for (int q = 0; q < 4; ++q)
      red[(w - NFIN) * 272 + ((lane >> 4) * 4 + q) * 17 + (lane & 15)] = acco[q];
  }
  __syncthreads();
  if (w < NFIN) {
    for (int pp = w; pp < NP; pp += NFIN) {
      #pragma unroll
      for (int q = 0; q < 4; ++q)
        acco[q] += red[pp * 272 + ((lane >> 4) * 4 + q) * 17 + (lane & 15)];
    }
    int r0 = (lane >> 4) * 4;
    #pragma unroll
    for (int q = 0; q < 4; ++q) {
      float wv = wrow[r0 + q];
      O[(rowbase + i0 + r0 + q) * DMV + dcol] = f2bf(acco[q] * wv);
    }
  }
}

// ---------------- LayerNorm v4: one row per wave, float4 loads ----------------
template<int D, bool WF, bool WB>
__global__ __launch_bounds__(256) void ln4_kernel(
    const float* __restrict__ X, const float* __restrict__ R,
    const float* __restrict__ g, const float* __restrict__ be,
    float* __restrict__ Y, unsigned short* __restrict__ Yb)
{
  constexpr int NC = D / 256;
  int row = blockIdx.x * 4 + (threadIdx.x >> 6);
  int lane = threadIdx.x & 63;
  const float* x = X + (size_t)row * D;
  f32x4 xv[NC];
  float s = 0.f;
  #pragma unroll
  for (int c = 0; c < NC; ++c) {
    xv[c] = *(const f32x4*)(x + c * 256 + lane * 4);
    if (R) {
      f32x4 rv = *(const f32x4*)(R + (size_t)row * D + c * 256 + lane * 4);
      #pragma unroll
      for (int k = 0; k < 4; ++k) xv[c][k] += rv[k];
    }
    #pragma unroll
    for (int k = 0; k < 4; ++k) s += xv[c][k];
  }
  #pragma unroll
  for (int o = 32; o > 0; o >>= 1) s += __shfl_xor(s, o, 64);
  float mean = s / (float)D;
  float vs = 0.f;
  #pragma unroll
  for (int c = 0; c < NC; ++c)
    #pragma unroll
    for (int k = 0; k < 4; ++k) { float d = xv[c][k] - mean; vs += d * d; }
  #pragma unroll
  for (int o = 32; o > 0; o >>= 1) vs += __shfl_xor(vs, o, 64);
  float rstd = rsqrtf(vs / (float)D + 1e-5f);
  #pragma unroll
  for (int c = 0; c < NC; ++c) {
    f32x4 gv = *(const f32x4*)(g + c * 256 + lane * 4);
    f32x4 bv = *(const f32x4*)(be + c * 256 + lane * 4);
    f32x4 ov;
    #pragma unroll
    for (int k = 0; k < 4; ++k) ov[k] = gv[k] * (xv[c][k] - mean) * rstd + bv[k];
    if (WF) *(f32x4*)(Y + (size_t)row * D + c * 256 + lane * 4) = ov;
    if (WB) {
      ushort4 h4 = { f2bf(ov[0]), f2bf(ov[1]), f2bf(ov[2]), f2bf(ov[3]) };
      *(ushort4*)(Yb + (size_t)row * D + c * 256 + lane * 4) = h4;
    }
  }
}

// ---------------- fused concat + LN (D=512) ----------------
__global__ __launch_bounds__(256) void lnc_kernel(
    const float* __restrict__ Xh, const float* __restrict__ Qe,
    const float* __restrict__ g, const float* __restrict__ be,
    unsigned short* __restrict__ Yb)
{
  int row = blockIdx.x * 4 + (threadIdx.x >> 6);
  int lane = threadIdx.x & 63;
  f32x4 xv[2];
  xv[0] = *(const f32x4*)(Xh + (size_t)row * 256 + lane * 4);
  xv[1] = *(const f32x4*)(Qe + (size_t)row * 256 + lane * 4);
  float s = 0.f;
  #pragma unroll
  for (int c = 0; c < 2; ++c)
    #pragma unroll
    for (int k = 0; k < 4; ++k) s += xv[c][k];
  #pragma unroll
  for (int o = 32; o > 0; o >>= 1) s += __shfl_xor(s, o, 64);
  float mean = s / 512.f;
  float vs = 0.f;
  #pragma unroll
  for (int c = 0; c < 2; ++c)
    #pragma unroll
    for (int k = 0; k < 4; ++k) { float d = xv[c][k] - mean; vs += d * d; }
  #pragma unroll
  for (int o = 32; o > 0; o >>= 1) vs += __shfl_xor(vs, o, 64);
  float rstd = rsqrtf(vs / 512.f + 1e-5f);
  #pragma unroll
  for (int c = 0; c < 2; ++c) {
    f32x4 gv = *(const f32x4*)(g + c * 256 + lane * 4);
    f32x4 bv = *(const f32x4*)(be + c * 256 + lane * 4);
    ushort4 h4;
    #pragma unroll
    for (int k = 0; k < 4; ++k) {
      float ov = gv[k] * (xv[c][k] - mean) * rstd + bv[k];
      ((unsigned short*)&h4)[k] = f2bf(ov);
    }
    *(ushort4*)(Yb + (size_t)row * 512 + c * 256 + lane * 4) = h4;
  }
}

// ---------------- fused LN(D=256) + dot ----------------
__global__ __launch_bounds__(256) void lndot_kernel(
    const float* __restrict__ X, const float* __restrict__ g,
    const float* __restrict__ be, const float* __restrict__ w3,
    const float* __restrict__ b3, float* __restrict__ out)
{
  int row = blockIdx.x * 4 + (threadIdx.x >> 6);
  int lane = threadIdx.x & 63;
  f32x4 v = *(const f32x4*)(X + (size_t)row * 256 + lane * 4);
  float s = v[0] + v[1] + v[2] + v[3];
  #pragma unroll
  for (int o = 32; o > 0; o >>= 1) s += __shfl_xor(s, o, 64);
  float mean = s / 256.f;
  float vs = 0.f;
  #pragma unroll
  for (int k = 0; k < 4; ++k) { float d = v[k] - mean; vs += d * d; }
  #pragma unroll
  for (int o = 32; o > 0; o >>= 1) vs += __shfl_xor(vs, o, 64);
  float rstd = rsqrtf(vs / 256.f + 1e-5f);
  f32x4 gv = *(const f32x4*)(g + lane * 4);
  f32x4 bv = *(const f32x4*)(be + lane * 4);
  f32x4 wv = *(const f32x4*)(w3 + lane * 4);
  float d = 0.f;
  #pragma unroll
  for (int k = 0; k < 4; ++k)
    d += (gv[k] * (v[k] - mean) * rstd + bv[k]) * wv[k];
  #pragma unroll
  for (int o = 32; o > 0; o >>= 1) d += __shfl_xor(d, o, 64);
  if (lane == 0) out[row] = d + b3[0];
}

// ---------------- launch ----------------
extern "C" void kernel_launch(void* const* d_in, const int* in_sizes, int n_in,
                              void* d_out, int out_size, void* d_ws, size_t ws_size,
                              hipStream_t stream) {
  const int* p_data  = (const int*)d_in[0];
  const int* pa_data = (const int*)d_in[1];
  const float* pemb_W = (const float*)d_in[3];
  const float* diff_W = (const float*)d_in[4];
  const float* qemb_W = (const float*)d_in[5];
  const float* qemb_b = (const float*)d_in[6];
  const float* y_kW = (const float*)d_in[7];   const float* y_kb = (const float*)d_in[8];
  const float* y_vW = (const float*)d_in[9];   const float* y_vb = (const float*)d_in[10];
  const float* y_oW = (const float*)d_in[11];  const float* y_ob = (const float*)d_in[12];
  const float* y_gam = (const float*)d_in[13];
  const float* y_ln1g = (const float*)d_in[14]; const float* y_ln1b = (const float*)d_in[15];
  const float* y_f1W = (const float*)d_in[16]; const float* y_f1b = (const float*)d_in[17];
  const float* y_f2W = (const float*)d_in[18]; const float* y_f2b = (const float*)d_in[19];
  const float* y_ln2g = (const float*)d_in[20]; const float* y_ln2b = (const float*)d_in[21];
  const float* x_kW = (const float*)d_in[22];  const float* x_kb = (const float*)d_in[23];
  const float* x_vW = (const float*)d_in[24];  const float* x_vb = (const float*)d_in[25];
  const float* x_oW = (const float*)d_in[26];  const float* x_ob = (const float*)d_in[27];
  const float* x_gam = (const float*)d_in[28];
  const float* x_ln1g = (const float*)d_in[29]; const float* x_ln1b = (const float*)d_in[30];
  const float* h_kW = (const float*)d_in[31];  const float* h_kb = (const float*)d_in[32];
  const float* h_vW = (const float*)d_in[33];  const float* h_vb = (const float*)d_in[34];
  const float* h_oW = (const float*)d_in[35];  const float* h_ob = (const float*)d_in[36];
  const float* h_gam = (const float*)d_in[37];
  const float* h_ln1g = (const float*)d_in[38]; const float* h_ln1b = (const float*)d_in[39];
  const float* h_f1W = (const float*)d_in[40]; const float* h_f1b = (const float*)d_in[41];
  const float* h_f2W = (const float*)d_in[42]; const float* h_f2b = (const float*)d_in[43];
  const float* h_ln2g = (const float*)d_in[44]; const float* h_ln2b = (const float*)d_in[45];
  const float* oln1g = (const float*)d_in[46]; const float* oln1b = (const float*)d_in[47];
  const float* o1W = (const float*)d_in[48];   const float* o1b = (const float*)d_in[49];
  const float* oln2g = (const float*)d_in[50]; const float* oln2b = (const float*)d_in[51];
  const float* o2W = (const float*)d_in[52];   const float* o2b = (const float*)d_in[53];
  const float* oln3g = (const float*)d_in[54]; const float* oln3b = (const float*)d_in[55];
  const float* o3W = (const float*)d_in[56];   const float* o3b = (const float*)d_in[57];

  float* out_f = (float*)d_out;

  const int B = 8, S = 1024, M = B * S;
  const int R = 4097, KQ = 1025, KQP = 1056;

  float* ws = (float*)d_ws;
  size_t off = 0;
  auto alloc = [&](size_t nfloats) { size_t o = off; off += (nfloats + 255) & ~(size_t)255; return o; };
  auto allocs = [&](size_t nshorts) { return alloc((nshorts + 1) / 2); };

  size_t oE    = alloc((size_t)R * 256);
  size_t oSIGb = allocs((size_t)R * KQP);
  size_t oSSUM = alloc(R);
  size_t oQE   = alloc((size_t)M * 256);
  size_t oQEb  = allocs((size_t)M * 256);
  size_t oQA   = alloc((size_t)M * 512);
  size_t oQAb  = allocs((size_t)M * 512);
  size_t oYOb  = allocs((size_t)M * 512);
  size_t oXO   = alloc((size_t)M * 256);
  size_t oXOb  = allocs((size_t)M * 256);
  size_t oHO   = alloc((size_t)M * 256);
  size_t oS0   = alloc((size_t)M * 512);   // FFb arena (S0+S1)
  size_t oS1   = alloc((size_t)M * 512);
  size_t oS2b  = allocs((size_t)M * 512);
  size_t oS3   = alloc((size_t)M * 512);
  size_t oS4   = alloc((size_t)M * 512);
  size_t oSX   = alloc((size_t)M * 512);
  size_t oSXb  = allocs((size_t)M * 512);
  size_t oS0b  = allocs((size_t)M * 512);
  size_t oVt   = allocs((size_t)M * 512);
  size_t oWqe  = allocs((size_t)256 * KQP);
  size_t oWyk  = allocs((size_t)512 * 512);
  size_t oWyv  = allocs((size_t)512 * 512);
  size_t oWyo  = allocs((size_t)512 * 512);
  size_t oWyf1 = allocs((size_t)2048 * 512);
  size_t oWyf2 = allocs((size_t)512 * 2048);
  size_t oWxk  = allocs((size_t)256 * 256);
  size_t oWxv  = allocs((size_t)256 * 256);
  size_t oWxo  = allocs((size_t)256 * 256);
  size_t oWhk  = allocs((size_t)256 * 256);
  size_t oWhv  = allocs((size_t)512 * 512);
  size_t oWho  = allocs((size_t)256 * 512);
  size_t oWhf1 = allocs((size_t)2048 * 256);
  size_t oWhf2 = allocs((size_t)256 * 2048);
  size_t oWo1  = allocs((size_t)512 * 512);
  size_t oWo2  = allocs((size_t)256 * 512);
  (void)ws_size; (void)in_sizes; (void)n_in; (void)out_size;

  float* E    = ws + oE;
  unsigned short* SIGb = (unsigned short*)(ws + oSIGb);
  float* SSUM = ws + oSSUM;
  float* QE   = ws + oQE;   unsigned short* QEb = (unsigned short*)(ws + oQEb);
  float* QA   = ws + oQA;   unsigned short* QAb = (unsigned short*)(ws + oQAb);
  unsigned short* YOb = (unsigned short*)(ws + oYOb);
  float* XO   = ws + oXO;   unsigned short* XOb = (unsigned short*)(ws + oXOb);
  float* HO   = ws + oHO;
  float* S0   = ws + oS0;
  unsigned short* S2b = (unsigned short*)(ws + oS2b);
  float* S3   = ws + oS3;
  float* S4   = ws + oS4;
  float* SX   = ws + oSX;   unsigned short* SXb = (unsigned short*)(ws + oSXb);
  unsigned short* S0b = (unsigned short*)(ws + oS0b);
  unsigned short* Vt  = (unsigned short*)(ws + oVt);
  unsigned short* FFb = (unsigned short*)S0;

  unsigned short* Wqe  = (unsigned short*)(ws + oWqe);
  unsigned short* Wyk  = (unsigned short*)(ws + oWyk);
  unsigned short* Wyv  = (unsigned short*)(ws + oWyv);
  unsigned short* Wyo  = (unsigned short*)(ws + oWyo);
  unsigned short* Wyf1 = (unsigned short*)(ws + oWyf1);
  unsigned short* Wyf2 = (unsigned short*)(ws + oWyf2);
  unsigned short* Wxk  = (unsigned short*)(ws + oWxk);
  unsigned short* Wxv  = (unsigned short*)(ws + oWxv);
  unsigned short* Wxo  = (unsigned short*)(ws + oWxo);
  unsigned short* Whk  = (unsigned short*)(ws + oWhk);
  unsigned short* Whv  = (unsigned short*)(ws + oWhv);
  unsigned short* Who  = (unsigned short*)(ws + oWho);
  unsigned short* Whf1 = (unsigned short*)(ws + oWhf1);
  unsigned short* Whf2 = (unsigned short*)(ws + oWhf2);
  unsigned short* Wo1  = (unsigned short*)(ws + oWo1);
  unsigned short* Wo2  = (unsigned short*)(ws + oWo2);

  dim3 blk(256);
  int nElem512 = (8192 * 512 + 255) / 256;

  // ---- fused weight transposes ----
  {
    struct HD { const float* src; unsigned short* dst; int K, N, Kp; };
    const HD hd[16] = {
      {qemb_W, Wqe, KQ, 256, KQP},
      {y_kW, Wyk, 512, 512, 512}, {y_vW, Wyv, 512, 512, 512}, {y_oW, Wyo, 512, 512, 512},
      {y_f1W, Wyf1, 512, 2048, 512}, {y_f2W, Wyf2, 2048, 512, 2048},
      {x_kW, Wxk, 256, 256, 256}, {x_vW, Wxv, 256, 256, 256}, {x_oW, Wxo, 256, 256, 256},
      {h_kW, Whk, 256, 256, 256}, {h_vW, Whv, 512, 512, 512}, {h_oW, Who, 512, 256, 512},
      {h_f1W, Whf1, 256, 2048, 256}, {h_f2W, Whf2, 2048, 256, 2048},
      {o1W, Wo1, 512, 512, 512}, {o2W, Wo2, 512, 256, 512},
    };
    TPack P;
    int tot = 0;
    for (int k = 0; k < 16; ++k) {
      int tx = (hd[k].N + 31) / 32, ty = (hd[k].Kp + 31) / 32;
      P.d[k] = { hd[k].src, hd[k].dst, hd[k].K, hd[k].N, hd[k].Kp, tx, tot };
      tot += tx * ty;
    }
    tconv_all_kernel<<<dim3(tot), blk, 0, stream>>>(P);
  }

  auto gg128 = [](int Mm, int Nn) { return dim3((unsigned)(Nn / 128), (unsigned)((Mm + 127) / 128)); };
  auto gg64  = [](int Mm, int Nn) { return dim3((unsigned)(Nn / 128), (unsigned)((Mm + 63) / 64)); };

  // 1. embedding table
  sig_kernel<<<R, blk, 0, stream>>>(pemb_W, SIGb, SSUM, KQ, KQP);
  mgemm_kernel<64, 2, true, false, false><<<gg64(R, 256), blk, 0, stream>>>(SIGb, Wqe, qemb_b, E, nullptr, nullptr, R, 256, KQP, SSUM, nullptr, 0);
  gather_kernel<<<nElem512, blk, 0, stream>>>(p_data, pa_data, E, diff_W, QE, QEb, QA, QAb);
  creg_kernel<<<1, blk, 0, stream>>>(p_data, diff_W, out_f + 8192);

  dim3 ablk(512);
  dim3 lgrid(M / 4);
  dim3 agB(32, B * NHEADS), agC(32, B * NHEADS);   // CHUNK16: ib 0-31, CHUNK32: ib 32-63

  // 2. y layer (dm=512, mask_k=1, zero_pad=0, FFN). Fused KV proj.
  mgemm_kernel<128, 0, false, true, true><<<dim3(8, 64), blk, 0, stream>>>(QAb, Wyk, y_kb, nullptr, S0b, Vt, M, 1024, 512, nullptr, y_vb, 512);
  attn7_kernel<64, 64, 1, 0, 16><<<agB, ablk, 0, stream>>>(S0b, Vt, y_gam, S2b, S, M, 0);
  attn7_kernel<64, 64, 1, 0, 32><<<agC, ablk, 0, stream>>>(S0b, Vt, y_gam, S2b, S, M, 32);
  mgemm_kernel<128, 0, true, false, false><<<gg128(M, 512), blk, 0, stream>>>(S2b, Wyo, y_ob, S3, nullptr, nullptr, M, 512, 512, nullptr, nullptr, 0);
  ln4_kernel<512, true, true><<<lgrid, blk, 0, stream>>>(QA, S3, y_ln1g, y_ln1b, SX, SXb);
  mgemm_kernel<128, 1, false, true, false><<<gg128(M, 2048), blk, 0, stream>>>(SXb, Wyf1, y_f1b, nullptr, FFb, nullptr, M, 2048, 512, nullptr, nullptr, 0);
  mgemm_kernel<128, 0, true, false, false><<<gg128(M, 512), blk, 0, stream>>>(FFb, Wyf2, y_f2b, S4, nullptr, nullptr, M, 512, 2048, nullptr, nullptr, 0);
  ln4_kernel<512, false, true><<<lgrid, blk, 0, stream>>>(SX, S4, y_ln2g, y_ln2b, nullptr, YOb);

  // 3. x layer (dm=256, mask_k=1, zero_pad=0, no FFN). Fused KV proj.
  mgemm_kernel<128, 0, false, true, true><<<dim3(4, 64), blk, 0, stream>>>(QEb, Wxk, x_kb, nullptr, S0b, Vt, M, 512, 256, nullptr, x_vb, 256);
  attn7_kernel<32, 32, 1, 0, 16><<<agB, ablk, 0, stream>>>(S0b, Vt, x_gam, S2b, S, M, 0);
  attn7_kernel<32, 32, 1, 0, 32><<<agC, ablk, 0, stream>>>(S0b, Vt, x_gam, S2b, S, M, 32);
  mgemm_kernel<64, 0, true, false, false><<<gg64(M, 256), blk, 0, stream>>>(S2b, Wxo, x_ob, S3, nullptr, nullptr, M, 256, 256, nullptr, nullptr, 0);
  ln4_kernel<256, true, true><<<lgrid, blk, 0, stream>>>(QE, S3, x_ln1g, x_ln1b, XO, XOb);

  // 4. h layer (q,k from XO; v from YO; mask_k=0, zero_pad=1, FFN)
  mgemm_kernel<64, 0, false, true, false><<<gg64(M, 256), blk, 0, stream>>>(XOb, Whk, h_kb, nullptr, S0b, nullptr, M, 256, 256, nullptr, nullptr, 0);
  mgemm_kernel<128, 0, false, false, true><<<gg128(M, 512), blk, 0, stream>>>(YOb, Whv, h_vb, nullptr, nullptr, Vt, M, 512, 512, nullptr, nullptr, 0);
  attn7_kernel<32, 64, 0, 1, 16><<<agB, ablk, 0, stream>>>(S0b, Vt, h_gam, S2b, S, M, 0);
  attn7_kernel<32, 64, 0, 1, 32><<<agC, ablk, 0, stream>>>(S0b, Vt, h_gam, S2b, S, M, 32);
  mgemm_kernel<64, 0, true, false, false><<<gg64(M, 256), blk, 0, stream>>>(S2b, Who, h_ob, S3, nullptr, nullptr, M, 256, 512, nullptr, nullptr, 0);
  ln4_kernel<256, true, true><<<lgrid, blk, 0, stream>>>(XO, S3, h_ln1g, h_ln1b, SX, SXb);
  mgemm_kernel<128, 1, false, true, false><<<gg128(M, 2048), blk, 0, stream>>>(SXb, Whf1, h_f1b, nullptr, FFb, nullptr, M, 2048, 256, nullptr, nullptr, 0);
  mgemm_kernel<64, 0, true, false, false><<<gg64(M, 256), blk, 0, stream>>>(FFb, Whf2, h_f2b, S4, nullptr, nullptr, M, 256, 2048, nullptr, nullptr, 0);
  ln4_kernel<256, true, false><<<lgrid, blk, 0, stream>>>(SX, S4, h_ln2g, h_ln2b, HO, nullptr);

  // 5. head: LN(concat) -> o1 -> LN -> o2 -> LN+dot
  lnc_kernel<<<lgrid, blk, 0, stream>>>(HO, QE, oln1g, oln1b, SXb);
  mgemm_kernel<128, 1, true, false, false><<<gg128(M, 512), blk, 0, stream>>>(SXb, Wo1, o1b, S3, nullptr, nullptr, M, 512, 512, nullptr, nullptr, 0);
  ln4_kernel<512, false, true><<<lgrid, blk, 0, stream>>>(S3, nullptr, oln2g, oln2b, nullptr, SXb);
  mgemm_kernel<64, 1, true, false, false><<<gg64(M, 256), blk, 0, stream>>>(SXb, Wo2, o2b, S4, nullptr, nullptr, M, 256, 512, nullptr, nullptr, 0);
  lndot_kernel<<<lgrid, blk, 0, stream>>>(S4, oln3g, oln3b, o3W, o3b, out_f);
}